// Round 1
// baseline (3254.442 us; speedup 1.0000x reference)
//
#include <hip/hip_runtime.h>
#include <float.h>
#include <math.h>

#define L_SEQ 2048
#define D_MODEL 1024
#define N_HEAD 16
#define HD 64
#define N_BH 64
#define U_TOP 40

// ---------------------------------------------------------------------------
// Generic fp32 GEMM: C[8192 x N] = A[8192 x K] @ B[K x N] (+bias) (+relu) (+=)
// 128x128 tile, BK=16, 256 threads, 8x8 per thread (4+4 split micro-tile).
// Grid: (N/128, 64). All our shapes are multiples of 128 -- no bounds checks.
// ---------------------------------------------------------------------------
template<bool RELU, bool ACCUM>
__global__ void __launch_bounds__(256)
gemm_f32(const float* __restrict__ A, int lda,
         const float* __restrict__ B, int ldb,
         float* __restrict__ C, int ldc,
         int K, const float* __restrict__ bias)
{
    __shared__ float As[16][132];   // transposed A tile, padded
    __shared__ float Bs[16][128];
    const int bx = blockIdx.x, by = blockIdx.y;
    const int tid = threadIdx.x;
    const int tx = tid & 15, ty = tid >> 4;

    float acc[8][8];
#pragma unroll
    for (int i = 0; i < 8; ++i)
#pragma unroll
        for (int j = 0; j < 8; ++j) acc[i][j] = 0.f;

    const float* Ablk = A + (size_t)(by * 128) * lda;
    const float* Bblk = B + bx * 128;

    for (int k0 = 0; k0 < K; k0 += 16) {
        // A tile 128x16 -> transposed store
#pragma unroll
        for (int t = 0; t < 2; ++t) {
            int idx = tid + t * 256;
            int ar = idx >> 2, ac4 = idx & 3;
            float4 v = *(const float4*)(Ablk + (size_t)ar * lda + k0 + ac4 * 4);
            As[ac4 * 4 + 0][ar] = v.x;
            As[ac4 * 4 + 1][ar] = v.y;
            As[ac4 * 4 + 2][ar] = v.z;
            As[ac4 * 4 + 3][ar] = v.w;
        }
        // B tile 16x128
#pragma unroll
        for (int t = 0; t < 2; ++t) {
            int idx = tid + t * 256;
            int br = idx >> 5, bc4 = idx & 31;
            float4 v = *(const float4*)(Bblk + (size_t)(k0 + br) * ldb + bc4 * 4);
            *(float4*)&Bs[br][bc4 * 4] = v;
        }
        __syncthreads();
#pragma unroll
        for (int kk = 0; kk < 16; ++kk) {
            float4 a0 = *(const float4*)&As[kk][ty * 4];
            float4 a1 = *(const float4*)&As[kk][64 + ty * 4];
            float4 b0 = *(const float4*)&Bs[kk][tx * 4];
            float4 b1 = *(const float4*)&Bs[kk][64 + tx * 4];
            float av[8] = {a0.x, a0.y, a0.z, a0.w, a1.x, a1.y, a1.z, a1.w};
            float bv[8] = {b0.x, b0.y, b0.z, b0.w, b1.x, b1.y, b1.z, b1.w};
#pragma unroll
            for (int i = 0; i < 8; ++i)
#pragma unroll
                for (int j = 0; j < 8; ++j)
                    acc[i][j] = fmaf(av[i], bv[j], acc[i][j]);
        }
        __syncthreads();
    }

    float bias0[8];
    if (bias != nullptr) {
        float4 c0 = *(const float4*)(bias + bx * 128 + tx * 4);
        float4 c1 = *(const float4*)(bias + bx * 128 + 64 + tx * 4);
        bias0[0] = c0.x; bias0[1] = c0.y; bias0[2] = c0.z; bias0[3] = c0.w;
        bias0[4] = c1.x; bias0[5] = c1.y; bias0[6] = c1.z; bias0[7] = c1.w;
    } else {
#pragma unroll
        for (int j = 0; j < 8; ++j) bias0[j] = 0.f;
    }
#pragma unroll
    for (int i = 0; i < 8; ++i) {
        int row = by * 128 + ((i < 4) ? (ty * 4 + i) : (64 + ty * 4 + (i - 4)));
        float* crow = C + (size_t)row * ldc + bx * 128;
#pragma unroll
        for (int jh = 0; jh < 2; ++jh) {
            float4 v;
            v.x = acc[i][jh * 4 + 0] + bias0[jh * 4 + 0];
            v.y = acc[i][jh * 4 + 1] + bias0[jh * 4 + 1];
            v.z = acc[i][jh * 4 + 2] + bias0[jh * 4 + 2];
            v.w = acc[i][jh * 4 + 3] + bias0[jh * 4 + 3];
            if (RELU) {
                v.x = fmaxf(v.x, 0.f); v.y = fmaxf(v.y, 0.f);
                v.z = fmaxf(v.z, 0.f); v.w = fmaxf(v.w, 0.f);
            }
            float* p = crow + jh * 64 + tx * 4;
            if (ACCUM) {
                float4 o = *(float4*)p;
                v.x += o.x; v.y += o.y; v.z += o.z; v.w += o.w;
            }
            *(float4*)p = v;
        }
    }
}

// ---------------------------------------------------------------------------
// M statistics: M[bh][i] = max_j(q_i . Ks_j) - (sum_j q_i . Ks_j)/2048
// q is the FLAT-reshaped Q buffer (reference quirk). Ks_j = k-head rows
// gathered at index_sample. Block: (i-tile of 128) x bh. 256 threads.
// ---------------------------------------------------------------------------
__global__ void __launch_bounds__(256)
mstat_kernel(const float* __restrict__ Q, const float* __restrict__ K,
             const int* __restrict__ idxs, float* __restrict__ Mout)
{
    __shared__ float Qs[64][132];  // [dd][i_local], padded
    __shared__ float Ks[64][68];   // [dd][j_local], padded
    const int itile = blockIdx.x;  // 0..15
    const int bh = blockIdx.y;
    const int b = bh >> 4, h = bh & 15;
    const int tid = threadIdx.x;
    const int tx = tid & 15, ty = tid >> 4;
    const int i0 = itile * 128;

    const float* Qbase = Q + (size_t)bh * (L_SEQ * HD);
    const float* Kbase = K + (size_t)b * (L_SEQ * D_MODEL) + h * HD;

    // load Q tile (128 rows x 64) transposed
#pragma unroll
    for (int t = 0; t < 8; ++t) {
        int idx = tid + t * 256;
        int il = idx >> 4, c4 = idx & 15;
        float4 v = *(const float4*)(Qbase + (size_t)(i0 + il) * HD + c4 * 4);
        Qs[c4 * 4 + 0][il] = v.x;
        Qs[c4 * 4 + 1][il] = v.y;
        Qs[c4 * 4 + 2][il] = v.z;
        Qs[c4 * 4 + 3][il] = v.w;
    }

    float mx[8], sm[8];
#pragma unroll
    for (int i = 0; i < 8; ++i) { mx[i] = -FLT_MAX; sm[i] = 0.f; }

    for (int jt = 0; jt < 32; ++jt) {
        __syncthreads();
        // gather K-sample tile 64 x 64, transposed
#pragma unroll
        for (int t = 0; t < 4; ++t) {
            int idx = tid + t * 256;
            int jl = idx >> 4, c4 = idx & 15;
            int js = idxs[jt * 64 + jl];
            float4 v = *(const float4*)(Kbase + (size_t)js * D_MODEL + c4 * 4);
            Ks[c4 * 4 + 0][jl] = v.x;
            Ks[c4 * 4 + 1][jl] = v.y;
            Ks[c4 * 4 + 2][jl] = v.z;
            Ks[c4 * 4 + 3][jl] = v.w;
        }
        __syncthreads();

        float accv[8][4];
#pragma unroll
        for (int i = 0; i < 8; ++i)
#pragma unroll
            for (int j = 0; j < 4; ++j) accv[i][j] = 0.f;

#pragma unroll 8
        for (int dd2 = 0; dd2 < 64; ++dd2) {
            float4 a0 = *(const float4*)&Qs[dd2][ty * 4];
            float4 a1 = *(const float4*)&Qs[dd2][64 + ty * 4];
            float4 bb = *(const float4*)&Ks[dd2][tx * 4];
            float av[8] = {a0.x, a0.y, a0.z, a0.w, a1.x, a1.y, a1.z, a1.w};
            float bv[4] = {bb.x, bb.y, bb.z, bb.w};
#pragma unroll
            for (int i = 0; i < 8; ++i)
#pragma unroll
                for (int j = 0; j < 4; ++j)
                    accv[i][j] = fmaf(av[i], bv[j], accv[i][j]);
        }
#pragma unroll
        for (int i = 0; i < 8; ++i)
#pragma unroll
            for (int j = 0; j < 4; ++j) {
                mx[i] = fmaxf(mx[i], accv[i][j]);
                sm[i] += accv[i][j];
            }
    }

    __syncthreads();
    // reduce across tx via LDS (reuse Qs storage: 4096 floats needed)
    float* redm = &Qs[0][0];
    float* reds = redm + 128 * 16;
#pragma unroll
    for (int i = 0; i < 8; ++i) {
        int row = (i < 4) ? (ty * 4 + i) : (64 + ty * 4 + (i - 4));
        redm[row * 16 + tx] = mx[i];
        reds[row * 16 + tx] = sm[i];
    }
    __syncthreads();
    if (tid < 128) {
        float m_ = -FLT_MAX, s_ = 0.f;
#pragma unroll
        for (int t2 = 0; t2 < 16; ++t2) {
            m_ = fmaxf(m_, redm[tid * 16 + t2]);
            s_ += reds[tid * 16 + t2];
        }
        Mout[(size_t)bh * L_SEQ + i0 + tid] = m_ - s_ * (1.0f / 2048.0f);
    }
}

// ---------------------------------------------------------------------------
// Top-40 smallest M per bh, lower-index tie-break (matches lax.top_k on -M).
// ---------------------------------------------------------------------------
__global__ void __launch_bounds__(256)
topk_kernel(const float* __restrict__ M, int* __restrict__ Mtop)
{
    __shared__ float mv[L_SEQ];
    __shared__ float wv_[4];
    __shared__ int wi_[4];
    const int bh = blockIdx.x;
    const int tid = threadIdx.x;
    for (int j = tid; j < L_SEQ; j += 256) mv[j] = M[(size_t)bh * L_SEQ + j];
    __syncthreads();
    for (int u = 0; u < U_TOP; ++u) {
        float best = FLT_MAX;
        int bi = 1 << 30;
        for (int j = tid; j < L_SEQ; j += 256) {
            float v = mv[j];
            if (v < best || (v == best && j < bi)) { best = v; bi = j; }
        }
#pragma unroll
        for (int off = 32; off; off >>= 1) {
            float ov = __shfl_down(best, off);
            int oi = __shfl_down(bi, off);
            if (ov < best || (ov == best && oi < bi)) { best = ov; bi = oi; }
        }
        if ((tid & 63) == 0) { wv_[tid >> 6] = best; wi_[tid >> 6] = bi; }
        __syncthreads();
        if (tid == 0) {
            for (int w = 1; w < 4; ++w)
                if (wv_[w] < best || (wv_[w] == best && wi_[w] < bi)) { best = wv_[w]; bi = wi_[w]; }
            Mtop[bh * U_TOP + u] = bi;
            mv[bi] = FLT_MAX;
        }
        __syncthreads();
    }
}

// ---------------------------------------------------------------------------
// Attention for the 40 selected rows, online softmax over all 2048 keys.
// Block per (u, bh), 256 threads. Writes into zero-init ATT (B,L,D) layout.
// ---------------------------------------------------------------------------
__global__ void __launch_bounds__(256)
attn_kernel(const float* __restrict__ Q, const float* __restrict__ K,
            const float* __restrict__ V, const int* __restrict__ Mtop,
            float* __restrict__ ATT)
{
    __shared__ float Ks[128][65];
    __shared__ float qs[64];
    __shared__ float ps[128];
    __shared__ float wred[4];
    __shared__ float fred[256];
    const int u = blockIdx.x, bh = blockIdx.y;
    const int b = bh >> 4, h = bh & 15;
    const int tid = threadIdx.x;
    const int lsel = Mtop[bh * U_TOP + u];

    if (tid < 64)
        qs[tid] = Q[(size_t)bh * (L_SEQ * HD) + (size_t)lsel * HD + tid] * 0.125f; // 1/sqrt(64)

    const float* Kbase = K + (size_t)b * (L_SEQ * D_MODEL) + h * HD;
    const float* Vbase = V + (size_t)b * (L_SEQ * D_MODEL) + h * HD;

    float m_run = -FLT_MAX, l_run = 0.f, accv = 0.f;
    const int ddl = tid & 63, jg = tid >> 6;

    for (int t = 0; t < 16; ++t) {
        const int j0 = t * 128;
        __syncthreads();  // protects Ks/ps reuse across iterations
#pragma unroll
        for (int q4 = 0; q4 < 8; ++q4) {
            int idx = tid + q4 * 256;
            int jl = idx >> 4, c4 = idx & 15;
            float4 v = *(const float4*)(Kbase + (size_t)(j0 + jl) * D_MODEL + c4 * 4);
            Ks[jl][c4 * 4 + 0] = v.x;
            Ks[jl][c4 * 4 + 1] = v.y;
            Ks[jl][c4 * 4 + 2] = v.z;
            Ks[jl][c4 * 4 + 3] = v.w;
        }
        __syncthreads();
        if (tid < 128) {
            float s = 0.f;
#pragma unroll 16
            for (int c = 0; c < 64; ++c) s = fmaf(qs[c], Ks[tid][c], s);
            ps[tid] = s;
        }
        __syncthreads();
        // tile max
        float v_ = (tid < 128) ? ps[tid] : -FLT_MAX;
#pragma unroll
        for (int off = 32; off; off >>= 1) v_ = fmaxf(v_, __shfl_down(v_, off));
        if ((tid & 63) == 0) wred[tid >> 6] = v_;
        __syncthreads();
        float mt = fmaxf(fmaxf(wred[0], wred[1]), fmaxf(wred[2], wred[3]));
        float m_new = fmaxf(m_run, mt);
        float r = expf(m_run - m_new);
        if (tid < 128) ps[tid] = expf(ps[tid] - m_new);
        __syncthreads();
        // tile sum
        float sv = (tid < 128) ? ps[tid] : 0.f;
#pragma unroll
        for (int off = 32; off; off >>= 1) sv += __shfl_down(sv, off);
        if ((tid & 63) == 0) wred[tid >> 6] = sv;
        __syncthreads();
        float lt = wred[0] + wred[1] + wred[2] + wred[3];
        l_run = l_run * r + lt;
        m_run = m_new;
        // PV: thread (ddl, jg) accumulates over its 32 j's
        float a2 = accv * r;
#pragma unroll 8
        for (int jj = 0; jj < 32; ++jj) {
            int j = jg * 32 + jj;
            a2 = fmaf(ps[j], Vbase[(size_t)(j0 + j) * D_MODEL + ddl], a2);
        }
        accv = a2;
    }
    fred[tid] = accv;
    __syncthreads();
    if (tid < 64) {
        float o = (fred[tid] + fred[tid + 64] + fred[tid + 128] + fred[tid + 192]) / l_run;
        ATT[((size_t)b * L_SEQ + lsel) * D_MODEL + h * HD + tid] = o;
    }
}

// ---------------------------------------------------------------------------
// Fused residual + LayerNorm: out = g*(v-mean)/sqrt(var+eps)+b, v = X+A row.
// Block per row (8192), 256 threads x 4 elems.
// ---------------------------------------------------------------------------
__global__ void __launch_bounds__(256)
ln_kernel(const float* __restrict__ X, const float* __restrict__ A,
          const float* __restrict__ g, const float* __restrict__ be,
          float* __restrict__ out)
{
    __shared__ float wred[4];
    const int row = blockIdx.x, tid = threadIdx.x;
    float4 xv = *(const float4*)(X + (size_t)row * D_MODEL + tid * 4);
    float4 av = *(const float4*)(A + (size_t)row * D_MODEL + tid * 4);
    float v0 = xv.x + av.x, v1 = xv.y + av.y, v2 = xv.z + av.z, v3 = xv.w + av.w;

    float s = v0 + v1 + v2 + v3;
#pragma unroll
    for (int off = 32; off; off >>= 1) s += __shfl_down(s, off);
    if ((tid & 63) == 0) wred[tid >> 6] = s;
    __syncthreads();
    float mean = (wred[0] + wred[1] + wred[2] + wred[3]) * (1.f / 1024.f);
    __syncthreads();

    float d0 = v0 - mean, d1 = v1 - mean, d2 = v2 - mean, d3 = v3 - mean;
    float q = d0 * d0 + d1 * d1 + d2 * d2 + d3 * d3;
#pragma unroll
    for (int off = 32; off; off >>= 1) q += __shfl_down(q, off);
    if ((tid & 63) == 0) wred[tid >> 6] = q;
    __syncthreads();
    float var = (wred[0] + wred[1] + wred[2] + wred[3]) * (1.f / 1024.f);
    float rstd = rsqrtf(var + 1e-12f);

    float4 gv = *(const float4*)(g + tid * 4);
    float4 bv = *(const float4*)(be + tid * 4);
    float4 o;
    o.x = gv.x * d0 * rstd + bv.x;
    o.y = gv.y * d1 * rstd + bv.y;
    o.z = gv.z * d2 * rstd + bv.z;
    o.w = gv.w * d3 * rstd + bv.w;
    *(float4*)(out + (size_t)row * D_MODEL + tid * 4) = o;
}

// ---------------------------------------------------------------------------
extern "C" void kernel_launch(void* const* d_in, const int* in_sizes, int n_in,
                              void* d_out, int out_size, void* d_ws, size_t ws_size,
                              hipStream_t stream)
{
    const float* x   = (const float*)d_in[0];
    const float* wq  = (const float*)d_in[1];
    const float* bq  = (const float*)d_in[2];
    const float* wk  = (const float*)d_in[3];
    const float* bk  = (const float*)d_in[4];
    const float* wv  = (const float*)d_in[5];
    const float* bv  = (const float*)d_in[6];
    const float* wo  = (const float*)d_in[7];
    const float* bo  = (const float*)d_in[8];
    const float* w1  = (const float*)d_in[9];
    const float* b1  = (const float*)d_in[10];
    const float* w2  = (const float*)d_in[11];
    const float* b2  = (const float*)d_in[12];
    const float* g1  = (const float*)d_in[13];
    const float* be1 = (const float*)d_in[14];
    const float* g2  = (const float*)d_in[15];
    const float* be2 = (const float*)d_in[16];
    const int*  idxs = (const int*)d_in[17];

    char* ws = (char*)d_ws;
    const size_t SZ = (size_t)8192 * 1024 * 4;  // 32 MB activation buffer
    float* Qb   = (float*)(ws);            // Q (flat)  -> later attn-proj out
    float* Kb   = (float*)(ws + SZ);       // K         -> later x1
    float* Vb   = (float*)(ws + 2 * SZ);   // V         -> later FFN out F
    float* ATT  = (float*)(ws + 3 * SZ);   // scattered attention (B,L,D)
    float* Mb   = (float*)(ws + 4 * SZ);   // M stats 64x2048
    int*   Mtop = (int*)(ws + 4 * SZ + (size_t)N_BH * L_SEQ * 4);
    float* HID  = (float*)d_out;           // FFN hidden chunk (reuses d_out)

    dim3 blk(256);
    dim3 g_gemm(8, 64);  // N=1024 / 128, M=8192 / 128

    // Projections (fp32 -- accuracy needed for exact top-k reproduction)
    gemm_f32<false, false><<<g_gemm, blk, 0, stream>>>(x, 1024, wq, 1024, Qb, 1024, 1024, bq);
    gemm_f32<false, false><<<g_gemm, blk, 0, stream>>>(x, 1024, wk, 1024, Kb, 1024, 1024, bk);
    gemm_f32<false, false><<<g_gemm, blk, 0, stream>>>(x, 1024, wv, 1024, Vb, 1024, 1024, bv);

    // M statistics and top-40 selection
    mstat_kernel<<<dim3(16, 64), blk, 0, stream>>>(Qb, Kb, idxs, Mb);
    topk_kernel<<<dim3(64), blk, 0, stream>>>(Mb, Mtop);

    // Sparse attention -> scattered ATT
    hipMemsetAsync(ATT, 0, SZ, stream);
    attn_kernel<<<dim3(U_TOP, N_BH), blk, 0, stream>>>(Qb, Kb, Vb, Mtop, ATT);

    // Output projection (into Qb), then x1 = LN(x + a) (into Kb)
    gemm_f32<false, false><<<g_gemm, blk, 0, stream>>>(ATT, 1024, wo, 1024, Qb, 1024, 1024, bo);
    ln_kernel<<<dim3(8192), blk, 0, stream>>>(x, Qb, g1, be1, Kb);

    // FFN, K-chunked: HID = relu(x1 @ w1[:,c] + b1[c]); F (+)= HID @ w2[c,:]
    for (int c = 0; c < 4; ++c) {
        gemm_f32<true, false><<<g_gemm, blk, 0, stream>>>(
            Kb, 1024, w1 + c * 1024, 4096, HID, 1024, 1024, b1 + c * 1024);
        if (c == 0)
            gemm_f32<false, false><<<g_gemm, blk, 0, stream>>>(
                HID, 1024, w2 + (size_t)c * 1024 * 1024, 1024, Vb, 1024, 1024, b2);
        else
            gemm_f32<false, true><<<g_gemm, blk, 0, stream>>>(
                HID, 1024, w2 + (size_t)c * 1024 * 1024, 1024, Vb, 1024, 1024, nullptr);
    }

    // out = LN(x1 + F)
    ln_kernel<<<dim3(8192), blk, 0, stream>>>(Kb, Vb, g2, be2, (float*)d_out);
}

// Round 2
// 1687.268 us; speedup vs baseline: 1.9288x; 1.9288x over previous
//
#include <hip/hip_runtime.h>
#include <float.h>
#include <math.h>

#define L_SEQ 2048
#define D_MODEL 1024
#define N_HEAD 16
#define HD 64
#define N_BH 64
#define U_TOP 40

using bf16x8 = __attribute__((ext_vector_type(8))) short;
using f32x4  = __attribute__((ext_vector_type(4))) float;

__device__ __forceinline__ unsigned short f2bf(float f) {
    unsigned int u = __builtin_bit_cast(unsigned int, f);
    u += 0x7fff + ((u >> 16) & 1);   // round-to-nearest-even
    return (unsigned short)(u >> 16);
}
__device__ __forceinline__ float bf2f(unsigned short h) {
    unsigned int u = ((unsigned int)h) << 16;
    return __builtin_bit_cast(float, u);
}

__device__ __forceinline__ void gload_lds16(const void* g, void* l) {
    __builtin_amdgcn_global_load_lds(
        (const __attribute__((address_space(1))) unsigned int*)g,
        (__attribute__((address_space(3))) unsigned int*)l, 16, 0, 0);
}

// ---------------------------------------------------------------------------
// fp32 GEMM (kept for q/k projections -- top-k selection needs fp32).
// ---------------------------------------------------------------------------
template<bool RELU, bool ACCUM>
__global__ void __launch_bounds__(256)
gemm_f32(const float* __restrict__ A, int lda,
         const float* __restrict__ B, int ldb,
         float* __restrict__ C, int ldc,
         int K, const float* __restrict__ bias)
{
    __shared__ float As[16][132];
    __shared__ float Bs[16][128];
    const int bx = blockIdx.x, by = blockIdx.y;
    const int tid = threadIdx.x;
    const int tx = tid & 15, ty = tid >> 4;

    float acc[8][8];
#pragma unroll
    for (int i = 0; i < 8; ++i)
#pragma unroll
        for (int j = 0; j < 8; ++j) acc[i][j] = 0.f;

    const float* Ablk = A + (size_t)(by * 128) * lda;
    const float* Bblk = B + bx * 128;

    for (int k0 = 0; k0 < K; k0 += 16) {
#pragma unroll
        for (int t = 0; t < 2; ++t) {
            int idx = tid + t * 256;
            int ar = idx >> 2, ac4 = idx & 3;
            float4 v = *(const float4*)(Ablk + (size_t)ar * lda + k0 + ac4 * 4);
            As[ac4 * 4 + 0][ar] = v.x;
            As[ac4 * 4 + 1][ar] = v.y;
            As[ac4 * 4 + 2][ar] = v.z;
            As[ac4 * 4 + 3][ar] = v.w;
        }
#pragma unroll
        for (int t = 0; t < 2; ++t) {
            int idx = tid + t * 256;
            int br = idx >> 5, bc4 = idx & 31;
            float4 v = *(const float4*)(Bblk + (size_t)(k0 + br) * ldb + bc4 * 4);
            *(float4*)&Bs[br][bc4 * 4] = v;
        }
        __syncthreads();
#pragma unroll
        for (int kk = 0; kk < 16; ++kk) {
            float4 a0 = *(const float4*)&As[kk][ty * 4];
            float4 a1 = *(const float4*)&As[kk][64 + ty * 4];
            float4 b0 = *(const float4*)&Bs[kk][tx * 4];
            float4 b1 = *(const float4*)&Bs[kk][64 + tx * 4];
            float av[8] = {a0.x, a0.y, a0.z, a0.w, a1.x, a1.y, a1.z, a1.w};
            float bv[8] = {b0.x, b0.y, b0.z, b0.w, b1.x, b1.y, b1.z, b1.w};
#pragma unroll
            for (int i = 0; i < 8; ++i)
#pragma unroll
                for (int j = 0; j < 8; ++j)
                    acc[i][j] = fmaf(av[i], bv[j], acc[i][j]);
        }
        __syncthreads();
    }

    float bias0[8];
    if (bias != nullptr) {
        float4 c0 = *(const float4*)(bias + bx * 128 + tx * 4);
        float4 c1 = *(const float4*)(bias + bx * 128 + 64 + tx * 4);
        bias0[0] = c0.x; bias0[1] = c0.y; bias0[2] = c0.z; bias0[3] = c0.w;
        bias0[4] = c1.x; bias0[5] = c1.y; bias0[6] = c1.z; bias0[7] = c1.w;
    } else {
#pragma unroll
        for (int j = 0; j < 8; ++j) bias0[j] = 0.f;
    }
#pragma unroll
    for (int i = 0; i < 8; ++i) {
        int row = by * 128 + ((i < 4) ? (ty * 4 + i) : (64 + ty * 4 + (i - 4)));
        float* crow = C + (size_t)row * ldc + bx * 128;
#pragma unroll
        for (int jh = 0; jh < 2; ++jh) {
            float4 v;
            v.x = acc[i][jh * 4 + 0] + bias0[jh * 4 + 0];
            v.y = acc[i][jh * 4 + 1] + bias0[jh * 4 + 1];
            v.z = acc[i][jh * 4 + 2] + bias0[jh * 4 + 2];
            v.w = acc[i][jh * 4 + 3] + bias0[jh * 4 + 3];
            if (RELU) {
                v.x = fmaxf(v.x, 0.f); v.y = fmaxf(v.y, 0.f);
                v.z = fmaxf(v.z, 0.f); v.w = fmaxf(v.w, 0.f);
            }
            float* p = crow + jh * 64 + tx * 4;
            if (ACCUM) {
                float4 o = *(float4*)p;
                v.x += o.x; v.y += o.y; v.z += o.z; v.w += o.w;
            }
            *(float4*)p = v;
        }
    }
}

// ---------------------------------------------------------------------------
// bf16 MFMA GEMM: C[M x N] = A[M x K](bf16) @ BT[N x K](bf16)^T, fp32 accum.
// 128x128 tile, BK=32, 4 waves (2x2 of 64x64), 16x16x32 MFMA.
// Staging: global_load_lds dwordx4 with source pre-swizzle matching the
// ds_read XOR swizzle (slot = kc ^ ((row>>1)&3)) -- both-sides rule.
// ---------------------------------------------------------------------------
template<bool OUTBF16, bool RELU, bool ACCUM>
__global__ void __launch_bounds__(256)
gemm_bf16(const unsigned short* __restrict__ A, int lda,
          const unsigned short* __restrict__ BT, int ldbt,
          void* __restrict__ Cp, int ldc, int K,
          const float* __restrict__ bias)
{
    __shared__ short As[4096];  // 128 rows x 32 k (8 KB), swizzled
    __shared__ short Bs[4096];
    const int tid = threadIdx.x;
    const int w = tid >> 6, l = tid & 63;
    const int bx = blockIdx.x, by = blockIdx.y;
    const int wm = w >> 1, wn = w & 1;

    f32x4 acc[4][4] = {};

    // per-lane staging sources (2 x 1KB chunks per wave per operand)
    const unsigned short* a_src[2];
    const unsigned short* b_src[2];
#pragma unroll
    for (int g = 0; g < 2; ++g) {
        int r = w * 32 + g * 16 + (l >> 2);          // tile row this lane fills
        int kc = (l & 3) ^ ((r >> 1) & 3);           // logical k-chunk for slot
        a_src[g] = A + (size_t)(by * 128 + r) * lda + kc * 8;
        b_src[g] = BT + (size_t)(bx * 128 + r) * ldbt + kc * 8;
    }
    short* As_w = As + w * 1024;   // 2048 B per wave
    short* Bs_w = Bs + w * 1024;

    const int lr = l & 15, lg = l >> 4;

    for (int k0 = 0; k0 < K; k0 += 32) {
        __syncthreads();
        gload_lds16(a_src[0] + k0, As_w);
        gload_lds16(a_src[1] + k0, As_w + 512);
        gload_lds16(b_src[0] + k0, Bs_w);
        gload_lds16(b_src[1] + k0, Bs_w + 512);
        __syncthreads();   // compiler drains vmcnt before barrier

        bf16x8 af[4], bg[4];
#pragma unroll
        for (int m = 0; m < 4; ++m) {
            int row = wm * 64 + m * 16 + lr;
            int off = row * 64 + ((lg ^ ((row >> 1) & 3)) << 4);
            af[m] = *(const bf16x8*)((const char*)As + off);
        }
#pragma unroll
        for (int n = 0; n < 4; ++n) {
            int row = wn * 64 + n * 16 + lr;
            int off = row * 64 + ((lg ^ ((row >> 1) & 3)) << 4);
            bg[n] = *(const bf16x8*)((const char*)Bs + off);
        }
#pragma unroll
        for (int m = 0; m < 4; ++m)
#pragma unroll
            for (int n = 0; n < 4; ++n)
                acc[m][n] = __builtin_amdgcn_mfma_f32_16x16x32_bf16(
                    af[m], bg[n], acc[m][n], 0, 0, 0);
    }

    float bcol[4];
#pragma unroll
    for (int n = 0; n < 4; ++n) {
        int colg = bx * 128 + wn * 64 + n * 16 + lr;
        bcol[n] = bias ? bias[colg] : 0.f;
    }
#pragma unroll
    for (int m = 0; m < 4; ++m) {
#pragma unroll
        for (int n = 0; n < 4; ++n) {
            int colg = bx * 128 + wn * 64 + n * 16 + lr;
#pragma unroll
            for (int r = 0; r < 4; ++r) {
                int rowg = by * 128 + wm * 64 + m * 16 + lg * 4 + r;
                float v = acc[m][n][r] + bcol[n];
                if (RELU) v = fmaxf(v, 0.f);
                if (OUTBF16) {
                    ((unsigned short*)Cp)[(size_t)rowg * ldc + colg] = f2bf(v);
                } else {
                    float* C = (float*)Cp;
                    if (ACCUM) v += C[(size_t)rowg * ldc + colg];
                    C[(size_t)rowg * ldc + colg] = v;
                }
            }
        }
    }
}

// ---------------------------------------------------------------------------
// Fused transpose + fp32->bf16: in[R][C] -> out[C][R].  grid (C/32, R/32).
// ---------------------------------------------------------------------------
__global__ void __launch_bounds__(256)
tconv(const float* __restrict__ in, int R, int C, unsigned short* __restrict__ out)
{
    __shared__ float t[32][33];
    const int bx = blockIdx.x * 32;  // col base
    const int by = blockIdx.y * 32;  // row base
    const int lx = threadIdx.x & 31, ly = threadIdx.x >> 5;
#pragma unroll
    for (int r = 0; r < 4; ++r)
        t[ly + r * 8][lx] = in[(size_t)(by + ly + r * 8) * C + bx + lx];
    __syncthreads();
#pragma unroll
    for (int r = 0; r < 4; ++r) {
        int oc = ly + r * 8;
        out[(size_t)(bx + oc) * R + by + lx] = f2bf(t[lx][oc]);
    }
}

// fp32 -> bf16 elementwise (4/thread)
__global__ void __launch_bounds__(256)
xcvt(const float* __restrict__ in, unsigned short* __restrict__ out)
{
    size_t i = ((size_t)blockIdx.x * 256 + threadIdx.x) * 4;
    float4 v = *(const float4*)(in + i);
    ushort4 o;
    o.x = f2bf(v.x); o.y = f2bf(v.y); o.z = f2bf(v.z); o.w = f2bf(v.w);
    *(ushort4*)(out + i) = o;
}

// ---------------------------------------------------------------------------
// M statistics (fp32, unchanged: selection precision)
// ---------------------------------------------------------------------------
__global__ void __launch_bounds__(256)
mstat_kernel(const float* __restrict__ Q, const float* __restrict__ K,
             const int* __restrict__ idxs, float* __restrict__ Mout)
{
    __shared__ float Qs[64][132];
    __shared__ float Ks[64][68];
    const int itile = blockIdx.x;
    const int bh = blockIdx.y;
    const int b = bh >> 4, h = bh & 15;
    const int tid = threadIdx.x;
    const int tx = tid & 15, ty = tid >> 4;
    const int i0 = itile * 128;

    const float* Qbase = Q + (size_t)bh * (L_SEQ * HD);
    const float* Kbase = K + (size_t)b * (L_SEQ * D_MODEL) + h * HD;

#pragma unroll
    for (int t = 0; t < 8; ++t) {
        int idx = tid + t * 256;
        int il = idx >> 4, c4 = idx & 15;
        float4 v = *(const float4*)(Qbase + (size_t)(i0 + il) * HD + c4 * 4);
        Qs[c4 * 4 + 0][il] = v.x;
        Qs[c4 * 4 + 1][il] = v.y;
        Qs[c4 * 4 + 2][il] = v.z;
        Qs[c4 * 4 + 3][il] = v.w;
    }

    float mx[8], sm[8];
#pragma unroll
    for (int i = 0; i < 8; ++i) { mx[i] = -FLT_MAX; sm[i] = 0.f; }

    for (int jt = 0; jt < 32; ++jt) {
        __syncthreads();
#pragma unroll
        for (int t = 0; t < 4; ++t) {
            int idx = tid + t * 256;
            int jl = idx >> 4, c4 = idx & 15;
            int js = idxs[jt * 64 + jl];
            float4 v = *(const float4*)(Kbase + (size_t)js * D_MODEL + c4 * 4);
            Ks[c4 * 4 + 0][jl] = v.x;
            Ks[c4 * 4 + 1][jl] = v.y;
            Ks[c4 * 4 + 2][jl] = v.z;
            Ks[c4 * 4 + 3][jl] = v.w;
        }
        __syncthreads();

        float accv[8][4];
#pragma unroll
        for (int i = 0; i < 8; ++i)
#pragma unroll
            for (int j = 0; j < 4; ++j) accv[i][j] = 0.f;

#pragma unroll 8
        for (int dd2 = 0; dd2 < 64; ++dd2) {
            float4 a0 = *(const float4*)&Qs[dd2][ty * 4];
            float4 a1 = *(const float4*)&Qs[dd2][64 + ty * 4];
            float4 bb = *(const float4*)&Ks[dd2][tx * 4];
            float av[8] = {a0.x, a0.y, a0.z, a0.w, a1.x, a1.y, a1.z, a1.w};
            float bv[4] = {bb.x, bb.y, bb.z, bb.w};
#pragma unroll
            for (int i = 0; i < 8; ++i)
#pragma unroll
                for (int j = 0; j < 4; ++j)
                    accv[i][j] = fmaf(av[i], bv[j], accv[i][j]);
        }
#pragma unroll
        for (int i = 0; i < 8; ++i)
#pragma unroll
            for (int j = 0; j < 4; ++j) {
                mx[i] = fmaxf(mx[i], accv[i][j]);
                sm[i] += accv[i][j];
            }
    }

    __syncthreads();
    float* redm = &Qs[0][0];
    float* reds = redm + 128 * 16;
#pragma unroll
    for (int i = 0; i < 8; ++i) {
        int row = (i < 4) ? (ty * 4 + i) : (64 + ty * 4 + (i - 4));
        redm[row * 16 + tx] = mx[i];
        reds[row * 16 + tx] = sm[i];
    }
    __syncthreads();
    if (tid < 128) {
        float m_ = -FLT_MAX, s_ = 0.f;
#pragma unroll
        for (int t2 = 0; t2 < 16; ++t2) {
            m_ = fmaxf(m_, redm[tid * 16 + t2]);
            s_ += reds[tid * 16 + t2];
        }
        Mout[(size_t)bh * L_SEQ + i0 + tid] = m_ - s_ * (1.0f / 2048.0f);
    }
}

// ---------------------------------------------------------------------------
// Top-40 smallest M per bh (lower-index tie-break).
// ---------------------------------------------------------------------------
__global__ void __launch_bounds__(256)
topk_kernel(const float* __restrict__ M, int* __restrict__ Mtop)
{
    __shared__ float mv[L_SEQ];
    __shared__ float wv_[4];
    __shared__ int wi_[4];
    const int bh = blockIdx.x;
    const int tid = threadIdx.x;
    for (int j = tid; j < L_SEQ; j += 256) mv[j] = M[(size_t)bh * L_SEQ + j];
    __syncthreads();
    for (int u = 0; u < U_TOP; ++u) {
        float best = FLT_MAX;
        int bi = 1 << 30;
        for (int j = tid; j < L_SEQ; j += 256) {
            float v = mv[j];
            if (v < best || (v == best && j < bi)) { best = v; bi = j; }
        }
#pragma unroll
        for (int off = 32; off; off >>= 1) {
            float ov = __shfl_down(best, off);
            int oi = __shfl_down(bi, off);
            if (ov < best || (ov == best && oi < bi)) { best = ov; bi = oi; }
        }
        if ((tid & 63) == 0) { wv_[tid >> 6] = best; wi_[tid >> 6] = bi; }
        __syncthreads();
        if (tid == 0) {
            for (int w = 1; w < 4; ++w)
                if (wv_[w] < best || (wv_[w] == best && wi_[w] < bi)) { best = wv_[w]; bi = wi_[w]; }
            Mtop[bh * U_TOP + u] = bi;
            mv[bi] = FLT_MAX;
        }
        __syncthreads();
    }
}

// ---------------------------------------------------------------------------
// Attention for the 40 selected rows (V in bf16, out scattered bf16).
// ---------------------------------------------------------------------------
__global__ void __launch_bounds__(256)
attn_kernel(const float* __restrict__ Q, const float* __restrict__ K,
            const unsigned short* __restrict__ V, const int* __restrict__ Mtop,
            unsigned short* __restrict__ ATT)
{
    __shared__ float Ks[128][65];
    __shared__ float qs[64];
    __shared__ float ps[128];
    __shared__ float wred[4];
    __shared__ float fred[256];
    const int u = blockIdx.x, bh = blockIdx.y;
    const int b = bh >> 4, h = bh & 15;
    const int tid = threadIdx.x;
    const int lsel = Mtop[bh * U_TOP + u];

    if (tid < 64)
        qs[tid] = Q[(size_t)bh * (L_SEQ * HD) + (size_t)lsel * HD + tid] * 0.125f;

    const float* Kbase = K + (size_t)b * (L_SEQ * D_MODEL) + h * HD;
    const unsigned short* Vbase = V + (size_t)b * (L_SEQ * D_MODEL) + h * HD;

    float m_run = -FLT_MAX, l_run = 0.f, accv = 0.f;
    const int ddl = tid & 63, jg = tid >> 6;

    for (int t = 0; t < 16; ++t) {
        const int j0 = t * 128;
        __syncthreads();
#pragma unroll
        for (int q4 = 0; q4 < 8; ++q4) {
            int idx = tid + q4 * 256;
            int jl = idx >> 4, c4 = idx & 15;
            float4 v = *(const float4*)(Kbase + (size_t)(j0 + jl) * D_MODEL + c4 * 4);
            Ks[jl][c4 * 4 + 0] = v.x;
            Ks[jl][c4 * 4 + 1] = v.y;
            Ks[jl][c4 * 4 + 2] = v.z;
            Ks[jl][c4 * 4 + 3] = v.w;
        }
        __syncthreads();
        if (tid < 128) {
            float s = 0.f;
#pragma unroll 16
            for (int c = 0; c < 64; ++c) s = fmaf(qs[c], Ks[tid][c], s);
            ps[tid] = s;
        }
        __syncthreads();
        float v_ = (tid < 128) ? ps[tid] : -FLT_MAX;
#pragma unroll
        for (int off = 32; off; off >>= 1) v_ = fmaxf(v_, __shfl_down(v_, off));
        if ((tid & 63) == 0) wred[tid >> 6] = v_;
        __syncthreads();
        float mt = fmaxf(fmaxf(wred[0], wred[1]), fmaxf(wred[2], wred[3]));
        float m_new = fmaxf(m_run, mt);
        float r = expf(m_run - m_new);
        if (tid < 128) ps[tid] = expf(ps[tid] - m_new);
        __syncthreads();
        float sv = (tid < 128) ? ps[tid] : 0.f;
#pragma unroll
        for (int off = 32; off; off >>= 1) sv += __shfl_down(sv, off);
        if ((tid & 63) == 0) wred[tid >> 6] = sv;
        __syncthreads();
        float lt = wred[0] + wred[1] + wred[2] + wred[3];
        l_run = l_run * r + lt;
        m_run = m_new;
        float a2 = accv * r;
#pragma unroll 8
        for (int jj = 0; jj < 32; ++jj) {
            int j = jg * 32 + jj;
            a2 = fmaf(ps[j], bf2f(Vbase[(size_t)(j0 + j) * D_MODEL + ddl]), a2);
        }
        accv = a2;
    }
    fred[tid] = accv;
    __syncthreads();
    if (tid < 64) {
        float o = (fred[tid] + fred[tid + 64] + fred[tid + 128] + fred[tid + 192]) / l_run;
        ATT[((size_t)b * L_SEQ + lsel) * D_MODEL + h * HD + tid] = f2bf(o);
    }
}

// ---------------------------------------------------------------------------
// Fused residual + LayerNorm (optionally also emits bf16 copy).
// ---------------------------------------------------------------------------
template<bool WB16>
__global__ void __launch_bounds__(256)
ln_kernel(const float* __restrict__ X, const float* __restrict__ A,
          const float* __restrict__ g, const float* __restrict__ be,
          float* __restrict__ out, unsigned short* __restrict__ out16)
{
    __shared__ float wred[4];
    const int row = blockIdx.x, tid = threadIdx.x;
    float4 xv = *(const float4*)(X + (size_t)row * D_MODEL + tid * 4);
    float4 av = *(const float4*)(A + (size_t)row * D_MODEL + tid * 4);
    float v0 = xv.x + av.x, v1 = xv.y + av.y, v2 = xv.z + av.z, v3 = xv.w + av.w;

    float s = v0 + v1 + v2 + v3;
#pragma unroll
    for (int off = 32; off; off >>= 1) s += __shfl_down(s, off);
    if ((tid & 63) == 0) wred[tid >> 6] = s;
    __syncthreads();
    float mean = (wred[0] + wred[1] + wred[2] + wred[3]) * (1.f / 1024.f);
    __syncthreads();

    float d0 = v0 - mean, d1 = v1 - mean, d2 = v2 - mean, d3 = v3 - mean;
    float q = d0 * d0 + d1 * d1 + d2 * d2 + d3 * d3;
#pragma unroll
    for (int off = 32; off; off >>= 1) q += __shfl_down(q, off);
    if ((tid & 63) == 0) wred[tid >> 6] = q;
    __syncthreads();
    float var = (wred[0] + wred[1] + wred[2] + wred[3]) * (1.f / 1024.f);
    float rstd = rsqrtf(var + 1e-12f);

    float4 gv = *(const float4*)(g + tid * 4);
    float4 bv = *(const float4*)(be + tid * 4);
    float4 o;
    o.x = gv.x * d0 * rstd + bv.x;
    o.y = gv.y * d1 * rstd + bv.y;
    o.z = gv.z * d2 * rstd + bv.z;
    o.w = gv.w * d3 * rstd + bv.w;
    *(float4*)(out + (size_t)row * D_MODEL + tid * 4) = o;
    if (WB16) {
        ushort4 ob;
        ob.x = f2bf(o.x); ob.y = f2bf(o.y); ob.z = f2bf(o.z); ob.w = f2bf(o.w);
        *(ushort4*)(out16 + (size_t)row * D_MODEL + tid * 4) = ob;
    }
}

// ---------------------------------------------------------------------------
extern "C" void kernel_launch(void* const* d_in, const int* in_sizes, int n_in,
                              void* d_out, int out_size, void* d_ws, size_t ws_size,
                              hipStream_t stream)
{
    const float* x   = (const float*)d_in[0];
    const float* wq  = (const float*)d_in[1];
    const float* bq  = (const float*)d_in[2];
    const float* wk  = (const float*)d_in[3];
    const float* bk  = (const float*)d_in[4];
    const float* wv  = (const float*)d_in[5];
    const float* bv  = (const float*)d_in[6];
    const float* wo  = (const float*)d_in[7];
    const float* bo  = (const float*)d_in[8];
    const float* w1  = (const float*)d_in[9];
    const float* b1  = (const float*)d_in[10];
    const float* w2  = (const float*)d_in[11];
    const float* b2  = (const float*)d_in[12];
    const float* g1  = (const float*)d_in[13];
    const float* be1 = (const float*)d_in[14];
    const float* g2  = (const float*)d_in[15];
    const float* be2 = (const float*)d_in[16];
    const int*  idxs = (const int*)d_in[17];

    char* ws = (char*)d_ws;
    const size_t MB = 1u << 20;
    // live ranges annotated; peak usage ~116.6 MB (< round-1's proven 128.5)
    float* Qb            = (float*)(ws);                       // [proj..attn]
    float* x1f           = (float*)(ws);                       // [ln1..ln2]
    float* Kb            = (float*)(ws + 32 * MB);             // [proj..attn]
    float* Ab            = (float*)(ws + 32 * MB);             // [wo-gemm..ln1]
    unsigned short* w1T  = (unsigned short*)(ws + 32 * MB);    // [post-ln1..ffn]
    unsigned short* w2T  = (unsigned short*)(ws + 40 * MB);    // [post-ln1..ffn]
    unsigned short* Vb   = (unsigned short*)(ws + 64 * MB);    // [wv..attn]
    unsigned short* HIDb = (unsigned short*)(ws + 64 * MB);    // [ffn]
    unsigned short* xb   = (unsigned short*)(ws + 80 * MB);    // [cvt..wv]
    unsigned short* x1b  = (unsigned short*)(ws + 80 * MB);    // [ln1..ffn]
    unsigned short* ATTb = (unsigned short*)(ws + 96 * MB);    // [attn..wo]
    unsigned short* wvT  = (unsigned short*)(ws + 112 * MB);
    unsigned short* woT  = (unsigned short*)(ws + 114 * MB);
    float* Mb            = (float*)(ws + 116 * MB);
    int*   Mtop          = (int*)(ws + 116 * MB + 512 * 1024);
    float* F             = (float*)d_out;                      // FFN accum

    dim3 blk(256);
    dim3 g_gemm(8, 64);

    // input conversions / weight transposes needed early
    xcvt<<<dim3(8192), blk, 0, stream>>>(x, xb);
    tconv<<<dim3(32, 32), blk, 0, stream>>>(wv, 1024, 1024, wvT);
    tconv<<<dim3(32, 32), blk, 0, stream>>>(wo, 1024, 1024, woT);

    // q/k projections in fp32 (selection precision), v in bf16 MFMA
    gemm_f32<false, false><<<g_gemm, blk, 0, stream>>>(x, 1024, wq, 1024, Qb, 1024, 1024, bq);
    gemm_f32<false, false><<<g_gemm, blk, 0, stream>>>(x, 1024, wk, 1024, Kb, 1024, 1024, bk);
    gemm_bf16<true, false, false><<<g_gemm, blk, 0, stream>>>(xb, 1024, wvT, 1024, Vb, 1024, 1024, bv);

    // selection
    mstat_kernel<<<dim3(16, 64), blk, 0, stream>>>(Qb, Kb, idxs, Mb);
    topk_kernel<<<dim3(64), blk, 0, stream>>>(Mb, Mtop);

    // sparse attention -> scattered bf16 ATT
    hipMemsetAsync(ATTb, 0, 16 * MB, stream);
    attn_kernel<<<dim3(U_TOP, N_BH), blk, 0, stream>>>(Qb, Kb, Vb, Mtop, ATTb);

    // output projection (bf16 MFMA) + LN1
    gemm_bf16<false, false, false><<<g_gemm, blk, 0, stream>>>(ATTb, 1024, woT, 1024, Ab, 1024, 1024, bo);
    ln_kernel<true><<<dim3(8192), blk, 0, stream>>>(x, Ab, g1, be1, x1f, x1b);

    // FFN weights transposed now (Ab region is dead)
    tconv<<<dim3(128, 32), blk, 0, stream>>>(w1, 1024, 4096, w1T);
    tconv<<<dim3(32, 128), blk, 0, stream>>>(w2, 4096, 1024, w2T);

    // FFN, chunked over F dim (4 x 1024), bf16 MFMA both GEMMs
    for (int c = 0; c < 4; ++c) {
        gemm_bf16<true, true, false><<<g_gemm, blk, 0, stream>>>(
            x1b, 1024, w1T + (size_t)c * 1024 * 1024, 1024, HIDb, 1024, 1024, b1 + c * 1024);
        if (c == 0)
            gemm_bf16<false, false, false><<<g_gemm, blk, 0, stream>>>(
                HIDb, 1024, w2T + c * 1024, 4096, F, 1024, 1024, b2);
        else
            gemm_bf16<false, false, true><<<g_gemm, blk, 0, stream>>>(
                HIDb, 1024, w2T + c * 1024, 4096, F, 1024, 1024, nullptr);
    }

    // out = LN(x1 + F)   (F lives in d_out; in-place row-wise is safe)
    ln_kernel<false><<<dim3(8192), blk, 0, stream>>>(x1f, F, g2, be2, (float*)d_out, nullptr);
}

// Round 3
// 1059.403 us; speedup vs baseline: 3.0720x; 1.5927x over previous
//
#include <hip/hip_runtime.h>
#include <float.h>
#include <math.h>

#define L_SEQ 2048
#define D_MODEL 1024
#define N_HEAD 16
#define HD 64
#define N_BH 64
#define U_TOP 40

using bf16x8 = __attribute__((ext_vector_type(8))) short;
using f32x4  = __attribute__((ext_vector_type(4))) float;

__device__ __forceinline__ unsigned short f2bf(float f) {
    unsigned int u = __builtin_bit_cast(unsigned int, f);
    u += 0x7fff + ((u >> 16) & 1);   // round-to-nearest-even
    return (unsigned short)(u >> 16);
}
__device__ __forceinline__ float bf2f(unsigned short h) {
    unsigned int u = ((unsigned int)h) << 16;
    return __builtin_bit_cast(float, u);
}

__device__ __forceinline__ void gload_lds16(const void* g, void* l) {
    __builtin_amdgcn_global_load_lds(
        (const __attribute__((address_space(1))) unsigned int*)g,
        (__attribute__((address_space(3))) unsigned int*)l, 16, 0, 0);
}

// ---------------------------------------------------------------------------
// bf16 MFMA GEMM: C = A(bf16) @ BT(bf16)^T, fp32 accum. 128x128 tile, BK=32.
// ---------------------------------------------------------------------------
template<bool OUTBF16, bool RELU, bool ACCUM>
__global__ void __launch_bounds__(256)
gemm_bf16(const unsigned short* __restrict__ A, int lda,
          const unsigned short* __restrict__ BT, int ldbt,
          void* __restrict__ Cp, int ldc, int K,
          const float* __restrict__ bias)
{
    __shared__ short As[4096];
    __shared__ short Bs[4096];
    const int tid = threadIdx.x;
    const int w = tid >> 6, l = tid & 63;
    const int bx = blockIdx.x, by = blockIdx.y;
    const int wm = w >> 1, wn = w & 1;

    f32x4 acc[4][4] = {};

    const unsigned short* a_src[2];
    const unsigned short* b_src[2];
#pragma unroll
    for (int g = 0; g < 2; ++g) {
        int r = w * 32 + g * 16 + (l >> 2);
        int kc = (l & 3) ^ ((r >> 1) & 3);
        a_src[g] = A + (size_t)(by * 128 + r) * lda + kc * 8;
        b_src[g] = BT + (size_t)(bx * 128 + r) * ldbt + kc * 8;
    }
    short* As_w = As + w * 1024;
    short* Bs_w = Bs + w * 1024;

    const int lr = l & 15, lg = l >> 4;

    for (int k0 = 0; k0 < K; k0 += 32) {
        __syncthreads();
        gload_lds16(a_src[0] + k0, As_w);
        gload_lds16(a_src[1] + k0, As_w + 512);
        gload_lds16(b_src[0] + k0, Bs_w);
        gload_lds16(b_src[1] + k0, Bs_w + 512);
        __syncthreads();

        bf16x8 af[4], bg[4];
#pragma unroll
        for (int m = 0; m < 4; ++m) {
            int row = wm * 64 + m * 16 + lr;
            int off = row * 64 + ((lg ^ ((row >> 1) & 3)) << 4);
            af[m] = *(const bf16x8*)((const char*)As + off);
        }
#pragma unroll
        for (int n = 0; n < 4; ++n) {
            int row = wn * 64 + n * 16 + lr;
            int off = row * 64 + ((lg ^ ((row >> 1) & 3)) << 4);
            bg[n] = *(const bf16x8*)((const char*)Bs + off);
        }
#pragma unroll
        for (int m = 0; m < 4; ++m)
#pragma unroll
            for (int n = 0; n < 4; ++n)
                acc[m][n] = __builtin_amdgcn_mfma_f32_16x16x32_bf16(
                    af[m], bg[n], acc[m][n], 0, 0, 0);
    }

    float bcol[4];
#pragma unroll
    for (int n = 0; n < 4; ++n) {
        int colg = bx * 128 + wn * 64 + n * 16 + lr;
        bcol[n] = bias ? bias[colg] : 0.f;
    }
#pragma unroll
    for (int m = 0; m < 4; ++m) {
#pragma unroll
        for (int n = 0; n < 4; ++n) {
            int colg = bx * 128 + wn * 64 + n * 16 + lr;
#pragma unroll
            for (int r = 0; r < 4; ++r) {
                int rowg = by * 128 + wm * 64 + m * 16 + lg * 4 + r;
                float v = acc[m][n][r] + bcol[n];
                if (RELU) v = fmaxf(v, 0.f);
                if (OUTBF16) {
                    ((unsigned short*)Cp)[(size_t)rowg * ldc + colg] = f2bf(v);
                } else {
                    float* C = (float*)Cp;
                    if (ACCUM) v += C[(size_t)rowg * ldc + colg];
                    C[(size_t)rowg * ldc + colg] = v;
                }
            }
        }
    }
}

// ---------------------------------------------------------------------------
// Split-bf16 GEMM (fp32-accurate): C = (Ah+Al) @ (BhT+BlT)^T + bias, with
// 3 MFMAs per tile (hh + hl + lh). Output written as split bf16 (hi, lo).
// Used for the q/k projections feeding top-k selection.
// ---------------------------------------------------------------------------
__global__ void __launch_bounds__(256)
gemm_bf16_split(const unsigned short* __restrict__ Ah,
                const unsigned short* __restrict__ Al, int lda,
                const unsigned short* __restrict__ BhT,
                const unsigned short* __restrict__ BlT, int ldbt,
                unsigned short* __restrict__ Ch,
                unsigned short* __restrict__ Cl, int ldc, int K,
                const float* __restrict__ bias)
{
    __shared__ short Ash[4096], Asl[4096], Bsh[4096], Bsl[4096];
    const int tid = threadIdx.x;
    const int w = tid >> 6, l = tid & 63;
    const int bx = blockIdx.x, by = blockIdx.y;
    const int wm = w >> 1, wn = w & 1;

    f32x4 acc[4][4] = {};

    size_t a_off[2], b_off[2];
#pragma unroll
    for (int g = 0; g < 2; ++g) {
        int r = w * 32 + g * 16 + (l >> 2);
        int kc = (l & 3) ^ ((r >> 1) & 3);
        a_off[g] = (size_t)(by * 128 + r) * lda + kc * 8;
        b_off[g] = (size_t)(bx * 128 + r) * ldbt + kc * 8;
    }
    const int wb = w * 1024;
    const int lr = l & 15, lg = l >> 4;

    for (int k0 = 0; k0 < K; k0 += 32) {
        __syncthreads();
#pragma unroll
        for (int g = 0; g < 2; ++g) {
            gload_lds16(Ah + a_off[g] + k0, Ash + wb + g * 512);
            gload_lds16(Al + a_off[g] + k0, Asl + wb + g * 512);
            gload_lds16(BhT + b_off[g] + k0, Bsh + wb + g * 512);
            gload_lds16(BlT + b_off[g] + k0, Bsl + wb + g * 512);
        }
        __syncthreads();

        bf16x8 afh[4], afl[4], bgh[4], bgl[4];
#pragma unroll
        for (int m = 0; m < 4; ++m) {
            int row = wm * 64 + m * 16 + lr;
            int off = row * 64 + ((lg ^ ((row >> 1) & 3)) << 4);
            afh[m] = *(const bf16x8*)((const char*)Ash + off);
            afl[m] = *(const bf16x8*)((const char*)Asl + off);
        }
#pragma unroll
        for (int n = 0; n < 4; ++n) {
            int row = wn * 64 + n * 16 + lr;
            int off = row * 64 + ((lg ^ ((row >> 1) & 3)) << 4);
            bgh[n] = *(const bf16x8*)((const char*)Bsh + off);
            bgl[n] = *(const bf16x8*)((const char*)Bsl + off);
        }
#pragma unroll
        for (int m = 0; m < 4; ++m)
#pragma unroll
            for (int n = 0; n < 4; ++n) {
                acc[m][n] = __builtin_amdgcn_mfma_f32_16x16x32_bf16(
                    afh[m], bgh[n], acc[m][n], 0, 0, 0);
                acc[m][n] = __builtin_amdgcn_mfma_f32_16x16x32_bf16(
                    afh[m], bgl[n], acc[m][n], 0, 0, 0);
                acc[m][n] = __builtin_amdgcn_mfma_f32_16x16x32_bf16(
                    afl[m], bgh[n], acc[m][n], 0, 0, 0);
            }
    }

    float bcol[4];
#pragma unroll
    for (int n = 0; n < 4; ++n)
        bcol[n] = bias[bx * 128 + wn * 64 + n * 16 + lr];
#pragma unroll
    for (int m = 0; m < 4; ++m)
#pragma unroll
        for (int n = 0; n < 4; ++n) {
            int colg = bx * 128 + wn * 64 + n * 16 + lr;
#pragma unroll
            for (int r = 0; r < 4; ++r) {
                int rowg = by * 128 + wm * 64 + m * 16 + lg * 4 + r;
                float v = acc[m][n][r] + bcol[n];
                unsigned short hh = f2bf(v);
                unsigned short ll = f2bf(v - bf2f(hh));
                Ch[(size_t)rowg * ldc + colg] = hh;
                Cl[(size_t)rowg * ldc + colg] = ll;
            }
        }
}

// ---------------------------------------------------------------------------
// MFMA M-stat: M[bh][i] = max_j(q_i.Ks_j) - sum_j(q_i.Ks_j)/2048, split-bf16.
// Block = (itile of 128 queries, bh). Q tile LDS-resident (row&7 XOR swizzle,
// d=128B rows). K_sample gathered per j-tile of 64 via per-lane-src gload_lds.
// ---------------------------------------------------------------------------
__global__ void __launch_bounds__(256)
mstat_mfma(const unsigned short* __restrict__ Qh, const unsigned short* __restrict__ Ql,
           const unsigned short* __restrict__ Kh, const unsigned short* __restrict__ Kl,
           const int* __restrict__ idxs, float* __restrict__ Mout)
{
    __shared__ short Qs[2][8192];   // [hi/lo][128 rows x 64], 32 KB
    __shared__ short Ks[2][4096];   // [hi/lo][ 64 rows x 64], 16 KB
    const int tid = threadIdx.x, w = tid >> 6, l = tid & 63;
    const int itile = blockIdx.x, bh = blockIdx.y;
    const int b = bh >> 4, h = bh & 15;
    const int i0 = itile * 128;
    const int lr = l & 15, lg = l >> 4;

    // ---- stage Q tile once (16 gloads per half, 4+4 per wave) ----
#pragma unroll
    for (int g = w * 4; g < w * 4 + 4; ++g) {
        int row = g * 8 + (l >> 3);
        int kc = (l & 7) ^ (row & 7);
        size_t src = (size_t)(bh * L_SEQ + i0 + row) * HD + kc * 8;
        gload_lds16(Qh + src, (char*)&Qs[0][0] + g * 1024);
        gload_lds16(Ql + src, (char*)&Qs[1][0] + g * 1024);
    }
    __syncthreads();

    // hoist A-fragments (Q) into registers: [m][kstep][hi/lo]
    bf16x8 af[2][2][2];
#pragma unroll
    for (int m = 0; m < 2; ++m) {
        int row = (w * 2 + m) * 16 + lr;
#pragma unroll
        for (int k = 0; k < 2; ++k) {
            int c = k * 4 + lg;
            int off = row * 128 + ((c ^ (row & 7)) << 4);
            af[m][k][0] = *(const bf16x8*)((const char*)&Qs[0][0] + off);
            af[m][k][1] = *(const bf16x8*)((const char*)&Qs[1][0] + off);
        }
    }

    float mx[2][4], sm[2][4];
#pragma unroll
    for (int m = 0; m < 2; ++m)
#pragma unroll
        for (int r = 0; r < 4; ++r) { mx[m][r] = -FLT_MAX; sm[m][r] = 0.f; }

    for (int jt = 0; jt < 32; ++jt) {
        const int j0 = jt * 64;
        __syncthreads();
        // gather 64 sampled K rows (wave w: rows w*16..w*16+15)
#pragma unroll
        for (int g = 2 * w; g <= 2 * w + 1; ++g) {
            int row = g * 8 + (l >> 3);
            int kc = (l & 7) ^ (row & 7);
            int gr = idxs[j0 + row];
            size_t src = (size_t)(b * L_SEQ + gr) * D_MODEL + h * HD + kc * 8;
            gload_lds16(Kh + src, (char*)&Ks[0][0] + g * 1024);
            gload_lds16(Kl + src, (char*)&Ks[1][0] + g * 1024);
        }
        __syncthreads();

        bf16x8 bgh[4][2], bgl[4][2];
#pragma unroll
        for (int n = 0; n < 4; ++n) {
            int row = n * 16 + lr;
#pragma unroll
            for (int k = 0; k < 2; ++k) {
                int c = k * 4 + lg;
                int off = row * 128 + ((c ^ (row & 7)) << 4);
                bgh[n][k] = *(const bf16x8*)((const char*)&Ks[0][0] + off);
                bgl[n][k] = *(const bf16x8*)((const char*)&Ks[1][0] + off);
            }
        }
#pragma unroll
        for (int m = 0; m < 2; ++m) {
            f32x4 a0[4];
#pragma unroll
            for (int n = 0; n < 4; ++n) {
                f32x4 a = {};
                a = __builtin_amdgcn_mfma_f32_16x16x32_bf16(af[m][0][0], bgh[n][0], a, 0, 0, 0);
                a = __builtin_amdgcn_mfma_f32_16x16x32_bf16(af[m][0][0], bgl[n][0], a, 0, 0, 0);
                a = __builtin_amdgcn_mfma_f32_16x16x32_bf16(af[m][0][1], bgh[n][0], a, 0, 0, 0);
                a = __builtin_amdgcn_mfma_f32_16x16x32_bf16(af[m][1][0], bgh[n][1], a, 0, 0, 0);
                a = __builtin_amdgcn_mfma_f32_16x16x32_bf16(af[m][1][0], bgl[n][1], a, 0, 0, 0);
                a = __builtin_amdgcn_mfma_f32_16x16x32_bf16(af[m][1][1], bgh[n][1], a, 0, 0, 0);
                a0[n] = a;
            }
#pragma unroll
            for (int r = 0; r < 4; ++r) {
                float vmax = fmaxf(fmaxf(a0[0][r], a0[1][r]), fmaxf(a0[2][r], a0[3][r]));
                float vsum = (a0[0][r] + a0[1][r]) + (a0[2][r] + a0[3][r]);
                mx[m][r] = fmaxf(mx[m][r], vmax);
                sm[m][r] += vsum;
            }
        }
    }

    // cross-lane reduce over the 16 cols held by each 16-lane group
#pragma unroll
    for (int m = 0; m < 2; ++m)
#pragma unroll
        for (int r = 0; r < 4; ++r) {
            float a = mx[m][r], s = sm[m][r];
#pragma unroll
            for (int mask = 1; mask < 16; mask <<= 1) {
                a = fmaxf(a, __shfl_xor(a, mask));
                s += __shfl_xor(s, mask);
            }
            if (lr == 0) {
                int row = i0 + (w * 2 + m) * 16 + lg * 4 + r;
                Mout[(size_t)bh * L_SEQ + row] = a - s * (1.0f / 2048.0f);
            }
        }
}

// ---------------------------------------------------------------------------
// transpose + fp32->bf16 (single and split variants)
// ---------------------------------------------------------------------------
__global__ void __launch_bounds__(256)
tconv(const float* __restrict__ in, int R, int C, unsigned short* __restrict__ out)
{
    __shared__ float t[32][33];
    const int bx = blockIdx.x * 32;
    const int by = blockIdx.y * 32;
    const int lx = threadIdx.x & 31, ly = threadIdx.x >> 5;
#pragma unroll
    for (int r = 0; r < 4; ++r)
        t[ly + r * 8][lx] = in[(size_t)(by + ly + r * 8) * C + bx + lx];
    __syncthreads();
#pragma unroll
    for (int r = 0; r < 4; ++r) {
        int oc = ly + r * 8;
        out[(size_t)(bx + oc) * R + by + lx] = f2bf(t[lx][oc]);
    }
}

__global__ void __launch_bounds__(256)
tconv_split(const float* __restrict__ in, int R, int C,
            unsigned short* __restrict__ outh, unsigned short* __restrict__ outl)
{
    __shared__ float t[32][33];
    const int bx = blockIdx.x * 32;
    const int by = blockIdx.y * 32;
    const int lx = threadIdx.x & 31, ly = threadIdx.x >> 5;
#pragma unroll
    for (int r = 0; r < 4; ++r)
        t[ly + r * 8][lx] = in[(size_t)(by + ly + r * 8) * C + bx + lx];
    __syncthreads();
#pragma unroll
    for (int r = 0; r < 4; ++r) {
        int oc = ly + r * 8;
        float f = t[lx][oc];
        unsigned short hh = f2bf(f);
        outh[(size_t)(bx + oc) * R + by + lx] = hh;
        outl[(size_t)(bx + oc) * R + by + lx] = f2bf(f - bf2f(hh));
    }
}

// fp32 -> split bf16 elementwise
__global__ void __launch_bounds__(256)
split_f32(const float* __restrict__ in, unsigned short* __restrict__ hi,
          unsigned short* __restrict__ lo)
{
    size_t i = ((size_t)blockIdx.x * 256 + threadIdx.x) * 4;
    float4 v = *(const float4*)(in + i);
    ushort4 h, l2;
    h.x = f2bf(v.x); l2.x = f2bf(v.x - bf2f(h.x));
    h.y = f2bf(v.y); l2.y = f2bf(v.y - bf2f(h.y));
    h.z = f2bf(v.z); l2.z = f2bf(v.z - bf2f(h.z));
    h.w = f2bf(v.w); l2.w = f2bf(v.w - bf2f(h.w));
    *(ushort4*)(hi + i) = h;
    *(ushort4*)(lo + i) = l2;
}

// ---------------------------------------------------------------------------
// Top-40 smallest M per bh (lower-index tie-break).
// ---------------------------------------------------------------------------
__global__ void __launch_bounds__(256)
topk_kernel(const float* __restrict__ M, int* __restrict__ Mtop)
{
    __shared__ float mv[L_SEQ];
    __shared__ float wv_[4];
    __shared__ int wi_[4];
    const int bh = blockIdx.x;
    const int tid = threadIdx.x;
    for (int j = tid; j < L_SEQ; j += 256) mv[j] = M[(size_t)bh * L_SEQ + j];
    __syncthreads();
    for (int u = 0; u < U_TOP; ++u) {
        float best = FLT_MAX;
        int bi = 1 << 30;
        for (int j = tid; j < L_SEQ; j += 256) {
            float v = mv[j];
            if (v < best || (v == best && j < bi)) { best = v; bi = j; }
        }
#pragma unroll
        for (int off = 32; off; off >>= 1) {
            float ov = __shfl_down(best, off);
            int oi = __shfl_down(bi, off);
            if (ov < best || (ov == best && oi < bi)) { best = ov; bi = oi; }
        }
        if ((tid & 63) == 0) { wv_[tid >> 6] = best; wi_[tid >> 6] = bi; }
        __syncthreads();
        if (tid == 0) {
            for (int w = 1; w < 4; ++w)
                if (wv_[w] < best || (wv_[w] == best && wi_[w] < bi)) { best = wv_[w]; bi = wi_[w]; }
            Mtop[bh * U_TOP + u] = bi;
            mv[bi] = FLT_MAX;
        }
        __syncthreads();
    }
}

// ---------------------------------------------------------------------------
// Attention for the 40 selected rows. Q,K recombined from split bf16.
// ---------------------------------------------------------------------------
__global__ void __launch_bounds__(256)
attn_kernel(const unsigned short* __restrict__ Qh, const unsigned short* __restrict__ Ql,
            const unsigned short* __restrict__ Kh, const unsigned short* __restrict__ Kl,
            const unsigned short* __restrict__ V, const int* __restrict__ Mtop,
            unsigned short* __restrict__ ATT)
{
    __shared__ float Ks[128][65];
    __shared__ float qs[64];
    __shared__ float ps[128];
    __shared__ float wred[4];
    __shared__ float fred[256];
    const int u = blockIdx.x, bh = blockIdx.y;
    const int b = bh >> 4, h = bh & 15;
    const int tid = threadIdx.x;
    const int lsel = Mtop[bh * U_TOP + u];

    if (tid < 64) {
        size_t qi = (size_t)bh * (L_SEQ * HD) + (size_t)lsel * HD + tid;
        qs[tid] = (bf2f(Qh[qi]) + bf2f(Ql[qi])) * 0.125f;
    }

    const size_t kb = (size_t)b * (L_SEQ * D_MODEL) + h * HD;
    const unsigned short* Vbase = V + kb;

    float m_run = -FLT_MAX, l_run = 0.f, accv = 0.f;
    const int ddl = tid & 63, jg = tid >> 6;

    for (int t = 0; t < 16; ++t) {
        const int j0 = t * 128;
        __syncthreads();
#pragma unroll
        for (int q4 = 0; q4 < 8; ++q4) {
            int idx = tid + q4 * 256;
            int jl = idx >> 4, c4 = idx & 15;
            size_t src = kb + (size_t)(j0 + jl) * D_MODEL + c4 * 4;
            ushort4 vh = *(const ushort4*)(Kh + src);
            ushort4 vl = *(const ushort4*)(Kl + src);
            Ks[jl][c4 * 4 + 0] = bf2f(vh.x) + bf2f(vl.x);
            Ks[jl][c4 * 4 + 1] = bf2f(vh.y) + bf2f(vl.y);
            Ks[jl][c4 * 4 + 2] = bf2f(vh.z) + bf2f(vl.z);
            Ks[jl][c4 * 4 + 3] = bf2f(vh.w) + bf2f(vl.w);
        }
        __syncthreads();
        if (tid < 128) {
            float s = 0.f;
#pragma unroll 16
            for (int c = 0; c < 64; ++c) s = fmaf(qs[c], Ks[tid][c], s);
            ps[tid] = s;
        }
        __syncthreads();
        float v_ = (tid < 128) ? ps[tid] : -FLT_MAX;
#pragma unroll
        for (int off = 32; off; off >>= 1) v_ = fmaxf(v_, __shfl_down(v_, off));
        if ((tid & 63) == 0) wred[tid >> 6] = v_;
        __syncthreads();
        float mt = fmaxf(fmaxf(wred[0], wred[1]), fmaxf(wred[2], wred[3]));
        float m_new = fmaxf(m_run, mt);
        float r = expf(m_run - m_new);
        if (tid < 128) ps[tid] = expf(ps[tid] - m_new);
        __syncthreads();
        float sv = (tid < 128) ? ps[tid] : 0.f;
#pragma unroll
        for (int off = 32; off; off >>= 1) sv += __shfl_down(sv, off);
        if ((tid & 63) == 0) wred[tid >> 6] = sv;
        __syncthreads();
        float lt = wred[0] + wred[1] + wred[2] + wred[3];
        l_run = l_run * r + lt;
        m_run = m_new;
        float a2 = accv * r;
#pragma unroll 8
        for (int jj = 0; jj < 32; ++jj) {
            int j = jg * 32 + jj;
            a2 = fmaf(ps[j], bf2f(Vbase[(size_t)(j0 + j) * D_MODEL + ddl]), a2);
        }
        accv = a2;
    }
    fred[tid] = accv;
    __syncthreads();
    if (tid < 64) {
        float o = (fred[tid] + fred[tid + 64] + fred[tid + 128] + fred[tid + 192]) / l_run;
        ATT[((size_t)b * L_SEQ + lsel) * D_MODEL + h * HD + tid] = f2bf(o);
    }
}

// ---------------------------------------------------------------------------
// Fused residual + LayerNorm (optionally also emits bf16 copy).
// ---------------------------------------------------------------------------
template<bool WB16>
__global__ void __launch_bounds__(256)
ln_kernel(const float* __restrict__ X, const float* __restrict__ A,
          const float* __restrict__ g, const float* __restrict__ be,
          float* __restrict__ out, unsigned short* __restrict__ out16)
{
    __shared__ float wred[4];
    const int row = blockIdx.x, tid = threadIdx.x;
    float4 xv = *(const float4*)(X + (size_t)row * D_MODEL + tid * 4);
    float4 av = *(const float4*)(A + (size_t)row * D_MODEL + tid * 4);
    float v0 = xv.x + av.x, v1 = xv.y + av.y, v2 = xv.z + av.z, v3 = xv.w + av.w;

    float s = v0 + v1 + v2 + v3;
#pragma unroll
    for (int off = 32; off; off >>= 1) s += __shfl_down(s, off);
    if ((tid & 63) == 0) wred[tid >> 6] = s;
    __syncthreads();
    float mean = (wred[0] + wred[1] + wred[2] + wred[3]) * (1.f / 1024.f);
    __syncthreads();

    float d0 = v0 - mean, d1 = v1 - mean, d2 = v2 - mean, d3 = v3 - mean;
    float q = d0 * d0 + d1 * d1 + d2 * d2 + d3 * d3;
#pragma unroll
    for (int off = 32; off; off >>= 1) q += __shfl_down(q, off);
    if ((tid & 63) == 0) wred[tid >> 6] = q;
    __syncthreads();
    float var = (wred[0] + wred[1] + wred[2] + wred[3]) * (1.f / 1024.f);
    float rstd = rsqrtf(var + 1e-12f);

    float4 gv = *(const float4*)(g + tid * 4);
    float4 bv = *(const float4*)(be + tid * 4);
    float4 o;
    o.x = gv.x * d0 * rstd + bv.x;
    o.y = gv.y * d1 * rstd + bv.y;
    o.z = gv.z * d2 * rstd + bv.z;
    o.w = gv.w * d3 * rstd + bv.w;
    *(float4*)(out + (size_t)row * D_MODEL + tid * 4) = o;
    if (WB16) {
        ushort4 ob;
        ob.x = f2bf(o.x); ob.y = f2bf(o.y); ob.z = f2bf(o.z); ob.w = f2bf(o.w);
        *(ushort4*)(out16 + (size_t)row * D_MODEL + tid * 4) = ob;
    }
}

// ---------------------------------------------------------------------------
extern "C" void kernel_launch(void* const* d_in, const int* in_sizes, int n_in,
                              void* d_out, int out_size, void* d_ws, size_t ws_size,
                              hipStream_t stream)
{
    const float* x   = (const float*)d_in[0];
    const float* wq  = (const float*)d_in[1];
    const float* bq  = (const float*)d_in[2];
    const float* wk  = (const float*)d_in[3];
    const float* bk  = (const float*)d_in[4];
    const float* wv  = (const float*)d_in[5];
    const float* bv  = (const float*)d_in[6];
    const float* wo  = (const float*)d_in[7];
    const float* bo  = (const float*)d_in[8];
    const float* w1  = (const float*)d_in[9];
    const float* b1  = (const float*)d_in[10];
    const float* w2  = (const float*)d_in[11];
    const float* b2  = (const float*)d_in[12];
    const float* g1  = (const float*)d_in[13];
    const float* be1 = (const float*)d_in[14];
    const float* g2  = (const float*)d_in[15];
    const float* be2 = (const float*)d_in[16];
    const int*  idxs = (const int*)d_in[17];

    char* ws = (char*)d_ws;
    const size_t MB = 1u << 20;
    // phase-annotated layout; peak use = 124 MB (round-1 proved >=128.6 ok)
    unsigned short* Qhb  = (unsigned short*)(ws);              // [proj..attn]
    unsigned short* Qlb  = (unsigned short*)(ws + 16 * MB);    // [proj..attn]
    unsigned short* Khb  = (unsigned short*)(ws + 32 * MB);    // [proj..attn]
    unsigned short* Klb  = (unsigned short*)(ws + 48 * MB);    // [proj..attn]
    unsigned short* xh   = (unsigned short*)(ws + 64 * MB);    // [split..vproj]
    unsigned short* xl   = (unsigned short*)(ws + 80 * MB);    // [split..kproj]
    unsigned short* ATTb = (unsigned short*)(ws + 64 * MB);    // [attn..wo] (over xh)
    unsigned short* x1b  = (unsigned short*)(ws + 80 * MB);    // [ln1..ffn] (over xl)
    unsigned short* wqhT = (unsigned short*)(ws + 96 * MB);    // [tc..qproj]
    unsigned short* wqlT = (unsigned short*)(ws + 98 * MB);
    unsigned short* wkhT = (unsigned short*)(ws + 100 * MB);
    unsigned short* wklT = (unsigned short*)(ws + 102 * MB);
    unsigned short* wvT  = (unsigned short*)(ws + 104 * MB);
    unsigned short* woT  = (unsigned short*)(ws + 106 * MB);   // [tc..wo-gemm]
    float* Mb            = (float*)(ws + 96 * MB);             // [mstat..topk] (over wq*)
    int*   Mtop          = (int*)(ws + 97 * MB);               // [topk..attn]
    unsigned short* Vb   = (unsigned short*)(ws + 108 * MB);   // [vproj..attn]
    float* Ab            = (float*)(ws);                       // [wo..ln1] (over Qh/Ql)
    float* x1f           = (float*)(ws + 32 * MB);             // [ln1..ln2] (over Kh/Kl)
    unsigned short* w1T  = (unsigned short*)(ws + 98 * MB);    // [post-ln1..ffn]
    unsigned short* w2T  = (unsigned short*)(ws + 108 * MB);   // [post-ln1..ffn] (over Vb)
    unsigned short* HIDb = (unsigned short*)(ws);              // [ffn] (over Ab)
    float* F             = (float*)d_out;                      // FFN accum

    dim3 blk(256);
    dim3 g_gemm(8, 64);

    // split x; split-transpose selection weights; plain transposes
    split_f32<<<dim3(8192), blk, 0, stream>>>(x, xh, xl);
    tconv_split<<<dim3(32, 32), blk, 0, stream>>>(wq, 1024, 1024, wqhT, wqlT);
    tconv_split<<<dim3(32, 32), blk, 0, stream>>>(wk, 1024, 1024, wkhT, wklT);
    tconv<<<dim3(32, 32), blk, 0, stream>>>(wv, 1024, 1024, wvT);
    tconv<<<dim3(32, 32), blk, 0, stream>>>(wo, 1024, 1024, woT);

    // q/k projections: split-bf16 (fp32-accurate for selection); v: plain bf16
    gemm_bf16_split<<<g_gemm, blk, 0, stream>>>(xh, xl, 1024, wqhT, wqlT, 1024,
                                                Qhb, Qlb, 1024, 1024, bq);
    gemm_bf16_split<<<g_gemm, blk, 0, stream>>>(xh, xl, 1024, wkhT, wklT, 1024,
                                                Khb, Klb, 1024, 1024, bk);
    gemm_bf16<true, false, false><<<g_gemm, blk, 0, stream>>>(xh, 1024, wvT, 1024,
                                                              Vb, 1024, 1024, bv);

    // selection: MFMA M-stat + top-40
    mstat_mfma<<<dim3(16, 64), blk, 0, stream>>>(Qhb, Qlb, Khb, Klb, idxs, Mb);
    topk_kernel<<<dim3(64), blk, 0, stream>>>(Mb, Mtop);

    // sparse attention -> scattered bf16 ATT
    hipMemsetAsync(ATTb, 0, 16 * MB, stream);
    attn_kernel<<<dim3(U_TOP, N_BH), blk, 0, stream>>>(Qhb, Qlb, Khb, Klb, Vb, Mtop, ATTb);

    // output projection + LN1
    gemm_bf16<false, false, false><<<g_gemm, blk, 0, stream>>>(ATTb, 1024, woT, 1024,
                                                               Ab, 1024, 1024, bo);
    ln_kernel<true><<<dim3(8192), blk, 0, stream>>>(x, Ab, g1, be1, x1f, x1b);

    // FFN weights (regions dead now)
    tconv<<<dim3(128, 32), blk, 0, stream>>>(w1, 1024, 4096, w1T);
    tconv<<<dim3(32, 128), blk, 0, stream>>>(w2, 4096, 1024, w2T);

    // FFN, chunked over F (4 x 1024)
    for (int c = 0; c < 4; ++c) {
        gemm_bf16<true, true, false><<<g_gemm, blk, 0, stream>>>(
            x1b, 1024, w1T + (size_t)c * 1024 * 1024, 1024, HIDb, 1024, 1024, b1 + c * 1024);
        if (c == 0)
            gemm_bf16<false, false, false><<<g_gemm, blk, 0, stream>>>(
                HIDb, 1024, w2T + c * 1024, 4096, F, 1024, 1024, b2);
        else
            gemm_bf16<false, false, true><<<g_gemm, blk, 0, stream>>>(
                HIDb, 1024, w2T + c * 1024, 4096, F, 1024, 1024, nullptr);
    }

    // out = LN(x1 + F)
    ln_kernel<false><<<dim3(8192), blk, 0, stream>>>(x1f, F, g2, be2, (float*)d_out, nullptr);
}

// Round 4
// 862.088 us; speedup vs baseline: 3.7751x; 1.2289x over previous
//
#include <hip/hip_runtime.h>
#include <float.h>
#include <math.h>

#define L_SEQ 2048
#define D_MODEL 1024
#define N_HEAD 16
#define HD 64
#define N_BH 64
#define U_TOP 40

using bf16x8 = __attribute__((ext_vector_type(8))) short;
using f32x4  = __attribute__((ext_vector_type(4))) float;

__device__ __forceinline__ unsigned short f2bf(float f) {
    unsigned int u = __builtin_bit_cast(unsigned int, f);
    u += 0x7fff + ((u >> 16) & 1);   // round-to-nearest-even
    return (unsigned short)(u >> 16);
}
__device__ __forceinline__ float bf2f(unsigned short h) {
    unsigned int u = ((unsigned int)h) << 16;
    return __builtin_bit_cast(float, u);
}

__device__ __forceinline__ void gload_lds16(const void* g, void* l) {
    __builtin_amdgcn_global_load_lds(
        (const __attribute__((address_space(1))) unsigned int*)g,
        (__attribute__((address_space(3))) unsigned int*)l, 16, 0, 0);
}

// ---------------------------------------------------------------------------
// bf16 MFMA GEMM: C = A(bf16) @ BT(bf16)^T, fp32 accum. 128x128 tile, BK=32.
// ---------------------------------------------------------------------------
template<bool OUTBF16, bool RELU, bool ACCUM>
__global__ void __launch_bounds__(256)
gemm_bf16(const unsigned short* __restrict__ A, int lda,
          const unsigned short* __restrict__ BT, int ldbt,
          void* __restrict__ Cp, int ldc, int K,
          const float* __restrict__ bias)
{
    __shared__ short As[4096];
    __shared__ short Bs[4096];
    const int tid = threadIdx.x;
    const int w = tid >> 6, l = tid & 63;
    const int bx = blockIdx.x, by = blockIdx.y;
    const int wm = w >> 1, wn = w & 1;

    f32x4 acc[4][4] = {};

    const unsigned short* a_src[2];
    const unsigned short* b_src[2];
#pragma unroll
    for (int g = 0; g < 2; ++g) {
        int r = w * 32 + g * 16 + (l >> 2);
        int kc = (l & 3) ^ ((r >> 1) & 3);
        a_src[g] = A + (size_t)(by * 128 + r) * lda + kc * 8;
        b_src[g] = BT + (size_t)(bx * 128 + r) * ldbt + kc * 8;
    }
    short* As_w = As + w * 1024;
    short* Bs_w = Bs + w * 1024;

    const int lr = l & 15, lg = l >> 4;

    for (int k0 = 0; k0 < K; k0 += 32) {
        __syncthreads();
        gload_lds16(a_src[0] + k0, As_w);
        gload_lds16(a_src[1] + k0, As_w + 512);
        gload_lds16(b_src[0] + k0, Bs_w);
        gload_lds16(b_src[1] + k0, Bs_w + 512);
        __syncthreads();

        bf16x8 af[4], bg[4];
#pragma unroll
        for (int m = 0; m < 4; ++m) {
            int row = wm * 64 + m * 16 + lr;
            int off = row * 64 + ((lg ^ ((row >> 1) & 3)) << 4);
            af[m] = *(const bf16x8*)((const char*)As + off);
        }
#pragma unroll
        for (int n = 0; n < 4; ++n) {
            int row = wn * 64 + n * 16 + lr;
            int off = row * 64 + ((lg ^ ((row >> 1) & 3)) << 4);
            bg[n] = *(const bf16x8*)((const char*)Bs + off);
        }
#pragma unroll
        for (int m = 0; m < 4; ++m)
#pragma unroll
            for (int n = 0; n < 4; ++n)
                acc[m][n] = __builtin_amdgcn_mfma_f32_16x16x32_bf16(
                    af[m], bg[n], acc[m][n], 0, 0, 0);
    }

    float bcol[4];
#pragma unroll
    for (int n = 0; n < 4; ++n) {
        int colg = bx * 128 + wn * 64 + n * 16 + lr;
        bcol[n] = bias ? bias[colg] : 0.f;
    }
#pragma unroll
    for (int m = 0; m < 4; ++m) {
#pragma unroll
        for (int n = 0; n < 4; ++n) {
            int colg = bx * 128 + wn * 64 + n * 16 + lr;
#pragma unroll
            for (int r = 0; r < 4; ++r) {
                int rowg = by * 128 + wm * 64 + m * 16 + lg * 4 + r;
                float v = acc[m][n][r] + bcol[n];
                if (RELU) v = fmaxf(v, 0.f);
                if (OUTBF16) {
                    ((unsigned short*)Cp)[(size_t)rowg * ldc + colg] = f2bf(v);
                } else {
                    float* C = (float*)Cp;
                    if (ACCUM) v += C[(size_t)rowg * ldc + colg];
                    C[(size_t)rowg * ldc + colg] = v;
                }
            }
        }
    }
}

// ---------------------------------------------------------------------------
// Split-bf16 GEMM (fp32-accurate): 3 MFMAs (hh+hl+lh), split bf16 output.
// ---------------------------------------------------------------------------
__global__ void __launch_bounds__(256)
gemm_bf16_split(const unsigned short* __restrict__ Ah,
                const unsigned short* __restrict__ Al, int lda,
                const unsigned short* __restrict__ BhT,
                const unsigned short* __restrict__ BlT, int ldbt,
                unsigned short* __restrict__ Ch,
                unsigned short* __restrict__ Cl, int ldc, int K,
                const float* __restrict__ bias)
{
    __shared__ short Ash[4096], Asl[4096], Bsh[4096], Bsl[4096];
    const int tid = threadIdx.x;
    const int w = tid >> 6, l = tid & 63;
    const int bx = blockIdx.x, by = blockIdx.y;
    const int wm = w >> 1, wn = w & 1;

    f32x4 acc[4][4] = {};

    size_t a_off[2], b_off[2];
#pragma unroll
    for (int g = 0; g < 2; ++g) {
        int r = w * 32 + g * 16 + (l >> 2);
        int kc = (l & 3) ^ ((r >> 1) & 3);
        a_off[g] = (size_t)(by * 128 + r) * lda + kc * 8;
        b_off[g] = (size_t)(bx * 128 + r) * ldbt + kc * 8;
    }
    const int wb = w * 1024;
    const int lr = l & 15, lg = l >> 4;

    for (int k0 = 0; k0 < K; k0 += 32) {
        __syncthreads();
#pragma unroll
        for (int g = 0; g < 2; ++g) {
            gload_lds16(Ah + a_off[g] + k0, Ash + wb + g * 512);
            gload_lds16(Al + a_off[g] + k0, Asl + wb + g * 512);
            gload_lds16(BhT + b_off[g] + k0, Bsh + wb + g * 512);
            gload_lds16(BlT + b_off[g] + k0, Bsl + wb + g * 512);
        }
        __syncthreads();

        bf16x8 afh[4], afl[4], bgh[4], bgl[4];
#pragma unroll
        for (int m = 0; m < 4; ++m) {
            int row = wm * 64 + m * 16 + lr;
            int off = row * 64 + ((lg ^ ((row >> 1) & 3)) << 4);
            afh[m] = *(const bf16x8*)((const char*)Ash + off);
            afl[m] = *(const bf16x8*)((const char*)Asl + off);
        }
#pragma unroll
        for (int n = 0; n < 4; ++n) {
            int row = wn * 64 + n * 16 + lr;
            int off = row * 64 + ((lg ^ ((row >> 1) & 3)) << 4);
            bgh[n] = *(const bf16x8*)((const char*)Bsh + off);
            bgl[n] = *(const bf16x8*)((const char*)Bsl + off);
        }
#pragma unroll
        for (int m = 0; m < 4; ++m)
#pragma unroll
            for (int n = 0; n < 4; ++n) {
                acc[m][n] = __builtin_amdgcn_mfma_f32_16x16x32_bf16(
                    afh[m], bgh[n], acc[m][n], 0, 0, 0);
                acc[m][n] = __builtin_amdgcn_mfma_f32_16x16x32_bf16(
                    afh[m], bgl[n], acc[m][n], 0, 0, 0);
                acc[m][n] = __builtin_amdgcn_mfma_f32_16x16x32_bf16(
                    afl[m], bgh[n], acc[m][n], 0, 0, 0);
            }
    }

    float bcol[4];
#pragma unroll
    for (int n = 0; n < 4; ++n)
        bcol[n] = bias[bx * 128 + wn * 64 + n * 16 + lr];
#pragma unroll
    for (int m = 0; m < 4; ++m)
#pragma unroll
        for (int n = 0; n < 4; ++n) {
            int colg = bx * 128 + wn * 64 + n * 16 + lr;
#pragma unroll
            for (int r = 0; r < 4; ++r) {
                int rowg = by * 128 + wm * 64 + m * 16 + lg * 4 + r;
                float v = acc[m][n][r] + bcol[n];
                unsigned short hh = f2bf(v);
                unsigned short ll = f2bf(v - bf2f(hh));
                Ch[(size_t)rowg * ldc + colg] = hh;
                Cl[(size_t)rowg * ldc + colg] = ll;
            }
        }
}

// ---------------------------------------------------------------------------
// MFMA M-stat (split-bf16), unchanged from round 3.
// ---------------------------------------------------------------------------
__global__ void __launch_bounds__(256)
mstat_mfma(const unsigned short* __restrict__ Qh, const unsigned short* __restrict__ Ql,
           const unsigned short* __restrict__ Kh, const unsigned short* __restrict__ Kl,
           const int* __restrict__ idxs, float* __restrict__ Mout)
{
    __shared__ short Qs[2][8192];
    __shared__ short Ks[2][4096];
    const int tid = threadIdx.x, w = tid >> 6, l = tid & 63;
    const int itile = blockIdx.x, bh = blockIdx.y;
    const int b = bh >> 4, h = bh & 15;
    const int i0 = itile * 128;
    const int lr = l & 15, lg = l >> 4;

#pragma unroll
    for (int g = w * 4; g < w * 4 + 4; ++g) {
        int row = g * 8 + (l >> 3);
        int kc = (l & 7) ^ (row & 7);
        size_t src = (size_t)(bh * L_SEQ + i0 + row) * HD + kc * 8;
        gload_lds16(Qh + src, (char*)&Qs[0][0] + g * 1024);
        gload_lds16(Ql + src, (char*)&Qs[1][0] + g * 1024);
    }
    __syncthreads();

    bf16x8 af[2][2][2];
#pragma unroll
    for (int m = 0; m < 2; ++m) {
        int row = (w * 2 + m) * 16 + lr;
#pragma unroll
        for (int k = 0; k < 2; ++k) {
            int c = k * 4 + lg;
            int off = row * 128 + ((c ^ (row & 7)) << 4);
            af[m][k][0] = *(const bf16x8*)((const char*)&Qs[0][0] + off);
            af[m][k][1] = *(const bf16x8*)((const char*)&Qs[1][0] + off);
        }
    }

    float mx[2][4], sm[2][4];
#pragma unroll
    for (int m = 0; m < 2; ++m)
#pragma unroll
        for (int r = 0; r < 4; ++r) { mx[m][r] = -FLT_MAX; sm[m][r] = 0.f; }

    for (int jt = 0; jt < 32; ++jt) {
        const int j0 = jt * 64;
        __syncthreads();
#pragma unroll
        for (int g = 2 * w; g <= 2 * w + 1; ++g) {
            int row = g * 8 + (l >> 3);
            int kc = (l & 7) ^ (row & 7);
            int gr = idxs[j0 + row];
            size_t src = (size_t)(b * L_SEQ + gr) * D_MODEL + h * HD + kc * 8;
            gload_lds16(Kh + src, (char*)&Ks[0][0] + g * 1024);
            gload_lds16(Kl + src, (char*)&Ks[1][0] + g * 1024);
        }
        __syncthreads();

        bf16x8 bgh[4][2], bgl[4][2];
#pragma unroll
        for (int n = 0; n < 4; ++n) {
            int row = n * 16 + lr;
#pragma unroll
            for (int k = 0; k < 2; ++k) {
                int c = k * 4 + lg;
                int off = row * 128 + ((c ^ (row & 7)) << 4);
                bgh[n][k] = *(const bf16x8*)((const char*)&Ks[0][0] + off);
                bgl[n][k] = *(const bf16x8*)((const char*)&Ks[1][0] + off);
            }
        }
#pragma unroll
        for (int m = 0; m < 2; ++m) {
            f32x4 a0[4];
#pragma unroll
            for (int n = 0; n < 4; ++n) {
                f32x4 a = {};
                a = __builtin_amdgcn_mfma_f32_16x16x32_bf16(af[m][0][0], bgh[n][0], a, 0, 0, 0);
                a = __builtin_amdgcn_mfma_f32_16x16x32_bf16(af[m][0][0], bgl[n][0], a, 0, 0, 0);
                a = __builtin_amdgcn_mfma_f32_16x16x32_bf16(af[m][0][1], bgh[n][0], a, 0, 0, 0);
                a = __builtin_amdgcn_mfma_f32_16x16x32_bf16(af[m][1][0], bgh[n][1], a, 0, 0, 0);
                a = __builtin_amdgcn_mfma_f32_16x16x32_bf16(af[m][1][0], bgl[n][1], a, 0, 0, 0);
                a = __builtin_amdgcn_mfma_f32_16x16x32_bf16(af[m][1][1], bgh[n][1], a, 0, 0, 0);
                a0[n] = a;
            }
#pragma unroll
            for (int r = 0; r < 4; ++r) {
                float vmax = fmaxf(fmaxf(a0[0][r], a0[1][r]), fmaxf(a0[2][r], a0[3][r]));
                float vsum = (a0[0][r] + a0[1][r]) + (a0[2][r] + a0[3][r]);
                mx[m][r] = fmaxf(mx[m][r], vmax);
                sm[m][r] += vsum;
            }
        }
    }

#pragma unroll
    for (int m = 0; m < 2; ++m)
#pragma unroll
        for (int r = 0; r < 4; ++r) {
            float a = mx[m][r], s = sm[m][r];
#pragma unroll
            for (int mask = 1; mask < 16; mask <<= 1) {
                a = fmaxf(a, __shfl_xor(a, mask));
                s += __shfl_xor(s, mask);
            }
            if (lr == 0) {
                int row = i0 + (w * 2 + m) * 16 + lg * 4 + r;
                Mout[(size_t)bh * L_SEQ + row] = a - s * (1.0f / 2048.0f);
            }
        }
}

// ---------------------------------------------------------------------------
// transpose + fp32->bf16 (single and split variants)
// ---------------------------------------------------------------------------
__global__ void __launch_bounds__(256)
tconv(const float* __restrict__ in, int R, int C, unsigned short* __restrict__ out)
{
    __shared__ float t[32][33];
    const int bx = blockIdx.x * 32;
    const int by = blockIdx.y * 32;
    const int lx = threadIdx.x & 31, ly = threadIdx.x >> 5;
#pragma unroll
    for (int r = 0; r < 4; ++r)
        t[ly + r * 8][lx] = in[(size_t)(by + ly + r * 8) * C + bx + lx];
    __syncthreads();
#pragma unroll
    for (int r = 0; r < 4; ++r) {
        int oc = ly + r * 8;
        out[(size_t)(bx + oc) * R + by + lx] = f2bf(t[lx][oc]);
    }
}

__global__ void __launch_bounds__(256)
tconv_split(const float* __restrict__ in, int R, int C,
            unsigned short* __restrict__ outh, unsigned short* __restrict__ outl)
{
    __shared__ float t[32][33];
    const int bx = blockIdx.x * 32;
    const int by = blockIdx.y * 32;
    const int lx = threadIdx.x & 31, ly = threadIdx.x >> 5;
#pragma unroll
    for (int r = 0; r < 4; ++r)
        t[ly + r * 8][lx] = in[(size_t)(by + ly + r * 8) * C + bx + lx];
    __syncthreads();
#pragma unroll
    for (int r = 0; r < 4; ++r) {
        int oc = ly + r * 8;
        float f = t[lx][oc];
        unsigned short hh = f2bf(f);
        outh[(size_t)(bx + oc) * R + by + lx] = hh;
        outl[(size_t)(bx + oc) * R + by + lx] = f2bf(f - bf2f(hh));
    }
}

__global__ void __launch_bounds__(256)
split_f32(const float* __restrict__ in, unsigned short* __restrict__ hi,
          unsigned short* __restrict__ lo)
{
    size_t i = ((size_t)blockIdx.x * 256 + threadIdx.x) * 4;
    float4 v = *(const float4*)(in + i);
    ushort4 h, l2;
    h.x = f2bf(v.x); l2.x = f2bf(v.x - bf2f(h.x));
    h.y = f2bf(v.y); l2.y = f2bf(v.y - bf2f(h.y));
    h.z = f2bf(v.z); l2.z = f2bf(v.z - bf2f(h.z));
    h.w = f2bf(v.w); l2.w = f2bf(v.w - bf2f(h.w));
    *(ushort4*)(hi + i) = h;
    *(ushort4*)(lo + i) = l2;
}

// ---------------------------------------------------------------------------
// Top-40 smallest M per bh (lower-index tie-break).
// ---------------------------------------------------------------------------
__global__ void __launch_bounds__(256)
topk_kernel(const float* __restrict__ M, int* __restrict__ Mtop)
{
    __shared__ float mv[L_SEQ];
    __shared__ float wv_[4];
    __shared__ int wi_[4];
    const int bh = blockIdx.x;
    const int tid = threadIdx.x;
    for (int j = tid; j < L_SEQ; j += 256) mv[j] = M[(size_t)bh * L_SEQ + j];
    __syncthreads();
    for (int u = 0; u < U_TOP; ++u) {
        float best = FLT_MAX;
        int bi = 1 << 30;
        for (int j = tid; j < L_SEQ; j += 256) {
            float v = mv[j];
            if (v < best || (v == best && j < bi)) { best = v; bi = j; }
        }
#pragma unroll
        for (int off = 32; off; off >>= 1) {
            float ov = __shfl_down(best, off);
            int oi = __shfl_down(bi, off);
            if (ov < best || (ov == best && oi < bi)) { best = ov; bi = oi; }
        }
        if ((tid & 63) == 0) { wv_[tid >> 6] = best; wi_[tid >> 6] = bi; }
        __syncthreads();
        if (tid == 0) {
            for (int w = 1; w < 4; ++w)
                if (wv_[w] < best || (wv_[w] == best && wi_[w] < bi)) { best = wv_[w]; bi = wi_[w]; }
            Mtop[bh * U_TOP + u] = bi;
            mv[bi] = FLT_MAX;
        }
        __syncthreads();
    }
}

// ---------------------------------------------------------------------------
// FUSED sparse attention: ONE block per bh (64 blocks). All 40 selected
// queries as a padded 64-row MFMA tile; K/V streamed ONCE per bh in 16
// tiles of 128 keys. Online softmax held in registers (row = lg*4+r is
// lane-local in the C-layout); P round-trips through swizzled LDS to reach
// the MFMA A-layout; V transpose-staged to LDS for the PV B-operand.
// ---------------------------------------------------------------------------
__global__ void __launch_bounds__(256)
attn_fused(const unsigned short* __restrict__ Q,   // Qh flat [BH*L][64]
           const unsigned short* __restrict__ K,   // Kh [B][L][1024]
           const unsigned short* __restrict__ V,   // Vb [B][L][1024]
           const int* __restrict__ Mtop,
           unsigned short* __restrict__ ATT)       // zeroed bf16 [B][L][1024]
{
    __shared__ unsigned short Qs[64 * 64];    // [row][d]  swizzled, 8 KB
    __shared__ unsigned short Ks[128 * 64];   // [key][d]  swizzled, 16 KB
    __shared__ unsigned short Vt[64 * 128];   // [d][key]  swizzled, 16 KB
    __shared__ unsigned short Pb[64 * 128];   // [row][key] swizzled, 16 KB
    const int bh = blockIdx.x;
    const int b = bh >> 4, h = bh & 15;
    const int tid = threadIdx.x, w = tid >> 6, l = tid & 63;
    const int lr = l & 15, lg = l >> 4;

    // ---- stage Q rows (gathered via Mtop; rows >= 40 duplicate row 39) ----
#pragma unroll
    for (int is = 0; is < 2; ++is) {
        int row = w * 16 + is * 8 + (l >> 3);
        int u = row < U_TOP ? row : U_TOP - 1;
        int lsel = Mtop[bh * U_TOP + u];
        int cg = (l & 7) ^ (row & 7);
        gload_lds16(Q + (((size_t)(bh * L_SEQ + lsel)) << 6) + cg * 8,
                    &Qs[(w * 16 + is * 8) * 64]);
    }
    __syncthreads();

    // hoist Q A-frags (wave w owns rows 16w..16w+15)
    bf16x8 af[2];
    {
        int row = w * 16 + lr;
#pragma unroll
        for (int ks = 0; ks < 2; ++ks) {
            int c = (ks * 4 + lg) ^ (row & 7);
            af[ks] = *(const bf16x8*)((const char*)Qs + row * 128 + (c << 4));
        }
    }

    float m_run[4], l_run[4];
    f32x4 oacc[4] = {};
#pragma unroll
    for (int r = 0; r < 4; ++r) { m_run[r] = -FLT_MAX; l_run[r] = 0.f; }

    for (int t = 0; t < 16; ++t) {
        const int j0 = t * 128;
        __syncthreads();   // prev tile's PV done: Ks/Vt/Pb reusable

        // stage K tile (gload_lds, pre-swizzled source)
#pragma unroll
        for (int is = 0; is < 4; ++is) {
            int kr = w * 32 + is * 8 + (l >> 3);
            int cg = (l & 7) ^ (kr & 7);
            gload_lds16(K + (((size_t)(b * L_SEQ + j0 + kr)) << 10) + (h << 6) + cg * 8,
                        &Ks[(w * 32 + is * 8) * 64]);
        }
        // transpose-stage V tile: thread owns (key, 32-d half)
        {
            int key = tid & 127, dh = (tid >> 7) * 32;
            const unsigned short* vsrc =
                V + (((size_t)(b * L_SEQ + j0 + key)) << 10) + (h << 6) + dh;
            bf16x8 vv[4];
#pragma unroll
            for (int i = 0; i < 4; ++i) vv[i] = *(const bf16x8*)(vsrc + i * 8);
            int ck = key >> 3, klo = (key & 7) * 2;
#pragma unroll
            for (int i = 0; i < 4; ++i)
#pragma unroll
                for (int j = 0; j < 8; ++j) {
                    int d = dh + i * 8 + j;
                    *(unsigned short*)((char*)Vt + d * 256 +
                                       ((ck ^ (d & 7)) << 4) + klo) =
                        (unsigned short)vv[i][j];
                }
        }
        __syncthreads();

        // QK^T: wave w rows 16w..16w+15 x all 128 keys
        f32x4 sc[8] = {};
#pragma unroll
        for (int ks = 0; ks < 2; ++ks)
#pragma unroll
            for (int n = 0; n < 8; ++n) {
                int krow = n * 16 + lr;
                int c = (ks * 4 + lg) ^ (krow & 7);
                bf16x8 bf = *(const bf16x8*)((const char*)Ks + krow * 128 + (c << 4));
                sc[n] = __builtin_amdgcn_mfma_f32_16x16x32_bf16(af[ks], bf, sc[n], 0, 0, 0);
            }

        // in-register online softmax; write P to LDS in A-frag layout
        float rs[4];
#pragma unroll
        for (int r = 0; r < 4; ++r) {
            int row = w * 16 + lg * 4 + r;
            float mt = -FLT_MAX;
#pragma unroll
            for (int n = 0; n < 8; ++n) mt = fmaxf(mt, sc[n][r]);
            mt *= 0.125f;
#pragma unroll
            for (int mask = 1; mask < 16; mask <<= 1)
                mt = fmaxf(mt, __shfl_xor(mt, mask));
            float mn = fmaxf(m_run[r], mt);
            rs[r] = expf(m_run[r] - mn);
            float ls = 0.f;
            int rsw = row & 7;
#pragma unroll
            for (int n = 0; n < 8; ++n) {
                float p = expf(sc[n][r] * 0.125f - mn);
                ls += p;
                int ckp = (lr >> 3) + 2 * n;
                *(unsigned short*)((char*)Pb + row * 256 +
                                   ((ckp ^ rsw) << 4) + (lr & 7) * 2) = f2bf(p);
            }
#pragma unroll
            for (int mask = 1; mask < 16; mask <<= 1) ls += __shfl_xor(ls, mask);
            l_run[r] = l_run[r] * rs[r] + ls;
            m_run[r] = mn;
        }
        __syncthreads();

        // rescale accumulators, then PV via MFMA
#pragma unroll
        for (int n = 0; n < 4; ++n)
#pragma unroll
            for (int r = 0; r < 4; ++r) oacc[n][r] *= rs[r];
#pragma unroll
        for (int ks = 0; ks < 4; ++ks) {
            int arow = w * 16 + lr;
            int ca = (lg + ks * 4) ^ (arow & 7);
            bf16x8 pa = *(const bf16x8*)((const char*)Pb + arow * 256 + (ca << 4));
#pragma unroll
            for (int n = 0; n < 4; ++n) {
                int d = n * 16 + lr;
                int cb = (lg + ks * 4) ^ (d & 7);
                bf16x8 vb = *(const bf16x8*)((const char*)Vt + d * 256 + (cb << 4));
                oacc[n] = __builtin_amdgcn_mfma_f32_16x16x32_bf16(pa, vb, oacc[n], 0, 0, 0);
            }
        }
    }

    // epilogue: normalize and scatter the 40 real rows
#pragma unroll
    for (int r = 0; r < 4; ++r) {
        int row = w * 16 + lg * 4 + r;
        if (row < U_TOP) {
            int lsel = Mtop[bh * U_TOP + row];
            float inv = 1.f / l_run[r];
            size_t base = (((size_t)(b * L_SEQ + lsel)) << 10) + (h << 6);
#pragma unroll
            for (int n = 0; n < 4; ++n)
                ATT[base + n * 16 + lr] = f2bf(oacc[n][r] * inv);
        }
    }
}

// ---------------------------------------------------------------------------
// Fused residual + LayerNorm (optionally also emits bf16 copy).
// ---------------------------------------------------------------------------
template<bool WB16>
__global__ void __launch_bounds__(256)
ln_kernel(const float* __restrict__ X, const float* __restrict__ A,
          const float* __restrict__ g, const float* __restrict__ be,
          float* __restrict__ out, unsigned short* __restrict__ out16)
{
    __shared__ float wred[4];
    const int row = blockIdx.x, tid = threadIdx.x;
    float4 xv = *(const float4*)(X + (size_t)row * D_MODEL + tid * 4);
    float4 av = *(const float4*)(A + (size_t)row * D_MODEL + tid * 4);
    float v0 = xv.x + av.x, v1 = xv.y + av.y, v2 = xv.z + av.z, v3 = xv.w + av.w;

    float s = v0 + v1 + v2 + v3;
#pragma unroll
    for (int off = 32; off; off >>= 1) s += __shfl_down(s, off);
    if ((tid & 63) == 0) wred[tid >> 6] = s;
    __syncthreads();
    float mean = (wred[0] + wred[1] + wred[2] + wred[3]) * (1.f / 1024.f);
    __syncthreads();

    float d0 = v0 - mean, d1 = v1 - mean, d2 = v2 - mean, d3 = v3 - mean;
    float q = d0 * d0 + d1 * d1 + d2 * d2 + d3 * d3;
#pragma unroll
    for (int off = 32; off; off >>= 1) q += __shfl_down(q, off);
    if ((tid & 63) == 0) wred[tid >> 6] = q;
    __syncthreads();
    float var = (wred[0] + wred[1] + wred[2] + wred[3]) * (1.f / 1024.f);
    float rstd = rsqrtf(var + 1e-12f);

    float4 gv = *(const float4*)(g + tid * 4);
    float4 bv = *(const float4*)(be + tid * 4);
    float4 o;
    o.x = gv.x * d0 * rstd + bv.x;
    o.y = gv.y * d1 * rstd + bv.y;
    o.z = gv.z * d2 * rstd + bv.z;
    o.w = gv.w * d3 * rstd + bv.w;
    *(float4*)(out + (size_t)row * D_MODEL + tid * 4) = o;
    if (WB16) {
        ushort4 ob;
        ob.x = f2bf(o.x); ob.y = f2bf(o.y); ob.z = f2bf(o.z); ob.w = f2bf(o.w);
        *(ushort4*)(out16 + (size_t)row * D_MODEL + tid * 4) = ob;
    }
}

// ---------------------------------------------------------------------------
extern "C" void kernel_launch(void* const* d_in, const int* in_sizes, int n_in,
                              void* d_out, int out_size, void* d_ws, size_t ws_size,
                              hipStream_t stream)
{
    const float* x   = (const float*)d_in[0];
    const float* wq  = (const float*)d_in[1];
    const float* bq  = (const float*)d_in[2];
    const float* wk  = (const float*)d_in[3];
    const float* bk  = (const float*)d_in[4];
    const float* wv  = (const float*)d_in[5];
    const float* bv  = (const float*)d_in[6];
    const float* wo  = (const float*)d_in[7];
    const float* bo  = (const float*)d_in[8];
    const float* w1  = (const float*)d_in[9];
    const float* b1  = (const float*)d_in[10];
    const float* w2  = (const float*)d_in[11];
    const float* b2  = (const float*)d_in[12];
    const float* g1  = (const float*)d_in[13];
    const float* be1 = (const float*)d_in[14];
    const float* g2  = (const float*)d_in[15];
    const float* be2 = (const float*)d_in[16];
    const int*  idxs = (const int*)d_in[17];

    char* ws = (char*)d_ws;
    const size_t MB = 1u << 20;
    // phase-annotated layout; peak ~124 MB
    unsigned short* Qhb  = (unsigned short*)(ws);              // [proj..attn]
    unsigned short* Qlb  = (unsigned short*)(ws + 16 * MB);    // [proj..mstat]
    unsigned short* Khb  = (unsigned short*)(ws + 32 * MB);    // [proj..attn]
    unsigned short* Klb  = (unsigned short*)(ws + 48 * MB);    // [proj..mstat]
    unsigned short* xh   = (unsigned short*)(ws + 64 * MB);    // [split..vproj]
    unsigned short* xl   = (unsigned short*)(ws + 80 * MB);    // [split..kproj]
    unsigned short* ATTb = (unsigned short*)(ws + 64 * MB);    // [attn..wo]   (over xh)
    unsigned short* x1b  = (unsigned short*)(ws + 80 * MB);    // [ln1..ffn]   (over xl)
    unsigned short* wqhT = (unsigned short*)(ws + 96 * MB);    // [tc..qproj]
    unsigned short* wqlT = (unsigned short*)(ws + 98 * MB);
    unsigned short* wkhT = (unsigned short*)(ws + 100 * MB);
    unsigned short* wklT = (unsigned short*)(ws + 102 * MB);
    unsigned short* wvT  = (unsigned short*)(ws + 104 * MB);
    unsigned short* woT  = (unsigned short*)(ws + 106 * MB);   // [tc..wo-gemm]
    float* Mb            = (float*)(ws + 96 * MB);             // [mstat..topk] (over wq*)
    int*   Mtop          = (int*)(ws + 97 * MB);               // [topk..attn]
    unsigned short* Vb   = (unsigned short*)(ws + 108 * MB);   // [vproj..attn]
    float* Ab            = (float*)(ws);                       // [wo..ln1]    (over Qhb/Qlb)
    float* x1f           = (float*)(ws + 32 * MB);             // [ln1..ln2]   (over Khb/Klb)
    unsigned short* w1T  = (unsigned short*)(ws + 96 * MB);    // [post-ln1..ffn]
    unsigned short* w2T  = (unsigned short*)(ws + 104 * MB);   // [post-ln1..ffn]
    unsigned short* HIDc = (unsigned short*)(ws);              // [ffn] 32MB (over Ab)
    float* F             = (float*)d_out;                      // FFN accum

    dim3 blk(256);
    dim3 g_gemm(8, 64);

    // split x; weight transposes needed before ln1
    split_f32<<<dim3(8192), blk, 0, stream>>>(x, xh, xl);
    tconv_split<<<dim3(32, 32), blk, 0, stream>>>(wq, 1024, 1024, wqhT, wqlT);
    tconv_split<<<dim3(32, 32), blk, 0, stream>>>(wk, 1024, 1024, wkhT, wklT);
    tconv<<<dim3(32, 32), blk, 0, stream>>>(wv, 1024, 1024, wvT);
    tconv<<<dim3(32, 32), blk, 0, stream>>>(wo, 1024, 1024, woT);

    // projections
    gemm_bf16_split<<<g_gemm, blk, 0, stream>>>(xh, xl, 1024, wqhT, wqlT, 1024,
                                                Qhb, Qlb, 1024, 1024, bq);
    gemm_bf16_split<<<g_gemm, blk, 0, stream>>>(xh, xl, 1024, wkhT, wklT, 1024,
                                                Khb, Klb, 1024, 1024, bk);
    gemm_bf16<true, false, false><<<g_gemm, blk, 0, stream>>>(xh, 1024, wvT, 1024,
                                                              Vb, 1024, 1024, bv);

    // selection
    mstat_mfma<<<dim3(16, 64), blk, 0, stream>>>(Qhb, Qlb, Khb, Klb, idxs, Mb);
    topk_kernel<<<dim3(64), blk, 0, stream>>>(Mb, Mtop);

    // fused sparse attention (one block per bh) -> scattered bf16 ATT
    hipMemsetAsync(ATTb, 0, 16 * MB, stream);
    attn_fused<<<dim3(N_BH), blk, 0, stream>>>(Qhb, Khb, Vb, Mtop, ATTb);

    // output projection + LN1
    gemm_bf16<false, false, false><<<g_gemm, blk, 0, stream>>>(ATTb, 1024, woT, 1024,
                                                               Ab, 1024, 1024, bo);
    ln_kernel<true><<<dim3(8192), blk, 0, stream>>>(x, Ab, g1, be1, x1f, x1b);

    // FFN weights (regions dead now)
    tconv<<<dim3(128, 32), blk, 0, stream>>>(w1, 1024, 4096, w1T);
    tconv<<<dim3(32, 128), blk, 0, stream>>>(w2, 4096, 1024, w2T);

    // FFN, 2 chunks of 2048 hidden dims
    for (int c = 0; c < 2; ++c) {
        gemm_bf16<true, true, false><<<dim3(16, 64), blk, 0, stream>>>(
            x1b, 1024, w1T + (size_t)c * 2048 * 1024, 1024, HIDc, 2048, 1024, b1 + c * 2048);
        if (c == 0)
            gemm_bf16<false, false, false><<<g_gemm, blk, 0, stream>>>(
                HIDc, 2048, w2T + c * 2048, 4096, F, 1024, 2048, b2);
        else
            gemm_bf16<false, false, true><<<g_gemm, blk, 0, stream>>>(
                HIDc, 2048, w2T + c * 2048, 4096, F, 1024, 2048, nullptr);
    }

    // out = LN(x1 + F)
    ln_kernel<false><<<dim3(8192), blk, 0, stream>>>(x1f, F, g2, be2, (float*)d_out, nullptr);
}

// Round 6
// 840.032 us; speedup vs baseline: 3.8742x; 1.0263x over previous
//
#include <hip/hip_runtime.h>
#include <float.h>
#include <math.h>

#define L_SEQ 2048
#define D_MODEL 1024
#define N_HEAD 16
#define HD 64
#define N_BH 64
#define U_TOP 40

using bf16x8 = __attribute__((ext_vector_type(8))) short;
using f32x4  = __attribute__((ext_vector_type(4))) float;

__device__ __forceinline__ unsigned short f2bf(float f) {
    unsigned int u = __builtin_bit_cast(unsigned int, f);
    u += 0x7fff + ((u >> 16) & 1);   // round-to-nearest-even
    return (unsigned short)(u >> 16);
}
__device__ __forceinline__ float bf2f(unsigned short h) {
    unsigned int u = ((unsigned int)h) << 16;
    return __builtin_bit_cast(float, u);
}

__device__ __forceinline__ void gload_lds16(const void* g, void* l) {
    __builtin_amdgcn_global_load_lds(
        (const __attribute__((address_space(1))) unsigned int*)g,
        (__attribute__((address_space(3))) unsigned int*)l, 16, 0, 0);
}

// ---------------------------------------------------------------------------
// bf16 MFMA GEMM: C = A(bf16) @ BT(bf16)^T, fp32 accum. 128x128 tile, BK=32.
// ---------------------------------------------------------------------------
template<bool OUTBF16, bool RELU, bool ACCUM>
__global__ void __launch_bounds__(256)
gemm_bf16(const unsigned short* __restrict__ A, int lda,
          const unsigned short* __restrict__ BT, int ldbt,
          void* __restrict__ Cp, int ldc, int K,
          const float* __restrict__ bias)
{
    __shared__ short As[4096];
    __shared__ short Bs[4096];
    const int tid = threadIdx.x;
    const int w = tid >> 6, l = tid & 63;
    const int bx = blockIdx.x, by = blockIdx.y;
    const int wm = w >> 1, wn = w & 1;

    f32x4 acc[4][4] = {};

    const unsigned short* a_src[2];
    const unsigned short* b_src[2];
#pragma unroll
    for (int g = 0; g < 2; ++g) {
        int r = w * 32 + g * 16 + (l >> 2);
        int kc = (l & 3) ^ ((r >> 1) & 3);
        a_src[g] = A + (size_t)(by * 128 + r) * lda + kc * 8;
        b_src[g] = BT + (size_t)(bx * 128 + r) * ldbt + kc * 8;
    }
    short* As_w = As + w * 1024;
    short* Bs_w = Bs + w * 1024;

    const int lr = l & 15, lg = l >> 4;

    for (int k0 = 0; k0 < K; k0 += 32) {
        __syncthreads();
        gload_lds16(a_src[0] + k0, As_w);
        gload_lds16(a_src[1] + k0, As_w + 512);
        gload_lds16(b_src[0] + k0, Bs_w);
        gload_lds16(b_src[1] + k0, Bs_w + 512);
        __syncthreads();

        bf16x8 af[4], bg[4];
#pragma unroll
        for (int m = 0; m < 4; ++m) {
            int row = wm * 64 + m * 16 + lr;
            int off = row * 64 + ((lg ^ ((row >> 1) & 3)) << 4);
            af[m] = *(const bf16x8*)((const char*)As + off);
        }
#pragma unroll
        for (int n = 0; n < 4; ++n) {
            int row = wn * 64 + n * 16 + lr;
            int off = row * 64 + ((lg ^ ((row >> 1) & 3)) << 4);
            bg[n] = *(const bf16x8*)((const char*)Bs + off);
        }
#pragma unroll
        for (int m = 0; m < 4; ++m)
#pragma unroll
            for (int n = 0; n < 4; ++n)
                acc[m][n] = __builtin_amdgcn_mfma_f32_16x16x32_bf16(
                    af[m], bg[n], acc[m][n], 0, 0, 0);
    }

    float bcol[4];
#pragma unroll
    for (int n = 0; n < 4; ++n) {
        int colg = bx * 128 + wn * 64 + n * 16 + lr;
        bcol[n] = bias ? bias[colg] : 0.f;
    }
#pragma unroll
    for (int m = 0; m < 4; ++m) {
#pragma unroll
        for (int n = 0; n < 4; ++n) {
            int colg = bx * 128 + wn * 64 + n * 16 + lr;
#pragma unroll
            for (int r = 0; r < 4; ++r) {
                int rowg = by * 128 + wm * 64 + m * 16 + lg * 4 + r;
                float v = acc[m][n][r] + bcol[n];
                if (RELU) v = fmaxf(v, 0.f);
                if (OUTBF16) {
                    ((unsigned short*)Cp)[(size_t)rowg * ldc + colg] = f2bf(v);
                } else {
                    float* C = (float*)Cp;
                    if (ACCUM) v += C[(size_t)rowg * ldc + colg];
                    C[(size_t)rowg * ldc + colg] = v;
                }
            }
        }
    }
}

// ---------------------------------------------------------------------------
// Split-bf16 GEMM (fp32-accurate): 3 MFMAs (hh+hl+lh). Output written PACKED:
// CP[row][2048] with 64-col groups interleaved hi|lo (group g: cols g*128..+63
// = hi, +64..+127 = lo).
// ---------------------------------------------------------------------------
__global__ void __launch_bounds__(256)
gemm_bf16_split(const unsigned short* __restrict__ Ah,
                const unsigned short* __restrict__ Al, int lda,
                const unsigned short* __restrict__ BhT,
                const unsigned short* __restrict__ BlT, int ldbt,
                unsigned short* __restrict__ CP, int K,
                const float* __restrict__ bias)
{
    __shared__ short Ash[4096], Asl[4096], Bsh[4096], Bsl[4096];
    const int tid = threadIdx.x;
    const int w = tid >> 6, l = tid & 63;
    const int bx = blockIdx.x, by = blockIdx.y;
    const int wm = w >> 1, wn = w & 1;

    f32x4 acc[4][4] = {};

    size_t a_off[2], b_off[2];
#pragma unroll
    for (int g = 0; g < 2; ++g) {
        int r = w * 32 + g * 16 + (l >> 2);
        int kc = (l & 3) ^ ((r >> 1) & 3);
        a_off[g] = (size_t)(by * 128 + r) * lda + kc * 8;
        b_off[g] = (size_t)(bx * 128 + r) * ldbt + kc * 8;
    }
    const int wb = w * 1024;
    const int lr = l & 15, lg = l >> 4;

    for (int k0 = 0; k0 < K; k0 += 32) {
        __syncthreads();
#pragma unroll
        for (int g = 0; g < 2; ++g) {
            gload_lds16(Ah + a_off[g] + k0, Ash + wb + g * 512);
            gload_lds16(Al + a_off[g] + k0, Asl + wb + g * 512);
            gload_lds16(BhT + b_off[g] + k0, Bsh + wb + g * 512);
            gload_lds16(BlT + b_off[g] + k0, Bsl + wb + g * 512);
        }
        __syncthreads();

        bf16x8 afh[4], afl[4], bgh[4], bgl[4];
#pragma unroll
        for (int m = 0; m < 4; ++m) {
            int row = wm * 64 + m * 16 + lr;
            int off = row * 64 + ((lg ^ ((row >> 1) & 3)) << 4);
            afh[m] = *(const bf16x8*)((const char*)Ash + off);
            afl[m] = *(const bf16x8*)((const char*)Asl + off);
        }
#pragma unroll
        for (int n = 0; n < 4; ++n) {
            int row = wn * 64 + n * 16 + lr;
            int off = row * 64 + ((lg ^ ((row >> 1) & 3)) << 4);
            bgh[n] = *(const bf16x8*)((const char*)Bsh + off);
            bgl[n] = *(const bf16x8*)((const char*)Bsl + off);
        }
#pragma unroll
        for (int m = 0; m < 4; ++m)
#pragma unroll
            for (int n = 0; n < 4; ++n) {
                acc[m][n] = __builtin_amdgcn_mfma_f32_16x16x32_bf16(
                    afh[m], bgh[n], acc[m][n], 0, 0, 0);
                acc[m][n] = __builtin_amdgcn_mfma_f32_16x16x32_bf16(
                    afh[m], bgl[n], acc[m][n], 0, 0, 0);
                acc[m][n] = __builtin_amdgcn_mfma_f32_16x16x32_bf16(
                    afl[m], bgh[n], acc[m][n], 0, 0, 0);
            }
    }

    float bcol[4];
#pragma unroll
    for (int n = 0; n < 4; ++n)
        bcol[n] = bias[bx * 128 + wn * 64 + n * 16 + lr];
    const int cg = bx * 2 + wn;
#pragma unroll
    for (int m = 0; m < 4; ++m)
#pragma unroll
        for (int n = 0; n < 4; ++n) {
            int cwi = n * 16 + lr;
#pragma unroll
            for (int r = 0; r < 4; ++r) {
                int rowg = by * 128 + wm * 64 + m * 16 + lg * 4 + r;
                float v = acc[m][n][r] + bcol[n];
                unsigned short hh = f2bf(v);
                unsigned short ll = f2bf(v - bf2f(hh));
                size_t ad = (size_t)rowg * 2048 + cg * 128 + cwi;
                CP[ad] = hh;
                CP[ad + 64] = ll;
            }
        }
}

// ---------------------------------------------------------------------------
// Gather sampled K rows into packed pre-swizzled KS[bh][2048][128]:
// row j: slots s=0..7 hold hi chunk (s ^ (j&7)), s=8..15 hold lo chunk.
// ---------------------------------------------------------------------------
__global__ void __launch_bounds__(256)
gather_ks(const unsigned short* __restrict__ KP, const int* __restrict__ idxs,
          unsigned short* __restrict__ KS)
{
    const int bh = blockIdx.x, b = bh >> 4, h = bh & 15;
    const int r0 = blockIdx.y * 256;
    const int s = threadIdx.x & 15, jr = threadIdx.x >> 4;
#pragma unroll
    for (int p = 0; p < 16; ++p) {
        int j = r0 + p * 16 + jr;
        int idx = idxs[j];
        int kc = (s & 7) ^ (j & 7);
        const unsigned short* src = KP + (size_t)(b * 2048 + idx) * 2048
                                  + h * 128 + ((s & 8) << 3) + kc * 8;
        *(bf16x8*)(KS + ((size_t)bh * 2048 + j) * 128 + s * 8) =
            *(const bf16x8*)src;
    }
}

// ---------------------------------------------------------------------------
// MFMA M-stat v2: block = (bh, qtile of 256 queries). Q frags in registers
// (staged once); K streamed linearly from pre-swizzled KS, double-buffered.
// ---------------------------------------------------------------------------
__global__ void __launch_bounds__(256)
mstat_mfma2(const unsigned short* __restrict__ QP,
            const unsigned short* __restrict__ KS,
            float* __restrict__ Mout)
{
    __shared__ char lds[32768];
    const int tid = threadIdx.x, w = tid >> 6, l = tid & 63;
    const int bh = blockIdx.x, qt = blockIdx.y;
    const int i0 = qt * 256;
    const int lr = l & 15, lg = l >> 4;

    // ---- stage Q (hi then lo through the same 32 KB), hoist frags ----
    bf16x8 af[4][2][2];   // [m][ks][hi/lo]
#pragma unroll
    for (int half = 0; half < 2; ++half) {
        __syncthreads();
#pragma unroll
        for (int it = 0; it < 8; ++it) {
            int rq = w * 64 + it * 8 + (l >> 3);
            int i = i0 + rq;
            int kc = (l & 7) ^ (rq & 7);
            gload_lds16(QP + (size_t)(bh * 128 + (i >> 4)) * 2048
                           + (i & 15) * 128 + half * 64 + kc * 8,
                        lds + w * 8192 + it * 1024);
        }
        __syncthreads();
#pragma unroll
        for (int m = 0; m < 4; ++m) {
            int rq = w * 64 + m * 16 + lr;
#pragma unroll
            for (int ks = 0; ks < 2; ++ks) {
                int c = (ks * 4 + lg) ^ (rq & 7);
                af[m][ks][half] = *(const bf16x8*)(lds + rq * 128 + (c << 4));
            }
        }
    }
    __syncthreads();   // Q frag reads complete before K staging reuses lds

    float mx[4][4], sm[4][4];
#pragma unroll
    for (int m = 0; m < 4; ++m)
#pragma unroll
        for (int r = 0; r < 4; ++r) { mx[m][r] = -FLT_MAX; sm[m][r] = 0.f; }

    const unsigned short* ksbase = KS + (size_t)bh * (2048 * 128);

    // prologue stage: jt=0 -> buf0
#pragma unroll
    for (int it = 0; it < 4; ++it)
        gload_lds16(ksbase + w * 2048 + it * 512 + l * 8,
                    lds + w * 4096 + it * 1024);

    for (int jt = 0; jt < 32; ++jt) {
        const int cur = jt & 1;
        __syncthreads();   // buf[cur] ready; buf[cur^1] free
        if (jt + 1 < 32) {
#pragma unroll
            for (int it = 0; it < 4; ++it)
                gload_lds16(ksbase + (size_t)(jt + 1) * 8192 + w * 2048 + it * 512 + l * 8,
                            lds + (cur ^ 1) * 16384 + w * 4096 + it * 1024);
        }
        const char* kb = lds + cur * 16384;
#pragma unroll
        for (int n = 0; n < 4; ++n) {
            int jr = n * 16 + lr;
            bf16x8 bgh[2], bgl[2];
#pragma unroll
            for (int ks = 0; ks < 2; ++ks) {
                int c = (ks * 4 + lg) ^ (jr & 7);
                bgh[ks] = *(const bf16x8*)(kb + jr * 256 + (c << 4));
                bgl[ks] = *(const bf16x8*)(kb + jr * 256 + (c << 4) + 128);
            }
#pragma unroll
            for (int m = 0; m < 4; ++m) {
                f32x4 a = {};
                a = __builtin_amdgcn_mfma_f32_16x16x32_bf16(af[m][0][0], bgh[0], a, 0, 0, 0);
                a = __builtin_amdgcn_mfma_f32_16x16x32_bf16(af[m][0][1], bgh[0], a, 0, 0, 0);
                a = __builtin_amdgcn_mfma_f32_16x16x32_bf16(af[m][0][0], bgl[0], a, 0, 0, 0);
                a = __builtin_amdgcn_mfma_f32_16x16x32_bf16(af[m][1][0], bgh[1], a, 0, 0, 0);
                a = __builtin_amdgcn_mfma_f32_16x16x32_bf16(af[m][1][1], bgh[1], a, 0, 0, 0);
                a = __builtin_amdgcn_mfma_f32_16x16x32_bf16(af[m][1][0], bgl[1], a, 0, 0, 0);
#pragma unroll
                for (int r = 0; r < 4; ++r) {
                    mx[m][r] = fmaxf(mx[m][r], a[r]);
                    sm[m][r] += a[r];
                }
            }
        }
    }

    // reduce over the 16 key-columns (lr bits) and write
#pragma unroll
    for (int m = 0; m < 4; ++m)
#pragma unroll
        for (int r = 0; r < 4; ++r) {
            float a = mx[m][r], s = sm[m][r];
#pragma unroll
            for (int mask = 1; mask < 16; mask <<= 1) {
                a = fmaxf(a, __shfl_xor(a, mask));
                s += __shfl_xor(s, mask);
            }
            if (lr == 0) {
                int row = i0 + w * 64 + m * 16 + lg * 4 + r;
                Mout[(size_t)bh * L_SEQ + row] = a - s * (1.0f / 2048.0f);
            }
        }
}

// ---------------------------------------------------------------------------
// transpose + fp32->bf16 (single and split variants)
// ---------------------------------------------------------------------------
__global__ void __launch_bounds__(256)
tconv(const float* __restrict__ in, int R, int C, unsigned short* __restrict__ out)
{
    __shared__ float t[32][33];
    const int bx = blockIdx.x * 32;
    const int by = blockIdx.y * 32;
    const int lx = threadIdx.x & 31, ly = threadIdx.x >> 5;
#pragma unroll
    for (int r = 0; r < 4; ++r)
        t[ly + r * 8][lx] = in[(size_t)(by + ly + r * 8) * C + bx + lx];
    __syncthreads();
#pragma unroll
    for (int r = 0; r < 4; ++r) {
        int oc = ly + r * 8;
        out[(size_t)(bx + oc) * R + by + lx] = f2bf(t[lx][oc]);
    }
}

__global__ void __launch_bounds__(256)
tconv_split(const float* __restrict__ in, int R, int C,
            unsigned short* __restrict__ outh, unsigned short* __restrict__ outl)
{
    __shared__ float t[32][33];
    const int bx = blockIdx.x * 32;
    const int by = blockIdx.y * 32;
    const int lx = threadIdx.x & 31, ly = threadIdx.x >> 5;
#pragma unroll
    for (int r = 0; r < 4; ++r)
        t[ly + r * 8][lx] = in[(size_t)(by + ly + r * 8) * C + bx + lx];
    __syncthreads();
#pragma unroll
    for (int r = 0; r < 4; ++r) {
        int oc = ly + r * 8;
        float f = t[lx][oc];
        unsigned short hh = f2bf(f);
        outh[(size_t)(bx + oc) * R + by + lx] = hh;
        outl[(size_t)(bx + oc) * R + by + lx] = f2bf(f - bf2f(hh));
    }
}

__global__ void __launch_bounds__(256)
split_f32(const float* __restrict__ in, unsigned short* __restrict__ hi,
          unsigned short* __restrict__ lo)
{
    size_t i = ((size_t)blockIdx.x * 256 + threadIdx.x) * 4;
    float4 v = *(const float4*)(in + i);
    ushort4 h, l2;
    h.x = f2bf(v.x); l2.x = f2bf(v.x - bf2f(h.x));
    h.y = f2bf(v.y); l2.y = f2bf(v.y - bf2f(h.y));
    h.z = f2bf(v.z); l2.z = f2bf(v.z - bf2f(h.z));
    h.w = f2bf(v.w); l2.w = f2bf(v.w - bf2f(h.w));
    *(ushort4*)(hi + i) = h;
    *(ushort4*)(lo + i) = l2;
}

// ---------------------------------------------------------------------------
// Top-40 smallest M per bh (lower-index tie-break).
// ---------------------------------------------------------------------------
__global__ void __launch_bounds__(256)
topk_kernel(const float* __restrict__ M, int* __restrict__ Mtop)
{
    __shared__ float mv[L_SEQ];
    __shared__ float wv_[4];
    __shared__ int wi_[4];
    const int bh = blockIdx.x;
    const int tid = threadIdx.x;
    for (int j = tid; j < L_SEQ; j += 256) mv[j] = M[(size_t)bh * L_SEQ + j];
    __syncthreads();
    for (int u = 0; u < U_TOP; ++u) {
        float best = FLT_MAX;
        int bi = 1 << 30;
        for (int j = tid; j < L_SEQ; j += 256) {
            float v = mv[j];
            if (v < best || (v == best && j < bi)) { best = v; bi = j; }
        }
#pragma unroll
        for (int off = 32; off; off >>= 1) {
            float ov = __shfl_down(best, off);
            int oi = __shfl_down(bi, off);
            if (ov < best || (ov == best && oi < bi)) { best = ov; bi = oi; }
        }
        if ((tid & 63) == 0) { wv_[tid >> 6] = best; wi_[tid >> 6] = bi; }
        __syncthreads();
        if (tid == 0) {
            for (int w = 1; w < 4; ++w)
                if (wv_[w] < best || (wv_[w] == best && wi_[w] < bi)) { best = wv_[w]; bi = wi_[w]; }
            Mtop[bh * U_TOP + u] = bi;
            mv[bi] = FLT_MAX;
        }
        __syncthreads();
    }
}

// ---------------------------------------------------------------------------
// FUSED sparse attention: one block per bh; K/V streamed once; compact output
// OUTC[bh][64][64] (rows >= 40 are padding duplicates, discarded downstream).
// ---------------------------------------------------------------------------
__global__ void __launch_bounds__(256)
attn_fused(const unsigned short* __restrict__ QP,  // packed [8192][2048]
           const unsigned short* __restrict__ KP,  // packed [8192][2048]
           const unsigned short* __restrict__ V,   // [8192][1024]
           const int* __restrict__ Mtop,
           unsigned short* __restrict__ OUTC)      // [64][64][64]
{
    __shared__ unsigned short Qs[64 * 64];
    __shared__ unsigned short Ks[128 * 64];
    __shared__ unsigned short Vt[64 * 128];
    __shared__ unsigned short Pb[64 * 128];
    const int bh = blockIdx.x;
    const int b = bh >> 4, h = bh & 15;
    const int tid = threadIdx.x, w = tid >> 6, l = tid & 63;
    const int lr = l & 15, lg = l >> 4;

    // stage Q rows (gathered via Mtop; rows >= 40 duplicate row 39)
#pragma unroll
    for (int is = 0; is < 2; ++is) {
        int row = w * 16 + is * 8 + (l >> 3);
        int u = row < U_TOP ? row : U_TOP - 1;
        int lsel = Mtop[bh * U_TOP + u];
        int cg = (l & 7) ^ (row & 7);
        gload_lds16(QP + (size_t)(bh * 128 + (lsel >> 4)) * 2048
                       + (lsel & 15) * 128 + cg * 8,
                    &Qs[(w * 16 + is * 8) * 64]);
    }
    __syncthreads();

    bf16x8 af[2];
    {
        int row = w * 16 + lr;
#pragma unroll
        for (int ks = 0; ks < 2; ++ks) {
            int c = (ks * 4 + lg) ^ (row & 7);
            af[ks] = *(const bf16x8*)((const char*)Qs + row * 128 + (c << 4));
        }
    }

    float m_run[4], l_run[4];
    f32x4 oacc[4] = {};
#pragma unroll
    for (int r = 0; r < 4; ++r) { m_run[r] = -FLT_MAX; l_run[r] = 0.f; }

    for (int t = 0; t < 16; ++t) {
        const int j0 = t * 128;
        __syncthreads();

#pragma unroll
        for (int is = 0; is < 4; ++is) {
            int kr = w * 32 + is * 8 + (l >> 3);
            int cg = (l & 7) ^ (kr & 7);
            gload_lds16(KP + (size_t)(b * 2048 + j0 + kr) * 2048 + h * 128 + cg * 8,
                        &Ks[(w * 32 + is * 8) * 64]);
        }
        {
            int key = tid & 127, dh = (tid >> 7) * 32;
            const unsigned short* vsrc =
                V + (((size_t)(b * L_SEQ + j0 + key)) << 10) + (h << 6) + dh;
            bf16x8 vv[4];
#pragma unroll
            for (int i = 0; i < 4; ++i) vv[i] = *(const bf16x8*)(vsrc + i * 8);
            int ck = key >> 3, klo = (key & 7) * 2;
#pragma unroll
            for (int i = 0; i < 4; ++i)
#pragma unroll
                for (int j = 0; j < 8; ++j) {
                    int d = dh + i * 8 + j;
                    *(unsigned short*)((char*)Vt + d * 256 +
                                       ((ck ^ (d & 7)) << 4) + klo) =
                        (unsigned short)vv[i][j];
                }
        }
        __syncthreads();

        f32x4 sc[8] = {};
#pragma unroll
        for (int ks = 0; ks < 2; ++ks)
#pragma unroll
            for (int n = 0; n < 8; ++n) {
                int krow = n * 16 + lr;
                int c = (ks * 4 + lg) ^ (krow & 7);
                bf16x8 bf = *(const bf16x8*)((const char*)Ks + krow * 128 + (c << 4));
                sc[n] = __builtin_amdgcn_mfma_f32_16x16x32_bf16(af[ks], bf, sc[n], 0, 0, 0);
            }

        float rs[4];
#pragma unroll
        for (int r = 0; r < 4; ++r) {
            int row = w * 16 + lg * 4 + r;
            float mt = -FLT_MAX;
#pragma unroll
            for (int n = 0; n < 8; ++n) mt = fmaxf(mt, sc[n][r]);
            mt *= 0.125f;
#pragma unroll
            for (int mask = 1; mask < 16; mask <<= 1)
                mt = fmaxf(mt, __shfl_xor(mt, mask));
            float mn = fmaxf(m_run[r], mt);
            rs[r] = expf(m_run[r] - mn);
            float ls = 0.f;
            int rsw = row & 7;
#pragma unroll
            for (int n = 0; n < 8; ++n) {
                float p = expf(sc[n][r] * 0.125f - mn);
                ls += p;
                int ckp = (lr >> 3) + 2 * n;
                *(unsigned short*)((char*)Pb + row * 256 +
                                   ((ckp ^ rsw) << 4) + (lr & 7) * 2) = f2bf(p);
            }
#pragma unroll
            for (int mask = 1; mask < 16; mask <<= 1) ls += __shfl_xor(ls, mask);
            l_run[r] = l_run[r] * rs[r] + ls;
            m_run[r] = mn;
        }
        __syncthreads();

#pragma unroll
        for (int n = 0; n < 4; ++n)
#pragma unroll
            for (int r = 0; r < 4; ++r) oacc[n][r] *= rs[r];
#pragma unroll
        for (int ks = 0; ks < 4; ++ks) {
            int arow = w * 16 + lr;
            int ca = (lg + ks * 4) ^ (arow & 7);
            bf16x8 pa = *(const bf16x8*)((const char*)Pb + arow * 256 + (ca << 4));
#pragma unroll
            for (int n = 0; n < 4; ++n) {
                int d = n * 16 + lr;
                int cb = (lg + ks * 4) ^ (d & 7);
                bf16x8 vb = *(const bf16x8*)((const char*)Vt + d * 256 + (cb << 4));
                oacc[n] = __builtin_amdgcn_mfma_f32_16x16x32_bf16(pa, vb, oacc[n], 0, 0, 0);
            }
        }
    }

    // compact epilogue
#pragma unroll
    for (int r = 0; r < 4; ++r) {
        int row = w * 16 + lg * 4 + r;
        float inv = 1.f / l_run[r];
#pragma unroll
        for (int n = 0; n < 4; ++n)
            OUTC[bh * 4096 + row * 64 + n * 16 + lr] = f2bf(oacc[n][r] * inv);
    }
}

// ---------------------------------------------------------------------------
// Scatter-GEMM: per bh, out_red[40x64] @ wo[h-slice][64x1024] atomically
// added into zeroed Ab (bo folded into LN1).
// ---------------------------------------------------------------------------
__global__ void __launch_bounds__(256)
woscatter(const unsigned short* __restrict__ OUTC,
          const unsigned short* __restrict__ woT,   // [1024][1024]
          const int* __restrict__ Mtop,
          float* __restrict__ Ab)
{
    const int bh = blockIdx.x, b = bh >> 4, h = bh & 15;
    const int tid = threadIdx.x, w = tid >> 6, l = tid & 63;
    const int lr = l & 15, lg = l >> 4;

    bf16x8 af[3][2];
#pragma unroll
    for (int m = 0; m < 3; ++m)
#pragma unroll
        for (int ks = 0; ks < 2; ++ks)
            af[m][ks] = *(const bf16x8*)(OUTC + bh * 4096 + (m * 16 + lr) * 64
                                         + (ks * 4 + lg) * 8);
    int lsel[3][4];
#pragma unroll
    for (int m = 0; m < 3; ++m)
#pragma unroll
        for (int r = 0; r < 4; ++r) {
            int row = m * 16 + lg * 4 + r;
            lsel[m][r] = row < U_TOP ? Mtop[bh * U_TOP + row] : -1;
        }

    for (int nn = 0; nn < 16; ++nn) {
        int ng = w * 16 + nn;
        bf16x8 bg[2];
#pragma unroll
        for (int ks = 0; ks < 2; ++ks)
            bg[ks] = *(const bf16x8*)(woT + (size_t)(ng * 16 + lr) * 1024
                                      + h * 64 + (ks * 4 + lg) * 8);
        f32x4 a[3] = {};
#pragma unroll
        for (int m = 0; m < 3; ++m)
#pragma unroll
            for (int ks = 0; ks < 2; ++ks)
                a[m] = __builtin_amdgcn_mfma_f32_16x16x32_bf16(af[m][ks], bg[ks], a[m], 0, 0, 0);
#pragma unroll
        for (int m = 0; m < 3; ++m)
#pragma unroll
            for (int r = 0; r < 4; ++r)
                if (lsel[m][r] >= 0)
                    atomicAdd(Ab + (size_t)(b * 2048 + lsel[m][r]) * 1024
                              + ng * 16 + lr, a[m][r]);
    }
}

// ---------------------------------------------------------------------------
// Fused residual + LayerNorm; optional extra bias (bo) and bf16 copy.
// ---------------------------------------------------------------------------
template<bool WB16, bool BADD>
__global__ void __launch_bounds__(256)
ln_kernel(const float* __restrict__ X, const float* __restrict__ A,
          const float* __restrict__ badd,
          const float* __restrict__ g, const float* __restrict__ be,
          float* __restrict__ out, unsigned short* __restrict__ out16)
{
    __shared__ float wred[4];
    const int row = blockIdx.x, tid = threadIdx.x;
    float4 xv = *(const float4*)(X + (size_t)row * D_MODEL + tid * 4);
    float4 av = *(const float4*)(A + (size_t)row * D_MODEL + tid * 4);
    float v0 = xv.x + av.x, v1 = xv.y + av.y, v2 = xv.z + av.z, v3 = xv.w + av.w;
    if (BADD) {
        float4 bb = *(const float4*)(badd + tid * 4);
        v0 += bb.x; v1 += bb.y; v2 += bb.z; v3 += bb.w;
    }

    float s = v0 + v1 + v2 + v3;
#pragma unroll
    for (int off = 32; off; off >>= 1) s += __shfl_down(s, off);
    if ((tid & 63) == 0) wred[tid >> 6] = s;
    __syncthreads();
    float mean = (wred[0] + wred[1] + wred[2] + wred[3]) * (1.f / 1024.f);
    __syncthreads();

    float d0 = v0 - mean, d1 = v1 - mean, d2 = v2 - mean, d3 = v3 - mean;
    float q = d0 * d0 + d1 * d1 + d2 * d2 + d3 * d3;
#pragma unroll
    for (int off = 32; off; off >>= 1) q += __shfl_down(q, off);
    if ((tid & 63) == 0) wred[tid >> 6] = q;
    __syncthreads();
    float var = (wred[0] + wred[1] + wred[2] + wred[3]) * (1.f / 1024.f);
    float rstd = rsqrtf(var + 1e-12f);

    float4 gv = *(const float4*)(g + tid * 4);
    float4 bv = *(const float4*)(be + tid * 4);
    float4 o;
    o.x = gv.x * d0 * rstd + bv.x;
    o.y = gv.y * d1 * rstd + bv.y;
    o.z = gv.z * d2 * rstd + bv.z;
    o.w = gv.w * d3 * rstd + bv.w;
    *(float4*)(out + (size_t)row * D_MODEL + tid * 4) = o;
    if (WB16) {
        ushort4 ob;
        ob.x = f2bf(o.x); ob.y = f2bf(o.y); ob.z = f2bf(o.z); ob.w = f2bf(o.w);
        *(ushort4*)(out16 + (size_t)row * D_MODEL + tid * 4) = ob;
    }
}

// ---------------------------------------------------------------------------
extern "C" void kernel_launch(void* const* d_in, const int* in_sizes, int n_in,
                              void* d_out, int out_size, void* d_ws, size_t ws_size,
                              hipStream_t stream)
{
    const float* x   = (const float*)d_in[0];
    const float* wq  = (const float*)d_in[1];
    const float* bq  = (const float*)d_in[2];
    const float* wk  = (const float*)d_in[3];
    const float* bk  = (const float*)d_in[4];
    const float* wv  = (const float*)d_in[5];
    const float* bv  = (const float*)d_in[6];
    const float* wo  = (const float*)d_in[7];
    const float* bo  = (const float*)d_in[8];
    const float* w1  = (const float*)d_in[9];
    const float* b1  = (const float*)d_in[10];
    const float* w2  = (const float*)d_in[11];
    const float* b2  = (const float*)d_in[12];
    const float* g1  = (const float*)d_in[13];
    const float* be1 = (const float*)d_in[14];
    const float* g2  = (const float*)d_in[15];
    const float* be2 = (const float*)d_in[16];
    const int*  idxs = (const int*)d_in[17];

    char* ws  = (char*)d_ws;
    char* dob = (char*)d_out;
    const size_t MB = 1u << 20;

    // ---- workspace (phase-disjoint; peak 128 MB) ----
    unsigned short* QP   = (unsigned short*)(ws);             // 0-32   [qproj..attn]
    unsigned short* KP   = (unsigned short*)(ws + 32 * MB);   // 32-64  [kproj..attn]
    unsigned short* xh   = (unsigned short*)(ws + 64 * MB);   // 64-80  [split..vproj]
    unsigned short* xl   = (unsigned short*)(ws + 80 * MB);   // 80-96  [split..kproj]
    unsigned short* KS   = (unsigned short*)(ws + 64 * MB);   // 64-96  [gather..mstat]
    float*          Ab   = (float*)(ws + 64 * MB);            // 64-96  [memset..ln1]
    float*          x1f  = (float*)(ws + 96 * MB);            // 96-128 [ln1..ln2]
    unsigned short* x1b  = (unsigned short*)(ws);             // 0-16   [ln1..ffn]
    unsigned short* w1T  = (unsigned short*)(ws + 16 * MB);   // 16-24  [tc..ffn]
    unsigned short* w2T  = (unsigned short*)(ws + 24 * MB);   // 24-32  [tc..ffn]
    unsigned short* HIDc = (unsigned short*)(ws + 32 * MB);   // 32-64  [ffn]

    // ---- d_out doubles as scratch until the FFN accumulation ----
    unsigned short* woT  = (unsigned short*)(dob);            // 0-2
    unsigned short* wqhT = (unsigned short*)(dob + 2 * MB);
    unsigned short* wqlT = (unsigned short*)(dob + 4 * MB);
    unsigned short* wkhT = (unsigned short*)(dob + 6 * MB);
    unsigned short* wklT = (unsigned short*)(dob + 8 * MB);
    unsigned short* wvT  = (unsigned short*)(dob + 10 * MB);
    float*          Mb   = (float*)(dob + 12 * MB);           // 512 KB
    int*            Mtop = (int*)(dob + 12 * MB + 768 * 1024);
    unsigned short* Vb   = (unsigned short*)(dob + 13 * MB);  // 13-29
    unsigned short* OUTC = (unsigned short*)(dob + 29 * MB);  // 512 KB
    float*          F    = (float*)d_out;                     // FFN accum

    dim3 blk(256);
    dim3 g_gemm(8, 64);

    // split x; weight transposes
    split_f32<<<dim3(8192), blk, 0, stream>>>(x, xh, xl);
    tconv_split<<<dim3(32, 32), blk, 0, stream>>>(wq, 1024, 1024, wqhT, wqlT);
    tconv_split<<<dim3(32, 32), blk, 0, stream>>>(wk, 1024, 1024, wkhT, wklT);
    tconv<<<dim3(32, 32), blk, 0, stream>>>(wv, 1024, 1024, wvT);
    tconv<<<dim3(32, 32), blk, 0, stream>>>(wo, 1024, 1024, woT);

    // projections: q/k split-packed; v plain bf16
    gemm_bf16_split<<<g_gemm, blk, 0, stream>>>(xh, xl, 1024, wqhT, wqlT, 1024,
                                                QP, 1024, bq);
    gemm_bf16_split<<<g_gemm, blk, 0, stream>>>(xh, xl, 1024, wkhT, wklT, 1024,
                                                KP, 1024, bk);
    gemm_bf16<true, false, false><<<g_gemm, blk, 0, stream>>>(xh, 1024, wvT, 1024,
                                                              Vb, 1024, 1024, bv);

    // selection: pre-gather sampled K, streamed MFMA M-stat, top-40
    gather_ks<<<dim3(64, 8), blk, 0, stream>>>(KP, idxs, KS);
    mstat_mfma2<<<dim3(64, 8), blk, 0, stream>>>(QP, KS, Mb);
    topk_kernel<<<dim3(64), blk, 0, stream>>>(Mb, Mtop);

    // fused sparse attention -> compact OUTC; wo via scatter-GEMM into Ab
    hipMemsetAsync(Ab, 0, 32 * MB, stream);
    attn_fused<<<dim3(N_BH), blk, 0, stream>>>(QP, KP, Vb, Mtop, OUTC);
    woscatter<<<dim3(N_BH), blk, 0, stream>>>(OUTC, woT, Mtop, Ab);

    // x1 = LN(x + Ab + bo)
    ln_kernel<true, true><<<dim3(8192), blk, 0, stream>>>(x, Ab, bo, g1, be1, x1f, x1b);

    // FFN weights
    tconv<<<dim3(128, 32), blk, 0, stream>>>(w1, 1024, 4096, w1T);
    tconv<<<dim3(32, 128), blk, 0, stream>>>(w2, 4096, 1024, w2T);

    // FFN, 2 chunks of 2048 hidden dims
    for (int c = 0; c < 2; ++c) {
        gemm_bf16<true, true, false><<<dim3(16, 64), blk, 0, stream>>>(
            x1b, 1024, w1T + (size_t)c * 2048 * 1024, 1024, HIDc, 2048, 1024, b1 + c * 2048);
        if (c == 0)
            gemm_bf16<false, false, false><<<g_gemm, blk, 0, stream>>>(
                HIDc, 2048, w2T + c * 2048, 4096, F, 1024, 2048, b2);
        else
            gemm_bf16<false, false, true><<<g_gemm, blk, 0, stream>>>(
                HIDc, 2048, w2T + c * 2048, 4096, F, 1024, 2048, nullptr);
    }

    // out = LN(x1 + F)
    ln_kernel<false, false><<<dim3(8192), blk, 0, stream>>>(x1f, F, nullptr, g2, be2,
                                                            (float*)d_out, nullptr);
}

// Round 7
// 751.208 us; speedup vs baseline: 4.3323x; 1.1182x over previous
//
#include <hip/hip_runtime.h>
#include <float.h>
#include <math.h>

#define L_SEQ 2048
#define D_MODEL 1024
#define N_HEAD 16
#define HD 64
#define N_BH 64
#define U_TOP 40

using bf16x8 = __attribute__((ext_vector_type(8))) short;
using f32x4  = __attribute__((ext_vector_type(4))) float;

__device__ __forceinline__ unsigned short f2bf(float f) {
    unsigned int u = __builtin_bit_cast(unsigned int, f);
    u += 0x7fff + ((u >> 16) & 1);   // round-to-nearest-even
    return (unsigned short)(u >> 16);
}
__device__ __forceinline__ float bf2f(unsigned short h) {
    unsigned int u = ((unsigned int)h) << 16;
    return __builtin_bit_cast(float, u);
}

__device__ __forceinline__ void gload_lds16(const void* g, void* l) {
    __builtin_amdgcn_global_load_lds(
        (const __attribute__((address_space(1))) unsigned int*)g,
        (__attribute__((address_space(3))) unsigned int*)l, 16, 0, 0);
}

// ---------------------------------------------------------------------------
// bf16 MFMA GEMM: C = A(bf16) @ BT(bf16)^T, fp32 accum. 128x128 tile, BK=32.
// ---------------------------------------------------------------------------
template<bool OUTBF16, bool RELU, bool ACCUM>
__global__ void __launch_bounds__(256)
gemm_bf16(const unsigned short* __restrict__ A, int lda,
          const unsigned short* __restrict__ BT, int ldbt,
          void* __restrict__ Cp, int ldc, int K,
          const float* __restrict__ bias)
{
    __shared__ short As[4096];
    __shared__ short Bs[4096];
    const int tid = threadIdx.x;
    const int w = tid >> 6, l = tid & 63;
    const int bx = blockIdx.x, by = blockIdx.y;
    const int wm = w >> 1, wn = w & 1;

    f32x4 acc[4][4] = {};

    const unsigned short* a_src[2];
    const unsigned short* b_src[2];
#pragma unroll
    for (int g = 0; g < 2; ++g) {
        int r = w * 32 + g * 16 + (l >> 2);
        int kc = (l & 3) ^ ((r >> 1) & 3);
        a_src[g] = A + (size_t)(by * 128 + r) * lda + kc * 8;
        b_src[g] = BT + (size_t)(bx * 128 + r) * ldbt + kc * 8;
    }
    short* As_w = As + w * 1024;
    short* Bs_w = Bs + w * 1024;

    const int lr = l & 15, lg = l >> 4;

    for (int k0 = 0; k0 < K; k0 += 32) {
        __syncthreads();
        gload_lds16(a_src[0] + k0, As_w);
        gload_lds16(a_src[1] + k0, As_w + 512);
        gload_lds16(b_src[0] + k0, Bs_w);
        gload_lds16(b_src[1] + k0, Bs_w + 512);
        __syncthreads();

        bf16x8 af[4], bg[4];
#pragma unroll
        for (int m = 0; m < 4; ++m) {
            int row = wm * 64 + m * 16 + lr;
            int off = row * 64 + ((lg ^ ((row >> 1) & 3)) << 4);
            af[m] = *(const bf16x8*)((const char*)As + off);
        }
#pragma unroll
        for (int n = 0; n < 4; ++n) {
            int row = wn * 64 + n * 16 + lr;
            int off = row * 64 + ((lg ^ ((row >> 1) & 3)) << 4);
            bg[n] = *(const bf16x8*)((const char*)Bs + off);
        }
#pragma unroll
        for (int m = 0; m < 4; ++m)
#pragma unroll
            for (int n = 0; n < 4; ++n)
                acc[m][n] = __builtin_amdgcn_mfma_f32_16x16x32_bf16(
                    af[m], bg[n], acc[m][n], 0, 0, 0);
    }

    float bcol[4];
#pragma unroll
    for (int n = 0; n < 4; ++n) {
        int colg = bx * 128 + wn * 64 + n * 16 + lr;
        bcol[n] = bias ? bias[colg] : 0.f;
    }
#pragma unroll
    for (int m = 0; m < 4; ++m) {
#pragma unroll
        for (int n = 0; n < 4; ++n) {
            int colg = bx * 128 + wn * 64 + n * 16 + lr;
#pragma unroll
            for (int r = 0; r < 4; ++r) {
                int rowg = by * 128 + wm * 64 + m * 16 + lg * 4 + r;
                float v = acc[m][n][r] + bcol[n];
                if (RELU) v = fmaxf(v, 0.f);
                if (OUTBF16) {
                    ((unsigned short*)Cp)[(size_t)rowg * ldc + colg] = f2bf(v);
                } else {
                    float* C = (float*)Cp;
                    if (ACCUM) v += C[(size_t)rowg * ldc + colg];
                    C[(size_t)rowg * ldc + colg] = v;
                }
            }
        }
    }
}

// ---------------------------------------------------------------------------
// Split-bf16 GEMM (fp32-accurate): 3 MFMAs (hh+hl+lh). Output written PACKED:
// CP[row][2048], 64-col groups interleaved hi|lo.
// ---------------------------------------------------------------------------
__global__ void __launch_bounds__(256)
gemm_bf16_split(const unsigned short* __restrict__ Ah,
                const unsigned short* __restrict__ Al, int lda,
                const unsigned short* __restrict__ BhT,
                const unsigned short* __restrict__ BlT, int ldbt,
                unsigned short* __restrict__ CP, int K,
                const float* __restrict__ bias)
{
    __shared__ short Ash[4096], Asl[4096], Bsh[4096], Bsl[4096];
    const int tid = threadIdx.x;
    const int w = tid >> 6, l = tid & 63;
    const int bx = blockIdx.x, by = blockIdx.y;
    const int wm = w >> 1, wn = w & 1;

    f32x4 acc[4][4] = {};

    size_t a_off[2], b_off[2];
#pragma unroll
    for (int g = 0; g < 2; ++g) {
        int r = w * 32 + g * 16 + (l >> 2);
        int kc = (l & 3) ^ ((r >> 1) & 3);
        a_off[g] = (size_t)(by * 128 + r) * lda + kc * 8;
        b_off[g] = (size_t)(bx * 128 + r) * ldbt + kc * 8;
    }
    const int wb = w * 1024;
    const int lr = l & 15, lg = l >> 4;

    for (int k0 = 0; k0 < K; k0 += 32) {
        __syncthreads();
#pragma unroll
        for (int g = 0; g < 2; ++g) {
            gload_lds16(Ah + a_off[g] + k0, Ash + wb + g * 512);
            gload_lds16(Al + a_off[g] + k0, Asl + wb + g * 512);
            gload_lds16(BhT + b_off[g] + k0, Bsh + wb + g * 512);
            gload_lds16(BlT + b_off[g] + k0, Bsl + wb + g * 512);
        }
        __syncthreads();

        bf16x8 afh[4], afl[4], bgh[4], bgl[4];
#pragma unroll
        for (int m = 0; m < 4; ++m) {
            int row = wm * 64 + m * 16 + lr;
            int off = row * 64 + ((lg ^ ((row >> 1) & 3)) << 4);
            afh[m] = *(const bf16x8*)((const char*)Ash + off);
            afl[m] = *(const bf16x8*)((const char*)Asl + off);
        }
#pragma unroll
        for (int n = 0; n < 4; ++n) {
            int row = wn * 64 + n * 16 + lr;
            int off = row * 64 + ((lg ^ ((row >> 1) & 3)) << 4);
            bgh[n] = *(const bf16x8*)((const char*)Bsh + off);
            bgl[n] = *(const bf16x8*)((const char*)Bsl + off);
        }
#pragma unroll
        for (int m = 0; m < 4; ++m)
#pragma unroll
            for (int n = 0; n < 4; ++n) {
                acc[m][n] = __builtin_amdgcn_mfma_f32_16x16x32_bf16(
                    afh[m], bgh[n], acc[m][n], 0, 0, 0);
                acc[m][n] = __builtin_amdgcn_mfma_f32_16x16x32_bf16(
                    afh[m], bgl[n], acc[m][n], 0, 0, 0);
                acc[m][n] = __builtin_amdgcn_mfma_f32_16x16x32_bf16(
                    afl[m], bgh[n], acc[m][n], 0, 0, 0);
            }
    }

    float bcol[4];
#pragma unroll
    for (int n = 0; n < 4; ++n)
        bcol[n] = bias[bx * 128 + wn * 64 + n * 16 + lr];
    const int cg = bx * 2 + wn;
#pragma unroll
    for (int m = 0; m < 4; ++m)
#pragma unroll
        for (int n = 0; n < 4; ++n) {
            int cwi = n * 16 + lr;
#pragma unroll
            for (int r = 0; r < 4; ++r) {
                int rowg = by * 128 + wm * 64 + m * 16 + lg * 4 + r;
                float v = acc[m][n][r] + bcol[n];
                unsigned short hh = f2bf(v);
                unsigned short ll = f2bf(v - bf2f(hh));
                size_t ad = (size_t)rowg * 2048 + cg * 128 + cwi;
                CP[ad] = hh;
                CP[ad + 64] = ll;
            }
        }
}

// ---------------------------------------------------------------------------
// Merged preprocessing: x split + 4 weight transposes in ONE dispatch.
// blocks [0,8192): split_f32 rows; [8192,9216): wq split-T; [9216,10240):
// wk split-T; [10240,11264): wv T; [11264,12288): wo T.
// ---------------------------------------------------------------------------
__global__ void __launch_bounds__(256)
preprocess(const float* __restrict__ x,
           const float* __restrict__ wq, const float* __restrict__ wk,
           const float* __restrict__ wv, const float* __restrict__ wo,
           unsigned short* __restrict__ xh, unsigned short* __restrict__ xl,
           unsigned short* __restrict__ wqhT, unsigned short* __restrict__ wqlT,
           unsigned short* __restrict__ wkhT, unsigned short* __restrict__ wklT,
           unsigned short* __restrict__ wvT, unsigned short* __restrict__ woT)
{
    __shared__ float t[32][33];
    const int bid = blockIdx.x, tid = threadIdx.x;
    if (bid < 8192) {
        size_t i = (size_t)bid * 1024 + tid * 4;
        float4 v = *(const float4*)(x + i);
        ushort4 h, l2;
        h.x = f2bf(v.x); l2.x = f2bf(v.x - bf2f(h.x));
        h.y = f2bf(v.y); l2.y = f2bf(v.y - bf2f(h.y));
        h.z = f2bf(v.z); l2.z = f2bf(v.z - bf2f(h.z));
        h.w = f2bf(v.w); l2.w = f2bf(v.w - bf2f(h.w));
        *(ushort4*)(xh + i) = h;
        *(ushort4*)(xl + i) = l2;
        return;
    }
    const int grp = (bid - 8192) >> 10;     // 0:wq 1:wk 2:wv 3:wo
    const int b2 = (bid - 8192) & 1023;
    const int bx = (b2 & 31) * 32, by = (b2 >> 5) * 32;
    const float* in = (grp == 0) ? wq : (grp == 1) ? wk : (grp == 2) ? wv : wo;
    const int lx = tid & 31, ly = tid >> 5;
#pragma unroll
    for (int r = 0; r < 4; ++r)
        t[ly + r * 8][lx] = in[(size_t)(by + ly + r * 8) * 1024 + bx + lx];
    __syncthreads();
#pragma unroll
    for (int r = 0; r < 4; ++r) {
        int oc = ly + r * 8;
        float f = t[lx][oc];
        size_t od = (size_t)(bx + oc) * 1024 + by + lx;
        unsigned short hh = f2bf(f);
        if (grp == 0) { wqhT[od] = hh; wqlT[od] = f2bf(f - bf2f(hh)); }
        else if (grp == 1) { wkhT[od] = hh; wklT[od] = f2bf(f - bf2f(hh)); }
        else if (grp == 2) wvT[od] = hh;
        else woT[od] = hh;
    }
}

// plain transpose+convert (FFN weights)
__global__ void __launch_bounds__(256)
tconv(const float* __restrict__ in, int R, int C, unsigned short* __restrict__ out)
{
    __shared__ float t[32][33];
    const int bx = blockIdx.x * 32;
    const int by = blockIdx.y * 32;
    const int lx = threadIdx.x & 31, ly = threadIdx.x >> 5;
#pragma unroll
    for (int r = 0; r < 4; ++r)
        t[ly + r * 8][lx] = in[(size_t)(by + ly + r * 8) * C + bx + lx];
    __syncthreads();
#pragma unroll
    for (int r = 0; r < 4; ++r) {
        int oc = ly + r * 8;
        out[(size_t)(bx + oc) * R + by + lx] = f2bf(t[lx][oc]);
    }
}

// ---------------------------------------------------------------------------
// Gather sampled K rows into packed pre-swizzled KS[bh][2048][128].
// ---------------------------------------------------------------------------
__global__ void __launch_bounds__(256)
gather_ks(const unsigned short* __restrict__ KP, const int* __restrict__ idxs,
          unsigned short* __restrict__ KS)
{
    const int bh = blockIdx.x, b = bh >> 4, h = bh & 15;
    const int r0 = blockIdx.y * 256;
    const int s = threadIdx.x & 15, jr = threadIdx.x >> 4;
#pragma unroll
    for (int p = 0; p < 16; ++p) {
        int j = r0 + p * 16 + jr;
        int idx = idxs[j];
        int kc = (s & 7) ^ (j & 7);
        const unsigned short* src = KP + (size_t)(b * 2048 + idx) * 2048
                                  + h * 128 + ((s & 8) << 3) + kc * 8;
        *(bf16x8*)(KS + ((size_t)bh * 2048 + j) * 128 + s * 8) =
            *(const bf16x8*)src;
    }
}

// ---------------------------------------------------------------------------
// MFMA M-stat v3: block = (bh, qtile of 128 queries) -> 1024 blocks (4/CU).
// Q frags in registers; K streamed from pre-swizzled KS, double-buffered.
// ---------------------------------------------------------------------------
__global__ void __launch_bounds__(256)
mstat_mfma2(const unsigned short* __restrict__ QP,
            const unsigned short* __restrict__ KS,
            float* __restrict__ Mout)
{
    __shared__ char lds[32768];
    const int tid = threadIdx.x, w = tid >> 6, l = tid & 63;
    const int bh = blockIdx.x, qt = blockIdx.y;
    const int i0 = qt * 128;
    const int lr = l & 15, lg = l >> 4;

    // ---- stage Q (hi then lo through lds[0..16K)), hoist frags ----
    bf16x8 af[2][2][2];   // [m][ks][hi/lo]
#pragma unroll
    for (int half = 0; half < 2; ++half) {
        __syncthreads();
#pragma unroll
        for (int it = 0; it < 4; ++it) {
            int rq = w * 32 + it * 8 + (l >> 3);
            int i = i0 + rq;
            int kc = (l & 7) ^ (rq & 7);
            gload_lds16(QP + (size_t)(bh * 128 + (i >> 4)) * 2048
                           + (i & 15) * 128 + half * 64 + kc * 8,
                        lds + w * 4096 + it * 1024);
        }
        __syncthreads();
#pragma unroll
        for (int m = 0; m < 2; ++m) {
            int rq = w * 32 + m * 16 + lr;
#pragma unroll
            for (int ks = 0; ks < 2; ++ks) {
                int c = (ks * 4 + lg) ^ (rq & 7);
                af[m][ks][half] = *(const bf16x8*)(lds + rq * 128 + (c << 4));
            }
        }
    }
    __syncthreads();   // Q frag reads complete before K staging reuses lds

    float mx[2][4], sm[2][4];
#pragma unroll
    for (int m = 0; m < 2; ++m)
#pragma unroll
        for (int r = 0; r < 4; ++r) { mx[m][r] = -FLT_MAX; sm[m][r] = 0.f; }

    const unsigned short* ksbase = KS + (size_t)bh * (2048 * 128);

    // prologue: jt=0 -> buf0
#pragma unroll
    for (int it = 0; it < 4; ++it)
        gload_lds16(ksbase + w * 2048 + it * 512 + l * 8,
                    lds + w * 4096 + it * 1024);

    for (int jt = 0; jt < 32; ++jt) {
        const int cur = jt & 1;
        __syncthreads();   // buf[cur] ready; buf[cur^1] free
        if (jt + 1 < 32) {
#pragma unroll
            for (int it = 0; it < 4; ++it)
                gload_lds16(ksbase + (size_t)(jt + 1) * 8192 + w * 2048 + it * 512 + l * 8,
                            lds + (cur ^ 1) * 16384 + w * 4096 + it * 1024);
        }
        const char* kb = lds + cur * 16384;
#pragma unroll
        for (int n = 0; n < 4; ++n) {
            int jr = n * 16 + lr;
            bf16x8 bgh[2], bgl[2];
#pragma unroll
            for (int ks = 0; ks < 2; ++ks) {
                int c = (ks * 4 + lg) ^ (jr & 7);
                bgh[ks] = *(const bf16x8*)(kb + jr * 256 + (c << 4));
                bgl[ks] = *(const bf16x8*)(kb + jr * 256 + (c << 4) + 128);
            }
#pragma unroll
            for (int m = 0; m < 2; ++m) {
                f32x4 a = {};
                a = __builtin_amdgcn_mfma_f32_16x16x32_bf16(af[m][0][0], bgh[0], a, 0, 0, 0);
                a = __builtin_amdgcn_mfma_f32_16x16x32_bf16(af[m][0][1], bgh[0], a, 0, 0, 0);
                a = __builtin_amdgcn_mfma_f32_16x16x32_bf16(af[m][0][0], bgl[0], a, 0, 0, 0);
                a = __builtin_amdgcn_mfma_f32_16x16x32_bf16(af[m][1][0], bgh[1], a, 0, 0, 0);
                a = __builtin_amdgcn_mfma_f32_16x16x32_bf16(af[m][1][1], bgh[1], a, 0, 0, 0);
                a = __builtin_amdgcn_mfma_f32_16x16x32_bf16(af[m][1][0], bgl[1], a, 0, 0, 0);
#pragma unroll
                for (int r = 0; r < 4; ++r) {
                    mx[m][r] = fmaxf(mx[m][r], a[r]);
                    sm[m][r] += a[r];
                }
            }
        }
    }

#pragma unroll
    for (int m = 0; m < 2; ++m)
#pragma unroll
        for (int r = 0; r < 4; ++r) {
            float a = mx[m][r], s = sm[m][r];
#pragma unroll
            for (int mask = 1; mask < 16; mask <<= 1) {
                a = fmaxf(a, __shfl_xor(a, mask));
                s += __shfl_xor(s, mask);
            }
            if (lr == 0) {
                int row = i0 + w * 32 + m * 16 + lg * 4 + r;
                Mout[(size_t)bh * L_SEQ + row] = a - s * (1.0f / 2048.0f);
            }
        }
}

// ---------------------------------------------------------------------------
// Top-40 smallest M per bh (lower-index tie-break).
// ---------------------------------------------------------------------------
__global__ void __launch_bounds__(256)
topk_kernel(const float* __restrict__ M, int* __restrict__ Mtop)
{
    __shared__ float mv[L_SEQ];
    __shared__ float wv_[4];
    __shared__ int wi_[4];
    const int bh = blockIdx.x;
    const int tid = threadIdx.x;
    for (int j = tid; j < L_SEQ; j += 256) mv[j] = M[(size_t)bh * L_SEQ + j];
    __syncthreads();
    for (int u = 0; u < U_TOP; ++u) {
        float best = FLT_MAX;
        int bi = 1 << 30;
        for (int j = tid; j < L_SEQ; j += 256) {
            float v = mv[j];
            if (v < best || (v == best && j < bi)) { best = v; bi = j; }
        }
#pragma unroll
        for (int off = 32; off; off >>= 1) {
            float ov = __shfl_down(best, off);
            int oi = __shfl_down(bi, off);
            if (ov < best || (ov == best && oi < bi)) { best = ov; bi = oi; }
        }
        if ((tid & 63) == 0) { wv_[tid >> 6] = best; wi_[tid >> 6] = bi; }
        __syncthreads();
        if (tid == 0) {
            for (int w = 1; w < 4; ++w)
                if (wv_[w] < best || (wv_[w] == best && wi_[w] < bi)) { best = wv_[w]; bi = wi_[w]; }
            Mtop[bh * U_TOP + u] = bi;
            mv[bi] = FLT_MAX;
        }
        __syncthreads();
    }
}

// ---------------------------------------------------------------------------
// FUSED sparse attention, KV-SPLIT: grid (4 splits, 64 bh) = 256 blocks.
// Split s handles keys [s*512, s*512+512). Emits unnormalized bf16 partial
// output PART[(bh*4+s)][64][64] and per-row (m, l) in ML.
// ---------------------------------------------------------------------------
__global__ void __launch_bounds__(256)
attn_fused(const unsigned short* __restrict__ QP,  // packed [8192][2048]
           const unsigned short* __restrict__ KP,  // packed [8192][2048]
           const unsigned short* __restrict__ V,   // [8192][1024]
           const int* __restrict__ Mtop,
           unsigned short* __restrict__ PART,      // [256][64][64] bf16
           float* __restrict__ ML)                 // [256][64][2]
{
    __shared__ unsigned short Qs[64 * 64];
    __shared__ unsigned short Ks[128 * 64];
    __shared__ unsigned short Vt[64 * 128];
    __shared__ unsigned short Pb[64 * 128];
    const int sp = blockIdx.x, bh = blockIdx.y;
    const int b = bh >> 4, h = bh & 15;
    const int tid = threadIdx.x, w = tid >> 6, l = tid & 63;
    const int lr = l & 15, lg = l >> 4;

    // stage Q rows (gathered via Mtop; rows >= 40 duplicate row 39)
#pragma unroll
    for (int is = 0; is < 2; ++is) {
        int row = w * 16 + is * 8 + (l >> 3);
        int u = row < U_TOP ? row : U_TOP - 1;
        int lsel = Mtop[bh * U_TOP + u];
        int cg = (l & 7) ^ (row & 7);
        gload_lds16(QP + (size_t)(bh * 128 + (lsel >> 4)) * 2048
                       + (lsel & 15) * 128 + cg * 8,
                    &Qs[(w * 16 + is * 8) * 64]);
    }
    __syncthreads();

    bf16x8 af[2];
    {
        int row = w * 16 + lr;
#pragma unroll
        for (int ks = 0; ks < 2; ++ks) {
            int c = (ks * 4 + lg) ^ (row & 7);
            af[ks] = *(const bf16x8*)((const char*)Qs + row * 128 + (c << 4));
        }
    }

    float m_run[4], l_run[4];
    f32x4 oacc[4] = {};
#pragma unroll
    for (int r = 0; r < 4; ++r) { m_run[r] = -FLT_MAX; l_run[r] = 0.f; }

    for (int t = sp * 4; t < sp * 4 + 4; ++t) {
        const int j0 = t * 128;
        __syncthreads();

#pragma unroll
        for (int is = 0; is < 4; ++is) {
            int kr = w * 32 + is * 8 + (l >> 3);
            int cg = (l & 7) ^ (kr & 7);
            gload_lds16(KP + (size_t)(b * 2048 + j0 + kr) * 2048 + h * 128 + cg * 8,
                        &Ks[(w * 32 + is * 8) * 64]);
        }
        {
            int key = tid & 127, dh = (tid >> 7) * 32;
            const unsigned short* vsrc =
                V + (((size_t)(b * L_SEQ + j0 + key)) << 10) + (h << 6) + dh;
            bf16x8 vv[4];
#pragma unroll
            for (int i = 0; i < 4; ++i) vv[i] = *(const bf16x8*)(vsrc + i * 8);
            int ck = key >> 3, klo = (key & 7) * 2;
#pragma unroll
            for (int i = 0; i < 4; ++i)
#pragma unroll
                for (int j = 0; j < 8; ++j) {
                    int d = dh + i * 8 + j;
                    *(unsigned short*)((char*)Vt + d * 256 +
                                       ((ck ^ (d & 7)) << 4) + klo) =
                        (unsigned short)vv[i][j];
                }
        }
        __syncthreads();

        f32x4 sc[8] = {};
#pragma unroll
        for (int ks = 0; ks < 2; ++ks)
#pragma unroll
            for (int n = 0; n < 8; ++n) {
                int krow = n * 16 + lr;
                int c = (ks * 4 + lg) ^ (krow & 7);
                bf16x8 bf = *(const bf16x8*)((const char*)Ks + krow * 128 + (c << 4));
                sc[n] = __builtin_amdgcn_mfma_f32_16x16x32_bf16(af[ks], bf, sc[n], 0, 0, 0);
            }

        float rs[4];
#pragma unroll
        for (int r = 0; r < 4; ++r) {
            int row = w * 16 + lg * 4 + r;
            float mt = -FLT_MAX;
#pragma unroll
            for (int n = 0; n < 8; ++n) mt = fmaxf(mt, sc[n][r]);
            mt *= 0.125f;
#pragma unroll
            for (int mask = 1; mask < 16; mask <<= 1)
                mt = fmaxf(mt, __shfl_xor(mt, mask));
            float mn = fmaxf(m_run[r], mt);
            rs[r] = expf(m_run[r] - mn);
            float ls = 0.f;
            int rsw = row & 7;
#pragma unroll
            for (int n = 0; n < 8; ++n) {
                float p = expf(sc[n][r] * 0.125f - mn);
                ls += p;
                int ckp = (lr >> 3) + 2 * n;
                *(unsigned short*)((char*)Pb + row * 256 +
                                   ((ckp ^ rsw) << 4) + (lr & 7) * 2) = f2bf(p);
            }
#pragma unroll
            for (int mask = 1; mask < 16; mask <<= 1) ls += __shfl_xor(ls, mask);
            l_run[r] = l_run[r] * rs[r] + ls;
            m_run[r] = mn;
        }
        __syncthreads();

#pragma unroll
        for (int n = 0; n < 4; ++n)
#pragma unroll
            for (int r = 0; r < 4; ++r) oacc[n][r] *= rs[r];
#pragma unroll
        for (int ks = 0; ks < 4; ++ks) {
            int arow = w * 16 + lr;
            int ca = (lg + ks * 4) ^ (arow & 7);
            bf16x8 pa = *(const bf16x8*)((const char*)Pb + arow * 256 + (ca << 4));
#pragma unroll
            for (int n = 0; n < 4; ++n) {
                int d = n * 16 + lr;
                int cb = (lg + ks * 4) ^ (d & 7);
                bf16x8 vb = *(const bf16x8*)((const char*)Vt + d * 256 + (cb << 4));
                oacc[n] = __builtin_amdgcn_mfma_f32_16x16x32_bf16(pa, vb, oacc[n], 0, 0, 0);
            }
        }
    }

    // partial epilogue: unnormalized o, plus (m, l) per row
    const int pbase = (bh * 4 + sp) * 64;
#pragma unroll
    for (int r = 0; r < 4; ++r) {
        int row = w * 16 + lg * 4 + r;
#pragma unroll
        for (int n = 0; n < 4; ++n)
            PART[(size_t)(pbase + row) * 64 + n * 16 + lr] = f2bf(oacc[n][r]);
        if (lr == 0) {
            ML[(size_t)(pbase + row) * 2 + 0] = m_run[r];
            ML[(size_t)(pbase + row) * 2 + 1] = l_run[r];
        }
    }
}

// ---------------------------------------------------------------------------
// Combine KV-splits + scatter-GEMM: per bh, combined out_red[40x64] @
// wo[h-slice] atomically added into zeroed Ab (bo folded into LN1).
// ---------------------------------------------------------------------------
__global__ void __launch_bounds__(256)
woscatter(const unsigned short* __restrict__ PART,
          const float* __restrict__ ML,
          const unsigned short* __restrict__ woT,   // [1024][1024]
          const int* __restrict__ Mtop,
          float* __restrict__ Ab)
{
    const int bh = blockIdx.x, b = bh >> 4, h = bh & 15;
    const int tid = threadIdx.x, w = tid >> 6, l = tid & 63;
    const int lr = l & 15, lg = l >> 4;

    // combine 4 splits into A-fragments (row = m*16+lr, dims (ks*4+lg)*8..+8)
    bf16x8 af[3][2];
#pragma unroll
    for (int m = 0; m < 3; ++m) {
        int row = m * 16 + lr;
        float ms[4], ls[4];
#pragma unroll
        for (int s = 0; s < 4; ++s) {
            ms[s] = ML[(size_t)((bh * 4 + s) * 64 + row) * 2 + 0];
            ls[s] = ML[(size_t)((bh * 4 + s) * 64 + row) * 2 + 1];
        }
        float M = fmaxf(fmaxf(ms[0], ms[1]), fmaxf(ms[2], ms[3]));
        float wgt[4], L = 0.f;
#pragma unroll
        for (int s = 0; s < 4; ++s) { wgt[s] = expf(ms[s] - M); L += wgt[s] * ls[s]; }
        float invL = 1.f / L;
#pragma unroll
        for (int ks = 0; ks < 2; ++ks) {
            float a8[8] = {};
#pragma unroll
            for (int s = 0; s < 4; ++s) {
                bf16x8 po = *(const bf16x8*)(PART +
                    (size_t)((bh * 4 + s) * 64 + row) * 64 + (ks * 4 + lg) * 8);
#pragma unroll
                for (int j = 0; j < 8; ++j)
                    a8[j] += wgt[s] * bf2f((unsigned short)po[j]);
            }
            bf16x8 fr;
#pragma unroll
            for (int j = 0; j < 8; ++j) fr[j] = (short)f2bf(a8[j] * invL);
            af[m][ks] = fr;
        }
    }

    int lsel[3][4];
#pragma unroll
    for (int m = 0; m < 3; ++m)
#pragma unroll
        for (int r = 0; r < 4; ++r) {
            int row = m * 16 + lg * 4 + r;
            lsel[m][r] = row < U_TOP ? Mtop[bh * U_TOP + row] : -1;
        }

    for (int nn = 0; nn < 16; ++nn) {
        int ng = w * 16 + nn;
        bf16x8 bg[2];
#pragma unroll
        for (int ks = 0; ks < 2; ++ks)
            bg[ks] = *(const bf16x8*)(woT + (size_t)(ng * 16 + lr) * 1024
                                      + h * 64 + (ks * 4 + lg) * 8);
        f32x4 a[3] = {};
#pragma unroll
        for (int m = 0; m < 3; ++m)
#pragma unroll
            for (int ks = 0; ks < 2; ++ks)
                a[m] = __builtin_amdgcn_mfma_f32_16x16x32_bf16(af[m][ks], bg[ks], a[m], 0, 0, 0);
#pragma unroll
        for (int m = 0; m < 3; ++m)
#pragma unroll
            for (int r = 0; r < 4; ++r)
                if (lsel[m][r] >= 0)
                    atomicAdd(Ab + (size_t)(b * 2048 + lsel[m][r]) * 1024
                              + ng * 16 + lr, a[m][r]);
    }
}

// ---------------------------------------------------------------------------
// Fused residual + LayerNorm; optional extra bias (bo) and bf16 copy.
// ---------------------------------------------------------------------------
template<bool WB16, bool BADD>
__global__ void __launch_bounds__(256)
ln_kernel(const float* __restrict__ X, const float* __restrict__ A,
          const float* __restrict__ badd,
          const float* __restrict__ g, const float* __restrict__ be,
          float* __restrict__ out, unsigned short* __restrict__ out16)
{
    __shared__ float wred[4];
    const int row = blockIdx.x, tid = threadIdx.x;
    float4 xv = *(const float4*)(X + (size_t)row * D_MODEL + tid * 4);
    float4 av = *(const float4*)(A + (size_t)row * D_MODEL + tid * 4);
    float v0 = xv.x + av.x, v1 = xv.y + av.y, v2 = xv.z + av.z, v3 = xv.w + av.w;
    if (BADD) {
        float4 bb = *(const float4*)(badd + tid * 4);
        v0 += bb.x; v1 += bb.y; v2 += bb.z; v3 += bb.w;
    }

    float s = v0 + v1 + v2 + v3;
#pragma unroll
    for (int off = 32; off; off >>= 1) s += __shfl_down(s, off);
    if ((tid & 63) == 0) wred[tid >> 6] = s;
    __syncthreads();
    float mean = (wred[0] + wred[1] + wred[2] + wred[3]) * (1.f / 1024.f);
    __syncthreads();

    float d0 = v0 - mean, d1 = v1 - mean, d2 = v2 - mean, d3 = v3 - mean;
    float q = d0 * d0 + d1 * d1 + d2 * d2 + d3 * d3;
#pragma unroll
    for (int off = 32; off; off >>= 1) q += __shfl_down(q, off);
    if ((tid & 63) == 0) wred[tid >> 6] = q;
    __syncthreads();
    float var = (wred[0] + wred[1] + wred[2] + wred[3]) * (1.f / 1024.f);
    float rstd = rsqrtf(var + 1e-12f);

    float4 gv = *(const float4*)(g + tid * 4);
    float4 bv = *(const float4*)(be + tid * 4);
    float4 o;
    o.x = gv.x * d0 * rstd + bv.x;
    o.y = gv.y * d1 * rstd + bv.y;
    o.z = gv.z * d2 * rstd + bv.z;
    o.w = gv.w * d3 * rstd + bv.w;
    *(float4*)(out + (size_t)row * D_MODEL + tid * 4) = o;
    if (WB16) {
        ushort4 ob;
        ob.x = f2bf(o.x); ob.y = f2bf(o.y); ob.z = f2bf(o.z); ob.w = f2bf(o.w);
        *(ushort4*)(out16 + (size_t)row * D_MODEL + tid * 4) = ob;
    }
}

// ---------------------------------------------------------------------------
extern "C" void kernel_launch(void* const* d_in, const int* in_sizes, int n_in,
                              void* d_out, int out_size, void* d_ws, size_t ws_size,
                              hipStream_t stream)
{
    const float* x   = (const float*)d_in[0];
    const float* wq  = (const float*)d_in[1];
    const float* bq  = (const float*)d_in[2];
    const float* wk  = (const float*)d_in[3];
    const float* bk  = (const float*)d_in[4];
    const float* wv  = (const float*)d_in[5];
    const float* bv  = (const float*)d_in[6];
    const float* wo  = (const float*)d_in[7];
    const float* bo  = (const float*)d_in[8];
    const float* w1  = (const float*)d_in[9];
    const float* b1  = (const float*)d_in[10];
    const float* w2  = (const float*)d_in[11];
    const float* b2  = (const float*)d_in[12];
    const float* g1  = (const float*)d_in[13];
    const float* be1 = (const float*)d_in[14];
    const float* g2  = (const float*)d_in[15];
    const float* be2 = (const float*)d_in[16];
    const int*  idxs = (const int*)d_in[17];

    char* ws  = (char*)d_ws;
    char* dob = (char*)d_out;
    const size_t MB = 1u << 20;

    // ---- workspace (phase-disjoint; peak 128 MB) ----
    unsigned short* QP   = (unsigned short*)(ws);             // 0-32   [qproj..attn]
    unsigned short* KP   = (unsigned short*)(ws + 32 * MB);   // 32-64  [kproj..attn]
    unsigned short* xh   = (unsigned short*)(ws + 64 * MB);   // 64-80  [pre..vproj]
    unsigned short* xl   = (unsigned short*)(ws + 80 * MB);   // 80-96  [pre..kproj]
    unsigned short* KS   = (unsigned short*)(ws + 64 * MB);   // 64-96  [gather..mstat]
    float*          Ab   = (float*)(ws + 64 * MB);            // 64-96  [memset..ln1]
    float*          x1f  = (float*)(ws + 96 * MB);            // 96-128 [ln1..ln2]
    unsigned short* x1b  = (unsigned short*)(ws);             // 0-16   [ln1..ffn]
    unsigned short* w1T  = (unsigned short*)(ws + 16 * MB);   // 16-24  [tc..ffn]
    unsigned short* w2T  = (unsigned short*)(ws + 24 * MB);   // 24-32  [tc..ffn]
    unsigned short* HID  = (unsigned short*)(ws + 32 * MB);   // 32-96  [ffn] 64MB

    // ---- d_out doubles as scratch until the FFN w2 GEMM ----
    unsigned short* woT  = (unsigned short*)(dob);            // 0-2
    unsigned short* wqhT = (unsigned short*)(dob + 2 * MB);
    unsigned short* wqlT = (unsigned short*)(dob + 4 * MB);
    unsigned short* wkhT = (unsigned short*)(dob + 6 * MB);
    unsigned short* wklT = (unsigned short*)(dob + 8 * MB);
    unsigned short* wvT  = (unsigned short*)(dob + 10 * MB);
    float*          Mb   = (float*)(dob + 12 * MB);           // 512 KB
    int*            Mtop = (int*)(dob + 12 * MB + 768 * 1024);
    unsigned short* Vb   = (unsigned short*)(dob + 13 * MB);  // 13-29
    unsigned short* PART = (unsigned short*)(dob + 29 * MB);  // 29-31 (bf16)
    float*          ML   = (float*)(dob + 31 * MB);           // 128 KB
    float*          F    = (float*)d_out;                     // FFN output

    dim3 blk(256);
    dim3 g_gemm(8, 64);

    // merged preprocessing: x split + wq/wk split-T + wv/wo T (one dispatch)
    preprocess<<<dim3(12288), blk, 0, stream>>>(x, wq, wk, wv, wo,
                                                xh, xl, wqhT, wqlT, wkhT, wklT,
                                                wvT, woT);

    // projections: q/k split-packed; v plain bf16
    gemm_bf16_split<<<g_gemm, blk, 0, stream>>>(xh, xl, 1024, wqhT, wqlT, 1024,
                                                QP, 1024, bq);
    gemm_bf16_split<<<g_gemm, blk, 0, stream>>>(xh, xl, 1024, wkhT, wklT, 1024,
                                                KP, 1024, bk);
    gemm_bf16<true, false, false><<<g_gemm, blk, 0, stream>>>(xh, 1024, wvT, 1024,
                                                              Vb, 1024, 1024, bv);

    // selection: pre-gather sampled K, streamed MFMA M-stat (128-q blocks), top-40
    gather_ks<<<dim3(64, 8), blk, 0, stream>>>(KP, idxs, KS);
    mstat_mfma2<<<dim3(64, 16), blk, 0, stream>>>(QP, KS, Mb);
    topk_kernel<<<dim3(64), blk, 0, stream>>>(Mb, Mtop);

    // fused sparse attention, kv-split 4x -> partials; combine+wo in woscatter
    hipMemsetAsync(Ab, 0, 32 * MB, stream);
    attn_fused<<<dim3(4, N_BH), blk, 0, stream>>>(QP, KP, Vb, Mtop, PART, ML);
    woscatter<<<dim3(N_BH), blk, 0, stream>>>(PART, ML, woT, Mtop, Ab);

    // x1 = LN(x + Ab + bo)
    ln_kernel<true, true><<<dim3(8192), blk, 0, stream>>>(x, Ab, bo, g1, be1, x1f, x1b);

    // FFN weights
    tconv<<<dim3(128, 32), blk, 0, stream>>>(w1, 1024, 4096, w1T);
    tconv<<<dim3(32, 128), blk, 0, stream>>>(w2, 4096, 1024, w2T);

    // FFN, single chunk: HID = relu(x1@w1+b1); F = HID@w2 + b2 (written once)
    gemm_bf16<true, true, false><<<dim3(32, 64), blk, 0, stream>>>(
        x1b, 1024, w1T, 1024, HID, 4096, 1024, b1);
    gemm_bf16<false, false, false><<<g_gemm, blk, 0, stream>>>(
        HID, 4096, w2T, 4096, F, 1024, 4096, b2);

    // out = LN(x1 + F)
    ln_kernel<false, false><<<dim3(8192), blk, 0, stream>>>(x1f, F, nullptr, g2, be2,
                                                            (float*)d_out, nullptr);
}

// Round 8
// 737.753 us; speedup vs baseline: 4.4113x; 1.0182x over previous
//
#include <hip/hip_runtime.h>
#include <float.h>
#include <math.h>

#define L_SEQ 2048
#define D_MODEL 1024
#define N_HEAD 16
#define HD 64
#define N_BH 64
#define U_TOP 40

using bf16x8 = __attribute__((ext_vector_type(8))) short;
using f32x4  = __attribute__((ext_vector_type(4))) float;

__device__ __forceinline__ unsigned short f2bf(float f) {
    unsigned int u = __builtin_bit_cast(unsigned int, f);
    u += 0x7fff + ((u >> 16) & 1);   // round-to-nearest-even
    return (unsigned short)(u >> 16);
}
__device__ __forceinline__ float bf2f(unsigned short h) {
    unsigned int u = ((unsigned int)h) << 16;
    return __builtin_bit_cast(float, u);
}

__device__ __forceinline__ void gload_lds16(const void* g, void* l) {
    __builtin_amdgcn_global_load_lds(
        (const __attribute__((address_space(1))) unsigned int*)g,
        (__attribute__((address_space(3))) unsigned int*)l, 16, 0, 0);
}

// XCD-aware bijective block remap (requires nwg % 8 == 0; all our grids are).
// Groups a contiguous logical-tile range per XCD so shared A-panels hit one L2.
__device__ __forceinline__ void xcd_tiles(int& bx, int& by) {
    const int nwgx = gridDim.x;
    const int nwg = nwgx * gridDim.y;
    int bid = blockIdx.y * nwgx + blockIdx.x;
    int lb = (bid & 7) * (nwg >> 3) + (bid >> 3);
    bx = lb % nwgx;
    by = lb / nwgx;
}

// ---------------------------------------------------------------------------
// bf16 MFMA GEMM: C = A(bf16) @ BT(bf16)^T, fp32 accum. 128x128 tile, BK=32.
// ---------------------------------------------------------------------------
template<bool OUTBF16, bool RELU, bool ACCUM>
__global__ void __launch_bounds__(256)
gemm_bf16(const unsigned short* __restrict__ A, int lda,
          const unsigned short* __restrict__ BT, int ldbt,
          void* __restrict__ Cp, int ldc, int K,
          const float* __restrict__ bias)
{
    __shared__ short As[4096];
    __shared__ short Bs[4096];
    const int tid = threadIdx.x;
    const int w = tid >> 6, l = tid & 63;
    int bx, by;
    xcd_tiles(bx, by);
    const int wm = w >> 1, wn = w & 1;

    f32x4 acc[4][4] = {};

    const unsigned short* a_src[2];
    const unsigned short* b_src[2];
#pragma unroll
    for (int g = 0; g < 2; ++g) {
        int r = w * 32 + g * 16 + (l >> 2);
        int kc = (l & 3) ^ ((r >> 1) & 3);
        a_src[g] = A + (size_t)(by * 128 + r) * lda + kc * 8;
        b_src[g] = BT + (size_t)(bx * 128 + r) * ldbt + kc * 8;
    }
    short* As_w = As + w * 1024;
    short* Bs_w = Bs + w * 1024;

    const int lr = l & 15, lg = l >> 4;

    for (int k0 = 0; k0 < K; k0 += 32) {
        __syncthreads();
        gload_lds16(a_src[0] + k0, As_w);
        gload_lds16(a_src[1] + k0, As_w + 512);
        gload_lds16(b_src[0] + k0, Bs_w);
        gload_lds16(b_src[1] + k0, Bs_w + 512);
        __syncthreads();

        bf16x8 af[4], bg[4];
#pragma unroll
        for (int m = 0; m < 4; ++m) {
            int row = wm * 64 + m * 16 + lr;
            int off = row * 64 + ((lg ^ ((row >> 1) & 3)) << 4);
            af[m] = *(const bf16x8*)((const char*)As + off);
        }
#pragma unroll
        for (int n = 0; n < 4; ++n) {
            int row = wn * 64 + n * 16 + lr;
            int off = row * 64 + ((lg ^ ((row >> 1) & 3)) << 4);
            bg[n] = *(const bf16x8*)((const char*)Bs + off);
        }
#pragma unroll
        for (int m = 0; m < 4; ++m)
#pragma unroll
            for (int n = 0; n < 4; ++n)
                acc[m][n] = __builtin_amdgcn_mfma_f32_16x16x32_bf16(
                    af[m], bg[n], acc[m][n], 0, 0, 0);
    }

    float bcol[4];
#pragma unroll
    for (int n = 0; n < 4; ++n) {
        int colg = bx * 128 + wn * 64 + n * 16 + lr;
        bcol[n] = bias ? bias[colg] : 0.f;
    }
#pragma unroll
    for (int m = 0; m < 4; ++m) {
#pragma unroll
        for (int n = 0; n < 4; ++n) {
            int colg = bx * 128 + wn * 64 + n * 16 + lr;
#pragma unroll
            for (int r = 0; r < 4; ++r) {
                int rowg = by * 128 + wm * 64 + m * 16 + lg * 4 + r;
                float v = acc[m][n][r] + bcol[n];
                if (RELU) v = fmaxf(v, 0.f);
                if (OUTBF16) {
                    ((unsigned short*)Cp)[(size_t)rowg * ldc + colg] = f2bf(v);
                } else {
                    float* C = (float*)Cp;
                    if (ACCUM) v += C[(size_t)rowg * ldc + colg];
                    C[(size_t)rowg * ldc + colg] = v;
                }
            }
        }
    }
}

// ---------------------------------------------------------------------------
// Split-bf16 GEMM (fp32-accurate): 3 MFMAs (hh+hl+lh). Output written PACKED:
// CP[row][2048], 64-col groups interleaved hi|lo.
// ---------------------------------------------------------------------------
__global__ void __launch_bounds__(256)
gemm_bf16_split(const unsigned short* __restrict__ Ah,
                const unsigned short* __restrict__ Al, int lda,
                const unsigned short* __restrict__ BhT,
                const unsigned short* __restrict__ BlT, int ldbt,
                unsigned short* __restrict__ CP, int K,
                const float* __restrict__ bias)
{
    __shared__ short Ash[4096], Asl[4096], Bsh[4096], Bsl[4096];
    const int tid = threadIdx.x;
    const int w = tid >> 6, l = tid & 63;
    int bx, by;
    xcd_tiles(bx, by);
    const int wm = w >> 1, wn = w & 1;

    f32x4 acc[4][4] = {};

    size_t a_off[2], b_off[2];
#pragma unroll
    for (int g = 0; g < 2; ++g) {
        int r = w * 32 + g * 16 + (l >> 2);
        int kc = (l & 3) ^ ((r >> 1) & 3);
        a_off[g] = (size_t)(by * 128 + r) * lda + kc * 8;
        b_off[g] = (size_t)(bx * 128 + r) * ldbt + kc * 8;
    }
    const int wb = w * 1024;
    const int lr = l & 15, lg = l >> 4;

    for (int k0 = 0; k0 < K; k0 += 32) {
        __syncthreads();
#pragma unroll
        for (int g = 0; g < 2; ++g) {
            gload_lds16(Ah + a_off[g] + k0, Ash + wb + g * 512);
            gload_lds16(Al + a_off[g] + k0, Asl + wb + g * 512);
            gload_lds16(BhT + b_off[g] + k0, Bsh + wb + g * 512);
            gload_lds16(BlT + b_off[g] + k0, Bsl + wb + g * 512);
        }
        __syncthreads();

        bf16x8 afh[4], afl[4], bgh[4], bgl[4];
#pragma unroll
        for (int m = 0; m < 4; ++m) {
            int row = wm * 64 + m * 16 + lr;
            int off = row * 64 + ((lg ^ ((row >> 1) & 3)) << 4);
            afh[m] = *(const bf16x8*)((const char*)Ash + off);
            afl[m] = *(const bf16x8*)((const char*)Asl + off);
        }
#pragma unroll
        for (int n = 0; n < 4; ++n) {
            int row = wn * 64 + n * 16 + lr;
            int off = row * 64 + ((lg ^ ((row >> 1) & 3)) << 4);
            bgh[n] = *(const bf16x8*)((const char*)Bsh + off);
            bgl[n] = *(const bf16x8*)((const char*)Bsl + off);
        }
#pragma unroll
        for (int m = 0; m < 4; ++m)
#pragma unroll
            for (int n = 0; n < 4; ++n) {
                acc[m][n] = __builtin_amdgcn_mfma_f32_16x16x32_bf16(
                    afh[m], bgh[n], acc[m][n], 0, 0, 0);
                acc[m][n] = __builtin_amdgcn_mfma_f32_16x16x32_bf16(
                    afh[m], bgl[n], acc[m][n], 0, 0, 0);
                acc[m][n] = __builtin_amdgcn_mfma_f32_16x16x32_bf16(
                    afl[m], bgh[n], acc[m][n], 0, 0, 0);
            }
    }

    float bcol[4];
#pragma unroll
    for (int n = 0; n < 4; ++n)
        bcol[n] = bias[bx * 128 + wn * 64 + n * 16 + lr];
    const int cg = bx * 2 + wn;
#pragma unroll
    for (int m = 0; m < 4; ++m)
#pragma unroll
        for (int n = 0; n < 4; ++n) {
            int cwi = n * 16 + lr;
#pragma unroll
            for (int r = 0; r < 4; ++r) {
                int rowg = by * 128 + wm * 64 + m * 16 + lg * 4 + r;
                float v = acc[m][n][r] + bcol[n];
                unsigned short hh = f2bf(v);
                unsigned short ll = f2bf(v - bf2f(hh));
                size_t ad = (size_t)rowg * 2048 + cg * 128 + cwi;
                CP[ad] = hh;
                CP[ad + 64] = ll;
            }
        }
}

// ---------------------------------------------------------------------------
// Merged preprocessing: x split + 4 weight transposes in ONE dispatch.
// ---------------------------------------------------------------------------
__global__ void __launch_bounds__(256)
preprocess(const float* __restrict__ x,
           const float* __restrict__ wq, const float* __restrict__ wk,
           const float* __restrict__ wv, const float* __restrict__ wo,
           unsigned short* __restrict__ xh, unsigned short* __restrict__ xl,
           unsigned short* __restrict__ wqhT, unsigned short* __restrict__ wqlT,
           unsigned short* __restrict__ wkhT, unsigned short* __restrict__ wklT,
           unsigned short* __restrict__ wvT, unsigned short* __restrict__ woT)
{
    __shared__ float t[32][33];
    const int bid = blockIdx.x, tid = threadIdx.x;
    if (bid < 8192) {
        size_t i = (size_t)bid * 1024 + tid * 4;
        float4 v = *(const float4*)(x + i);
        ushort4 h, l2;
        h.x = f2bf(v.x); l2.x = f2bf(v.x - bf2f(h.x));
        h.y = f2bf(v.y); l2.y = f2bf(v.y - bf2f(h.y));
        h.z = f2bf(v.z); l2.z = f2bf(v.z - bf2f(h.z));
        h.w = f2bf(v.w); l2.w = f2bf(v.w - bf2f(h.w));
        *(ushort4*)(xh + i) = h;
        *(ushort4*)(xl + i) = l2;
        return;
    }
    const int grp = (bid - 8192) >> 10;     // 0:wq 1:wk 2:wv 3:wo
    const int b2 = (bid - 8192) & 1023;
    const int bx = (b2 & 31) * 32, by = (b2 >> 5) * 32;
    const float* in = (grp == 0) ? wq : (grp == 1) ? wk : (grp == 2) ? wv : wo;
    const int lx = tid & 31, ly = tid >> 5;
#pragma unroll
    for (int r = 0; r < 4; ++r)
        t[ly + r * 8][lx] = in[(size_t)(by + ly + r * 8) * 1024 + bx + lx];
    __syncthreads();
#pragma unroll
    for (int r = 0; r < 4; ++r) {
        int oc = ly + r * 8;
        float f = t[lx][oc];
        size_t od = (size_t)(bx + oc) * 1024 + by + lx;
        unsigned short hh = f2bf(f);
        if (grp == 0) { wqhT[od] = hh; wqlT[od] = f2bf(f - bf2f(hh)); }
        else if (grp == 1) { wkhT[od] = hh; wklT[od] = f2bf(f - bf2f(hh)); }
        else if (grp == 2) wvT[od] = hh;
        else woT[od] = hh;
    }
}

// plain transpose+convert (FFN weights)
__global__ void __launch_bounds__(256)
tconv(const float* __restrict__ in, int R, int C, unsigned short* __restrict__ out)
{
    __shared__ float t[32][33];
    const int bx = blockIdx.x * 32;
    const int by = blockIdx.y * 32;
    const int lx = threadIdx.x & 31, ly = threadIdx.x >> 5;
#pragma unroll
    for (int r = 0; r < 4; ++r)
        t[ly + r * 8][lx] = in[(size_t)(by + ly + r * 8) * C + bx + lx];
    __syncthreads();
#pragma unroll
    for (int r = 0; r < 4; ++r) {
        int oc = ly + r * 8;
        out[(size_t)(bx + oc) * R + by + lx] = f2bf(t[lx][oc]);
    }
}

// ---------------------------------------------------------------------------
// Gather sampled K rows into packed pre-swizzled KS[bh][2048][128].
// ---------------------------------------------------------------------------
__global__ void __launch_bounds__(256)
gather_ks(const unsigned short* __restrict__ KP, const int* __restrict__ idxs,
          unsigned short* __restrict__ KS)
{
    const int bh = blockIdx.x, b = bh >> 4, h = bh & 15;
    const int r0 = blockIdx.y * 256;
    const int s = threadIdx.x & 15, jr = threadIdx.x >> 4;
#pragma unroll
    for (int p = 0; p < 16; ++p) {
        int j = r0 + p * 16 + jr;
        int idx = idxs[j];
        int kc = (s & 7) ^ (j & 7);
        const unsigned short* src = KP + (size_t)(b * 2048 + idx) * 2048
                                  + h * 128 + ((s & 8) << 3) + kc * 8;
        *(bf16x8*)(KS + ((size_t)bh * 2048 + j) * 128 + s * 8) =
            *(const bf16x8*)src;
    }
}

// ---------------------------------------------------------------------------
// MFMA M-stat v3: block = (bh, qtile of 128 queries) -> 1024 blocks.
// ---------------------------------------------------------------------------
__global__ void __launch_bounds__(256)
mstat_mfma2(const unsigned short* __restrict__ QP,
            const unsigned short* __restrict__ KS,
            float* __restrict__ Mout)
{
    __shared__ char lds[32768];
    const int tid = threadIdx.x, w = tid >> 6, l = tid & 63;
    const int bh = blockIdx.x, qt = blockIdx.y;
    const int i0 = qt * 128;
    const int lr = l & 15, lg = l >> 4;

    bf16x8 af[2][2][2];   // [m][ks][hi/lo]
#pragma unroll
    for (int half = 0; half < 2; ++half) {
        __syncthreads();
#pragma unroll
        for (int it = 0; it < 4; ++it) {
            int rq = w * 32 + it * 8 + (l >> 3);
            int i = i0 + rq;
            int kc = (l & 7) ^ (rq & 7);
            gload_lds16(QP + (size_t)(bh * 128 + (i >> 4)) * 2048
                           + (i & 15) * 128 + half * 64 + kc * 8,
                        lds + w * 4096 + it * 1024);
        }
        __syncthreads();
#pragma unroll
        for (int m = 0; m < 2; ++m) {
            int rq = w * 32 + m * 16 + lr;
#pragma unroll
            for (int ks = 0; ks < 2; ++ks) {
                int c = (ks * 4 + lg) ^ (rq & 7);
                af[m][ks][half] = *(const bf16x8*)(lds + rq * 128 + (c << 4));
            }
        }
    }
    __syncthreads();

    float mx[2][4], sm[2][4];
#pragma unroll
    for (int m = 0; m < 2; ++m)
#pragma unroll
        for (int r = 0; r < 4; ++r) { mx[m][r] = -FLT_MAX; sm[m][r] = 0.f; }

    const unsigned short* ksbase = KS + (size_t)bh * (2048 * 128);

#pragma unroll
    for (int it = 0; it < 4; ++it)
        gload_lds16(ksbase + w * 2048 + it * 512 + l * 8,
                    lds + w * 4096 + it * 1024);

    for (int jt = 0; jt < 32; ++jt) {
        const int cur = jt & 1;
        __syncthreads();
        if (jt + 1 < 32) {
#pragma unroll
            for (int it = 0; it < 4; ++it)
                gload_lds16(ksbase + (size_t)(jt + 1) * 8192 + w * 2048 + it * 512 + l * 8,
                            lds + (cur ^ 1) * 16384 + w * 4096 + it * 1024);
        }
        const char* kb = lds + cur * 16384;
#pragma unroll
        for (int n = 0; n < 4; ++n) {
            int jr = n * 16 + lr;
            bf16x8 bgh[2], bgl[2];
#pragma unroll
            for (int ks = 0; ks < 2; ++ks) {
                int c = (ks * 4 + lg) ^ (jr & 7);
                bgh[ks] = *(const bf16x8*)(kb + jr * 256 + (c << 4));
                bgl[ks] = *(const bf16x8*)(kb + jr * 256 + (c << 4) + 128);
            }
#pragma unroll
            for (int m = 0; m < 2; ++m) {
                f32x4 a = {};
                a = __builtin_amdgcn_mfma_f32_16x16x32_bf16(af[m][0][0], bgh[0], a, 0, 0, 0);
                a = __builtin_amdgcn_mfma_f32_16x16x32_bf16(af[m][0][1], bgh[0], a, 0, 0, 0);
                a = __builtin_amdgcn_mfma_f32_16x16x32_bf16(af[m][0][0], bgl[0], a, 0, 0, 0);
                a = __builtin_amdgcn_mfma_f32_16x16x32_bf16(af[m][1][0], bgh[1], a, 0, 0, 0);
                a = __builtin_amdgcn_mfma_f32_16x16x32_bf16(af[m][1][1], bgh[1], a, 0, 0, 0);
                a = __builtin_amdgcn_mfma_f32_16x16x32_bf16(af[m][1][0], bgl[1], a, 0, 0, 0);
#pragma unroll
                for (int r = 0; r < 4; ++r) {
                    mx[m][r] = fmaxf(mx[m][r], a[r]);
                    sm[m][r] += a[r];
                }
            }
        }
    }

#pragma unroll
    for (int m = 0; m < 2; ++m)
#pragma unroll
        for (int r = 0; r < 4; ++r) {
            float a = mx[m][r], s = sm[m][r];
#pragma unroll
            for (int mask = 1; mask < 16; mask <<= 1) {
                a = fmaxf(a, __shfl_xor(a, mask));
                s += __shfl_xor(s, mask);
            }
            if (lr == 0) {
                int row = i0 + w * 32 + m * 16 + lg * 4 + r;
                Mout[(size_t)bh * L_SEQ + row] = a - s * (1.0f / 2048.0f);
            }
        }
}

// ---------------------------------------------------------------------------
// Top-40 smallest M per bh (lower-index tie-break).
// ---------------------------------------------------------------------------
__global__ void __launch_bounds__(256)
topk_kernel(const float* __restrict__ M, int* __restrict__ Mtop)
{
    __shared__ float mv[L_SEQ];
    __shared__ float wv_[4];
    __shared__ int wi_[4];
    const int bh = blockIdx.x;
    const int tid = threadIdx.x;
    for (int j = tid; j < L_SEQ; j += 256) mv[j] = M[(size_t)bh * L_SEQ + j];
    __syncthreads();
    for (int u = 0; u < U_TOP; ++u) {
        float best = FLT_MAX;
        int bi = 1 << 30;
        for (int j = tid; j < L_SEQ; j += 256) {
            float v = mv[j];
            if (v < best || (v == best && j < bi)) { best = v; bi = j; }
        }
#pragma unroll
        for (int off = 32; off; off >>= 1) {
            float ov = __shfl_down(best, off);
            int oi = __shfl_down(bi, off);
            if (ov < best || (ov == best && oi < bi)) { best = ov; bi = oi; }
        }
        if ((tid & 63) == 0) { wv_[tid >> 6] = best; wi_[tid >> 6] = bi; }
        __syncthreads();
        if (tid == 0) {
            for (int w = 1; w < 4; ++w)
                if (wv_[w] < best || (wv_[w] == best && wi_[w] < bi)) { best = wv_[w]; bi = wi_[w]; }
            Mtop[bh * U_TOP + u] = bi;
            mv[bi] = FLT_MAX;
        }
        __syncthreads();
    }
}

// ---------------------------------------------------------------------------
// FUSED sparse attention, KV-SPLIT: grid (4 splits, 64 bh) = 256 blocks.
// ---------------------------------------------------------------------------
__global__ void __launch_bounds__(256)
attn_fused(const unsigned short* __restrict__ QP,  // packed [8192][2048]
           const unsigned short* __restrict__ KP,  // packed [8192][2048]
           const unsigned short* __restrict__ V,   // [8192][1024]
           const int* __restrict__ Mtop,
           unsigned short* __restrict__ PART,      // [256][64][64] bf16
           float* __restrict__ ML)                 // [256][64][2]
{
    __shared__ unsigned short Qs[64 * 64];
    __shared__ unsigned short Ks[128 * 64];
    __shared__ unsigned short Vt[64 * 128];
    __shared__ unsigned short Pb[64 * 128];
    const int sp = blockIdx.x, bh = blockIdx.y;
    const int b = bh >> 4, h = bh & 15;
    const int tid = threadIdx.x, w = tid >> 6, l = tid & 63;
    const int lr = l & 15, lg = l >> 4;

#pragma unroll
    for (int is = 0; is < 2; ++is) {
        int row = w * 16 + is * 8 + (l >> 3);
        int u = row < U_TOP ? row : U_TOP - 1;
        int lsel = Mtop[bh * U_TOP + u];
        int cg = (l & 7) ^ (row & 7);
        gload_lds16(QP + (size_t)(bh * 128 + (lsel >> 4)) * 2048
                       + (lsel & 15) * 128 + cg * 8,
                    &Qs[(w * 16 + is * 8) * 64]);
    }
    __syncthreads();

    bf16x8 af[2];
    {
        int row = w * 16 + lr;
#pragma unroll
        for (int ks = 0; ks < 2; ++ks) {
            int c = (ks * 4 + lg) ^ (row & 7);
            af[ks] = *(const bf16x8*)((const char*)Qs + row * 128 + (c << 4));
        }
    }

    float m_run[4], l_run[4];
    f32x4 oacc[4] = {};
#pragma unroll
    for (int r = 0; r < 4; ++r) { m_run[r] = -FLT_MAX; l_run[r] = 0.f; }

    for (int t = sp * 4; t < sp * 4 + 4; ++t) {
        const int j0 = t * 128;
        __syncthreads();

#pragma unroll
        for (int is = 0; is < 4; ++is) {
            int kr = w * 32 + is * 8 + (l >> 3);
            int cg = (l & 7) ^ (kr & 7);
            gload_lds16(KP + (size_t)(b * 2048 + j0 + kr) * 2048 + h * 128 + cg * 8,
                        &Ks[(w * 32 + is * 8) * 64]);
        }
        {
            int key = tid & 127, dh = (tid >> 7) * 32;
            const unsigned short* vsrc =
                V + (((size_t)(b * L_SEQ + j0 + key)) << 10) + (h << 6) + dh;
            bf16x8 vv[4];
#pragma unroll
            for (int i = 0; i < 4; ++i) vv[i] = *(const bf16x8*)(vsrc + i * 8);
            int ck = key >> 3, klo = (key & 7) * 2;
#pragma unroll
            for (int i = 0; i < 4; ++i)
#pragma unroll
                for (int j = 0; j < 8; ++j) {
                    int d = dh + i * 8 + j;
                    *(unsigned short*)((char*)Vt + d * 256 +
                                       ((ck ^ (d & 7)) << 4) + klo) =
                        (unsigned short)vv[i][j];
                }
        }
        __syncthreads();

        f32x4 sc[8] = {};
#pragma unroll
        for (int ks = 0; ks < 2; ++ks)
#pragma unroll
            for (int n = 0; n < 8; ++n) {
                int krow = n * 16 + lr;
                int c = (ks * 4 + lg) ^ (krow & 7);
                bf16x8 bf = *(const bf16x8*)((const char*)Ks + krow * 128 + (c << 4));
                sc[n] = __builtin_amdgcn_mfma_f32_16x16x32_bf16(af[ks], bf, sc[n], 0, 0, 0);
            }

        float rs[4];
#pragma unroll
        for (int r = 0; r < 4; ++r) {
            int row = w * 16 + lg * 4 + r;
            float mt = -FLT_MAX;
#pragma unroll
            for (int n = 0; n < 8; ++n) mt = fmaxf(mt, sc[n][r]);
            mt *= 0.125f;
#pragma unroll
            for (int mask = 1; mask < 16; mask <<= 1)
                mt = fmaxf(mt, __shfl_xor(mt, mask));
            float mn = fmaxf(m_run[r], mt);
            rs[r] = expf(m_run[r] - mn);
            float ls = 0.f;
            int rsw = row & 7;
#pragma unroll
            for (int n = 0; n < 8; ++n) {
                float p = expf(sc[n][r] * 0.125f - mn);
                ls += p;
                int ckp = (lr >> 3) + 2 * n;
                *(unsigned short*)((char*)Pb + row * 256 +
                                   ((ckp ^ rsw) << 4) + (lr & 7) * 2) = f2bf(p);
            }
#pragma unroll
            for (int mask = 1; mask < 16; mask <<= 1) ls += __shfl_xor(ls, mask);
            l_run[r] = l_run[r] * rs[r] + ls;
            m_run[r] = mn;
        }
        __syncthreads();

#pragma unroll
        for (int n = 0; n < 4; ++n)
#pragma unroll
            for (int r = 0; r < 4; ++r) oacc[n][r] *= rs[r];
#pragma unroll
        for (int ks = 0; ks < 4; ++ks) {
            int arow = w * 16 + lr;
            int ca = (lg + ks * 4) ^ (arow & 7);
            bf16x8 pa = *(const bf16x8*)((const char*)Pb + arow * 256 + (ca << 4));
#pragma unroll
            for (int n = 0; n < 4; ++n) {
                int d = n * 16 + lr;
                int cb = (lg + ks * 4) ^ (d & 7);
                bf16x8 vb = *(const bf16x8*)((const char*)Vt + d * 256 + (cb << 4));
                oacc[n] = __builtin_amdgcn_mfma_f32_16x16x32_bf16(pa, vb, oacc[n], 0, 0, 0);
            }
        }
    }

    const int pbase = (bh * 4 + sp) * 64;
#pragma unroll
    for (int r = 0; r < 4; ++r) {
        int row = w * 16 + lg * 4 + r;
#pragma unroll
        for (int n = 0; n < 4; ++n)
            PART[(size_t)(pbase + row) * 64 + n * 16 + lr] = f2bf(oacc[n][r]);
        if (lr == 0) {
            ML[(size_t)(pbase + row) * 2 + 0] = m_run[r];
            ML[(size_t)(pbase + row) * 2 + 1] = l_run[r];
        }
    }
}

// ---------------------------------------------------------------------------
// Combine KV-splits + scatter-GEMM into zeroed Ab (bo folded into LN1).
// ---------------------------------------------------------------------------
__global__ void __launch_bounds__(256)
woscatter(const unsigned short* __restrict__ PART,
          const float* __restrict__ ML,
          const unsigned short* __restrict__ woT,   // [1024][1024]
          const int* __restrict__ Mtop,
          float* __restrict__ Ab)
{
    const int bh = blockIdx.x, b = bh >> 4, h = bh & 15;
    const int tid = threadIdx.x, w = tid >> 6, l = tid & 63;
    const int lr = l & 15, lg = l >> 4;

    bf16x8 af[3][2];
#pragma unroll
    for (int m = 0; m < 3; ++m) {
        int row = m * 16 + lr;
        float ms[4], ls[4];
#pragma unroll
        for (int s = 0; s < 4; ++s) {
            ms[s] = ML[(size_t)((bh * 4 + s) * 64 + row) * 2 + 0];
            ls[s] = ML[(size_t)((bh * 4 + s) * 64 + row) * 2 + 1];
        }
        float M = fmaxf(fmaxf(ms[0], ms[1]), fmaxf(ms[2], ms[3]));
        float wgt[4], L = 0.f;
#pragma unroll
        for (int s = 0; s < 4; ++s) { wgt[s] = expf(ms[s] - M); L += wgt[s] * ls[s]; }
        float invL = 1.f / L;
#pragma unroll
        for (int ks = 0; ks < 2; ++ks) {
            float a8[8] = {};
#pragma unroll
            for (int s = 0; s < 4; ++s) {
                bf16x8 po = *(const bf16x8*)(PART +
                    (size_t)((bh * 4 + s) * 64 + row) * 64 + (ks * 4 + lg) * 8);
#pragma unroll
                for (int j = 0; j < 8; ++j)
                    a8[j] += wgt[s] * bf2f((unsigned short)po[j]);
            }
            bf16x8 fr;
#pragma unroll
            for (int j = 0; j < 8; ++j) fr[j] = (short)f2bf(a8[j] * invL);
            af[m][ks] = fr;
        }
    }

    int lsel[3][4];
#pragma unroll
    for (int m = 0; m < 3; ++m)
#pragma unroll
        for (int r = 0; r < 4; ++r) {
            int row = m * 16 + lg * 4 + r;
            lsel[m][r] = row < U_TOP ? Mtop[bh * U_TOP + row] : -1;
        }

    for (int nn = 0; nn < 16; ++nn) {
        int ng = w * 16 + nn;
        bf16x8 bg[2];
#pragma unroll
        for (int ks = 0; ks < 2; ++ks)
            bg[ks] = *(const bf16x8*)(woT + (size_t)(ng * 16 + lr) * 1024
                                      + h * 64 + (ks * 4 + lg) * 8);
        f32x4 a[3] = {};
#pragma unroll
        for (int m = 0; m < 3; ++m)
#pragma unroll
            for (int ks = 0; ks < 2; ++ks)
                a[m] = __builtin_amdgcn_mfma_f32_16x16x32_bf16(af[m][ks], bg[ks], a[m], 0, 0, 0);
#pragma unroll
        for (int m = 0; m < 3; ++m)
#pragma unroll
            for (int r = 0; r < 4; ++r)
                if (lsel[m][r] >= 0)
                    atomicAdd(Ab + (size_t)(b * 2048 + lsel[m][r]) * 1024
                              + ng * 16 + lr, a[m][r]);
    }
}

// ---------------------------------------------------------------------------
// Fused residual + LayerNorm; optional extra bias (bo) and bf16 copy.
// ---------------------------------------------------------------------------
template<bool WB16, bool BADD>
__global__ void __launch_bounds__(256)
ln_kernel(const float* __restrict__ X, const float* __restrict__ A,
          const float* __restrict__ badd,
          const float* __restrict__ g, const float* __restrict__ be,
          float* __restrict__ out, unsigned short* __restrict__ out16)
{
    __shared__ float wred[4];
    const int row = blockIdx.x, tid = threadIdx.x;
    float4 xv = *(const float4*)(X + (size_t)row * D_MODEL + tid * 4);
    float4 av = *(const float4*)(A + (size_t)row * D_MODEL + tid * 4);
    float v0 = xv.x + av.x, v1 = xv.y + av.y, v2 = xv.z + av.z, v3 = xv.w + av.w;
    if (BADD) {
        float4 bb = *(const float4*)(badd + tid * 4);
        v0 += bb.x; v1 += bb.y; v2 += bb.z; v3 += bb.w;
    }

    float s = v0 + v1 + v2 + v3;
#pragma unroll
    for (int off = 32; off; off >>= 1) s += __shfl_down(s, off);
    if ((tid & 63) == 0) wred[tid >> 6] = s;
    __syncthreads();
    float mean = (wred[0] + wred[1] + wred[2] + wred[3]) * (1.f / 1024.f);
    __syncthreads();

    float d0 = v0 - mean, d1 = v1 - mean, d2 = v2 - mean, d3 = v3 - mean;
    float q = d0 * d0 + d1 * d1 + d2 * d2 + d3 * d3;
#pragma unroll
    for (int off = 32; off; off >>= 1) q += __shfl_down(q, off);
    if ((tid & 63) == 0) wred[tid >> 6] = q;
    __syncthreads();
    float var = (wred[0] + wred[1] + wred[2] + wred[3]) * (1.f / 1024.f);
    float rstd = rsqrtf(var + 1e-12f);

    float4 gv = *(const float4*)(g + tid * 4);
    float4 bv = *(const float4*)(be + tid * 4);
    float4 o;
    o.x = gv.x * d0 * rstd + bv.x;
    o.y = gv.y * d1 * rstd + bv.y;
    o.z = gv.z * d2 * rstd + bv.z;
    o.w = gv.w * d3 * rstd + bv.w;
    *(float4*)(out + (size_t)row * D_MODEL + tid * 4) = o;
    if (WB16) {
        ushort4 ob;
        ob.x = f2bf(o.x); ob.y = f2bf(o.y); ob.z = f2bf(o.z); ob.w = f2bf(o.w);
        *(ushort4*)(out16 + (size_t)row * D_MODEL + tid * 4) = ob;
    }
}

// ---------------------------------------------------------------------------
extern "C" void kernel_launch(void* const* d_in, const int* in_sizes, int n_in,
                              void* d_out, int out_size, void* d_ws, size_t ws_size,
                              hipStream_t stream)
{
    const float* x   = (const float*)d_in[0];
    const float* wq  = (const float*)d_in[1];
    const float* bq  = (const float*)d_in[2];
    const float* wk  = (const float*)d_in[3];
    const float* bk  = (const float*)d_in[4];
    const float* wv  = (const float*)d_in[5];
    const float* bv  = (const float*)d_in[6];
    const float* wo  = (const float*)d_in[7];
    const float* bo  = (const float*)d_in[8];
    const float* w1  = (const float*)d_in[9];
    const float* b1  = (const float*)d_in[10];
    const float* w2  = (const float*)d_in[11];
    const float* b2  = (const float*)d_in[12];
    const float* g1  = (const float*)d_in[13];
    const float* be1 = (const float*)d_in[14];
    const float* g2  = (const float*)d_in[15];
    const float* be2 = (const float*)d_in[16];
    const int*  idxs = (const int*)d_in[17];

    char* ws  = (char*)d_ws;
    char* dob = (char*)d_out;
    const size_t MB = 1u << 20;

    // ---- workspace (phase-disjoint; peak 128 MB) ----
    unsigned short* QP   = (unsigned short*)(ws);             // 0-32   [qproj..attn]
    unsigned short* KP   = (unsigned short*)(ws + 32 * MB);   // 32-64  [kproj..attn]
    unsigned short* xh   = (unsigned short*)(ws + 64 * MB);   // 64-80  [pre..vproj]
    unsigned short* xl   = (unsigned short*)(ws + 80 * MB);   // 80-96  [pre..kproj]
    unsigned short* KS   = (unsigned short*)(ws + 64 * MB);   // 64-96  [gather..mstat]
    float*          Ab   = (float*)(ws + 64 * MB);            // 64-96  [memset..ln1]
    float*          x1f  = (float*)(ws + 96 * MB);            // 96-128 [ln1..ln2]
    unsigned short* x1b  = (unsigned short*)(ws);             // 0-16   [ln1..ffn]
    unsigned short* w1T  = (unsigned short*)(ws + 16 * MB);   // 16-24  [tc..ffn]
    unsigned short* w2T  = (unsigned short*)(ws + 24 * MB);   // 24-32  [tc..ffn]
    unsigned short* HID  = (unsigned short*)(ws + 32 * MB);   // 32-96  [ffn] 64MB

    // ---- d_out doubles as scratch until the FFN w2 GEMM ----
    unsigned short* woT  = (unsigned short*)(dob);            // 0-2
    unsigned short* wqhT = (unsigned short*)(dob + 2 * MB);
    unsigned short* wqlT = (unsigned short*)(dob + 4 * MB);
    unsigned short* wkhT = (unsigned short*)(dob + 6 * MB);
    unsigned short* wklT = (unsigned short*)(dob + 8 * MB);
    unsigned short* wvT  = (unsigned short*)(dob + 10 * MB);
    float*          Mb   = (float*)(dob + 12 * MB);           // 512 KB
    int*            Mtop = (int*)(dob + 12 * MB + 768 * 1024);
    unsigned short* Vb   = (unsigned short*)(dob + 13 * MB);  // 13-29
    unsigned short* PART = (unsigned short*)(dob + 29 * MB);  // 29-31 (bf16)
    float*          ML   = (float*)(dob + 31 * MB);           // 128 KB
    float*          F    = (float*)d_out;                     // FFN output

    dim3 blk(256);
    dim3 g_gemm(8, 64);

    // merged preprocessing: x split + wq/wk split-T + wv/wo T (one dispatch)
    preprocess<<<dim3(12288), blk, 0, stream>>>(x, wq, wk, wv, wo,
                                                xh, xl, wqhT, wqlT, wkhT, wklT,
                                                wvT, woT);

    // projections: q/k split-packed; v plain bf16
    gemm_bf16_split<<<g_gemm, blk, 0, stream>>>(xh, xl, 1024, wqhT, wqlT, 1024,
                                                QP, 1024, bq);
    gemm_bf16_split<<<g_gemm, blk, 0, stream>>>(xh, xl, 1024, wkhT, wklT, 1024,
                                                KP, 1024, bk);
    gemm_bf16<true, false, false><<<g_gemm, blk, 0, stream>>>(xh, 1024, wvT, 1024,
                                                              Vb, 1024, 1024, bv);

    // selection: pre-gather sampled K, streamed MFMA M-stat, top-40
    gather_ks<<<dim3(64, 8), blk, 0, stream>>>(KP, idxs, KS);
    mstat_mfma2<<<dim3(64, 16), blk, 0, stream>>>(QP, KS, Mb);
    topk_kernel<<<dim3(64), blk, 0, stream>>>(Mb, Mtop);

    // fused sparse attention, kv-split 4x -> partials; combine+wo in woscatter
    hipMemsetAsync(Ab, 0, 32 * MB, stream);
    attn_fused<<<dim3(4, N_BH), blk, 0, stream>>>(QP, KP, Vb, Mtop, PART, ML);
    woscatter<<<dim3(N_BH), blk, 0, stream>>>(PART, ML, woT, Mtop, Ab);

    // x1 = LN(x + Ab + bo)
    ln_kernel<true, true><<<dim3(8192), blk, 0, stream>>>(x, Ab, bo, g1, be1, x1f, x1b);

    // FFN weights
    tconv<<<dim3(128, 32), blk, 0, stream>>>(w1, 1024, 4096, w1T);
    tconv<<<dim3(32, 128), blk, 0, stream>>>(w2, 4096, 1024, w2T);

    // FFN, single chunk: HID = relu(x1@w1+b1); F = HID@w2 + b2 (written once)
    gemm_bf16<true, true, false><<<dim3(32, 64), blk, 0, stream>>>(
        x1b, 1024, w1T, 1024, HID, 4096, 1024, b1);
    gemm_bf16<false, false, false><<<g_gemm, blk, 0, stream>>>(
        HID, 4096, w2T, 4096, F, 1024, 4096, b2);

    // out = LN(x1 + F)
    ln_kernel<false, false><<<dim3(8192), blk, 0, stream>>>(x1f, F, nullptr, g2, be2,
                                                            (float*)d_out, nullptr);
}

// Round 9
// 731.256 us; speedup vs baseline: 4.4505x; 1.0089x over previous
//
#include <hip/hip_runtime.h>
#include <float.h>
#include <math.h>

#define L_SEQ 2048
#define D_MODEL 1024
#define N_HEAD 16
#define HD 64
#define N_BH 64
#define U_TOP 40

using bf16x8 = __attribute__((ext_vector_type(8))) short;
using f32x4  = __attribute__((ext_vector_type(4))) float;

__device__ __forceinline__ unsigned short f2bf(float f) {
    unsigned int u = __builtin_bit_cast(unsigned int, f);
    u += 0x7fff + ((u >> 16) & 1);   // round-to-nearest-even
    return (unsigned short)(u >> 16);
}
__device__ __forceinline__ float bf2f(unsigned short h) {
    unsigned int u = ((unsigned int)h) << 16;
    return __builtin_bit_cast(float, u);
}

__device__ __forceinline__ void gload_lds16(const void* g, void* l) {
    __builtin_amdgcn_global_load_lds(
        (const __attribute__((address_space(1))) unsigned int*)g,
        (__attribute__((address_space(3))) unsigned int*)l, 16, 0, 0);
}

// XCD-aware bijective block remap (requires nwg % 8 == 0; all our grids are).
__device__ __forceinline__ void xcd_tiles(int& bx, int& by) {
    const int nwgx = gridDim.x;
    const int nwg = nwgx * gridDim.y;
    int bid = blockIdx.y * nwgx + blockIdx.x;
    int lb = (bid & 7) * (nwg >> 3) + (bid >> 3);
    bx = lb % nwgx;
    by = lb / nwgx;
}

// ---------------------------------------------------------------------------
// bf16 MFMA GEMM: C = A(bf16) @ BT(bf16)^T, fp32 accum. 128x128 tile, BK=32.
// KSPLIT: gridDim.z=2, z-half k-range; z=0 -> Cp(+bias), z=1 -> Cp2 (no bias).
// ---------------------------------------------------------------------------
template<bool OUTBF16, bool RELU, bool KSPLIT>
__global__ void __launch_bounds__(256)
gemm_bf16(const unsigned short* __restrict__ A, int lda,
          const unsigned short* __restrict__ BT, int ldbt,
          void* __restrict__ Cp, int ldc, int K,
          const float* __restrict__ bias, void* __restrict__ Cp2)
{
    __shared__ short As[4096];
    __shared__ short Bs[4096];
    const int tid = threadIdx.x;
    const int w = tid >> 6, l = tid & 63;
    int bx, by;
    xcd_tiles(bx, by);
    const int kz = KSPLIT ? blockIdx.z : 0;
    const size_t koff = (size_t)kz * K;
    const int wm = w >> 1, wn = w & 1;

    f32x4 acc[4][4] = {};

    const unsigned short* a_src[2];
    const unsigned short* b_src[2];
#pragma unroll
    for (int g = 0; g < 2; ++g) {
        int r = w * 32 + g * 16 + (l >> 2);
        int kc = (l & 3) ^ ((r >> 1) & 3);
        a_src[g] = A + (size_t)(by * 128 + r) * lda + koff + kc * 8;
        b_src[g] = BT + (size_t)(bx * 128 + r) * ldbt + koff + kc * 8;
    }
    short* As_w = As + w * 1024;
    short* Bs_w = Bs + w * 1024;

    const int lr = l & 15, lg = l >> 4;

    for (int k0 = 0; k0 < K; k0 += 32) {
        __syncthreads();
        gload_lds16(a_src[0] + k0, As_w);
        gload_lds16(a_src[1] + k0, As_w + 512);
        gload_lds16(b_src[0] + k0, Bs_w);
        gload_lds16(b_src[1] + k0, Bs_w + 512);
        __syncthreads();

        bf16x8 af[4], bg[4];
#pragma unroll
        for (int m = 0; m < 4; ++m) {
            int row = wm * 64 + m * 16 + lr;
            int off = row * 64 + ((lg ^ ((row >> 1) & 3)) << 4);
            af[m] = *(const bf16x8*)((const char*)As + off);
        }
#pragma unroll
        for (int n = 0; n < 4; ++n) {
            int row = wn * 64 + n * 16 + lr;
            int off = row * 64 + ((lg ^ ((row >> 1) & 3)) << 4);
            bg[n] = *(const bf16x8*)((const char*)Bs + off);
        }
#pragma unroll
        for (int m = 0; m < 4; ++m)
#pragma unroll
            for (int n = 0; n < 4; ++n)
                acc[m][n] = __builtin_amdgcn_mfma_f32_16x16x32_bf16(
                    af[m], bg[n], acc[m][n], 0, 0, 0);
    }

    const float* bias_eff = (KSPLIT && kz) ? nullptr : bias;
    void* Cp_eff = (KSPLIT && kz) ? Cp2 : Cp;
    float bcol[4];
#pragma unroll
    for (int n = 0; n < 4; ++n) {
        int colg = bx * 128 + wn * 64 + n * 16 + lr;
        bcol[n] = bias_eff ? bias_eff[colg] : 0.f;
    }
#pragma unroll
    for (int m = 0; m < 4; ++m) {
#pragma unroll
        for (int n = 0; n < 4; ++n) {
            int colg = bx * 128 + wn * 64 + n * 16 + lr;
#pragma unroll
            for (int r = 0; r < 4; ++r) {
                int rowg = by * 128 + wm * 64 + m * 16 + lg * 4 + r;
                float v = acc[m][n][r] + bcol[n];
                if (RELU) v = fmaxf(v, 0.f);
                if (OUTBF16) {
                    ((unsigned short*)Cp_eff)[(size_t)rowg * ldc + colg] = f2bf(v);
                } else {
                    ((float*)Cp_eff)[(size_t)rowg * ldc + colg] = v;
                }
            }
        }
    }
}

// ---------------------------------------------------------------------------
// FUSED QKV projection: grid (24, 64) = 1536 blocks (~5/CU, LDS-capped).
// bx<8: q split-GEMM (3 MFMA, packed hi|lo out); bx<16: k split-GEMM;
// bx>=16: v plain GEMM (1 MFMA, bf16 out). Block-uniform branch.
// ---------------------------------------------------------------------------
__global__ void __launch_bounds__(256)
gemm_qkv(const unsigned short* __restrict__ xh, const unsigned short* __restrict__ xl,
         const unsigned short* __restrict__ wqhT, const unsigned short* __restrict__ wqlT,
         const unsigned short* __restrict__ wkhT, const unsigned short* __restrict__ wklT,
         const unsigned short* __restrict__ wvT,
         unsigned short* __restrict__ QP, unsigned short* __restrict__ KP,
         unsigned short* __restrict__ Vb,
         const float* __restrict__ bq, const float* __restrict__ bk,
         const float* __restrict__ bv)
{
    __shared__ short Ash[4096], Asl[4096], Bsh[4096], Bsl[4096];
    const int tid = threadIdx.x;
    const int w = tid >> 6, l = tid & 63;
    int bxf, by;
    xcd_tiles(bxf, by);
    const int grp = bxf >> 3;          // 0=q 1=k 2=v
    const int bx = bxf & 7;
    const int wm = w >> 1, wn = w & 1;
    const int wb = w * 1024;
    const int lr = l & 15, lg = l >> 4;

    size_t a_off[2], b_off[2];
#pragma unroll
    for (int g = 0; g < 2; ++g) {
        int r = w * 32 + g * 16 + (l >> 2);
        int kc = (l & 3) ^ ((r >> 1) & 3);
        a_off[g] = (size_t)(by * 128 + r) * 1024 + kc * 8;
        b_off[g] = (size_t)(bx * 128 + r) * 1024 + kc * 8;
    }

    f32x4 acc[4][4] = {};

    if (grp < 2) {
        const unsigned short* BhT = grp ? wkhT : wqhT;
        const unsigned short* BlT = grp ? wklT : wqlT;
        for (int k0 = 0; k0 < 1024; k0 += 32) {
            __syncthreads();
#pragma unroll
            for (int g = 0; g < 2; ++g) {
                gload_lds16(xh + a_off[g] + k0, Ash + wb + g * 512);
                gload_lds16(xl + a_off[g] + k0, Asl + wb + g * 512);
                gload_lds16(BhT + b_off[g] + k0, Bsh + wb + g * 512);
                gload_lds16(BlT + b_off[g] + k0, Bsl + wb + g * 512);
            }
            __syncthreads();

            bf16x8 afh[4], afl[4], bgh[4], bgl[4];
#pragma unroll
            for (int m = 0; m < 4; ++m) {
                int row = wm * 64 + m * 16 + lr;
                int off = row * 64 + ((lg ^ ((row >> 1) & 3)) << 4);
                afh[m] = *(const bf16x8*)((const char*)Ash + off);
                afl[m] = *(const bf16x8*)((const char*)Asl + off);
            }
#pragma unroll
            for (int n = 0; n < 4; ++n) {
                int row = wn * 64 + n * 16 + lr;
                int off = row * 64 + ((lg ^ ((row >> 1) & 3)) << 4);
                bgh[n] = *(const bf16x8*)((const char*)Bsh + off);
                bgl[n] = *(const bf16x8*)((const char*)Bsl + off);
            }
#pragma unroll
            for (int m = 0; m < 4; ++m)
#pragma unroll
                for (int n = 0; n < 4; ++n) {
                    acc[m][n] = __builtin_amdgcn_mfma_f32_16x16x32_bf16(
                        afh[m], bgh[n], acc[m][n], 0, 0, 0);
                    acc[m][n] = __builtin_amdgcn_mfma_f32_16x16x32_bf16(
                        afh[m], bgl[n], acc[m][n], 0, 0, 0);
                    acc[m][n] = __builtin_amdgcn_mfma_f32_16x16x32_bf16(
                        afl[m], bgh[n], acc[m][n], 0, 0, 0);
                }
        }

        const float* bias = grp ? bk : bq;
        unsigned short* CP = grp ? KP : QP;
        float bcol[4];
#pragma unroll
        for (int n = 0; n < 4; ++n)
            bcol[n] = bias[bx * 128 + wn * 64 + n * 16 + lr];
        const int cg = bx * 2 + wn;
#pragma unroll
        for (int m = 0; m < 4; ++m)
#pragma unroll
            for (int n = 0; n < 4; ++n) {
                int cwi = n * 16 + lr;
#pragma unroll
                for (int r = 0; r < 4; ++r) {
                    int rowg = by * 128 + wm * 64 + m * 16 + lg * 4 + r;
                    float v = acc[m][n][r] + bcol[n];
                    unsigned short hh = f2bf(v);
                    unsigned short ll = f2bf(v - bf2f(hh));
                    size_t ad = (size_t)rowg * 2048 + cg * 128 + cwi;
                    CP[ad] = hh;
                    CP[ad + 64] = ll;
                }
            }
    } else {
        for (int k0 = 0; k0 < 1024; k0 += 32) {
            __syncthreads();
#pragma unroll
            for (int g = 0; g < 2; ++g) {
                gload_lds16(xh + a_off[g] + k0, Ash + wb + g * 512);
                gload_lds16(wvT + b_off[g] + k0, Bsh + wb + g * 512);
            }
            __syncthreads();

            bf16x8 af[4], bg[4];
#pragma unroll
            for (int m = 0; m < 4; ++m) {
                int row = wm * 64 + m * 16 + lr;
                int off = row * 64 + ((lg ^ ((row >> 1) & 3)) << 4);
                af[m] = *(const bf16x8*)((const char*)Ash + off);
            }
#pragma unroll
            for (int n = 0; n < 4; ++n) {
                int row = wn * 64 + n * 16 + lr;
                int off = row * 64 + ((lg ^ ((row >> 1) & 3)) << 4);
                bg[n] = *(const bf16x8*)((const char*)Bsh + off);
            }
#pragma unroll
            for (int m = 0; m < 4; ++m)
#pragma unroll
                for (int n = 0; n < 4; ++n)
                    acc[m][n] = __builtin_amdgcn_mfma_f32_16x16x32_bf16(
                        af[m], bg[n], acc[m][n], 0, 0, 0);
        }

        float bcol[4];
#pragma unroll
        for (int n = 0; n < 4; ++n)
            bcol[n] = bv[bx * 128 + wn * 64 + n * 16 + lr];
#pragma unroll
        for (int m = 0; m < 4; ++m)
#pragma unroll
            for (int n = 0; n < 4; ++n) {
                int colg = bx * 128 + wn * 64 + n * 16 + lr;
#pragma unroll
                for (int r = 0; r < 4; ++r) {
                    int rowg = by * 128 + wm * 64 + m * 16 + lg * 4 + r;
                    Vb[(size_t)rowg * 1024 + colg] = f2bf(acc[m][n][r] + bcol[n]);
                }
            }
    }
}

// ---------------------------------------------------------------------------
// Merged preprocessing: x split + 4 weight transposes in ONE dispatch.
// ---------------------------------------------------------------------------
__global__ void __launch_bounds__(256)
preprocess(const float* __restrict__ x,
           const float* __restrict__ wq, const float* __restrict__ wk,
           const float* __restrict__ wv, const float* __restrict__ wo,
           unsigned short* __restrict__ xh, unsigned short* __restrict__ xl,
           unsigned short* __restrict__ wqhT, unsigned short* __restrict__ wqlT,
           unsigned short* __restrict__ wkhT, unsigned short* __restrict__ wklT,
           unsigned short* __restrict__ wvT, unsigned short* __restrict__ woT)
{
    __shared__ float t[32][33];
    const int bid = blockIdx.x, tid = threadIdx.x;
    if (bid < 8192) {
        size_t i = (size_t)bid * 1024 + tid * 4;
        float4 v = *(const float4*)(x + i);
        ushort4 h, l2;
        h.x = f2bf(v.x); l2.x = f2bf(v.x - bf2f(h.x));
        h.y = f2bf(v.y); l2.y = f2bf(v.y - bf2f(h.y));
        h.z = f2bf(v.z); l2.z = f2bf(v.z - bf2f(h.z));
        h.w = f2bf(v.w); l2.w = f2bf(v.w - bf2f(h.w));
        *(ushort4*)(xh + i) = h;
        *(ushort4*)(xl + i) = l2;
        return;
    }
    const int grp = (bid - 8192) >> 10;
    const int b2 = (bid - 8192) & 1023;
    const int bx = (b2 & 31) * 32, by = (b2 >> 5) * 32;
    const float* in = (grp == 0) ? wq : (grp == 1) ? wk : (grp == 2) ? wv : wo;
    const int lx = tid & 31, ly = tid >> 5;
#pragma unroll
    for (int r = 0; r < 4; ++r)
        t[ly + r * 8][lx] = in[(size_t)(by + ly + r * 8) * 1024 + bx + lx];
    __syncthreads();
#pragma unroll
    for (int r = 0; r < 4; ++r) {
        int oc = ly + r * 8;
        float f = t[lx][oc];
        size_t od = (size_t)(bx + oc) * 1024 + by + lx;
        unsigned short hh = f2bf(f);
        if (grp == 0) { wqhT[od] = hh; wqlT[od] = f2bf(f - bf2f(hh)); }
        else if (grp == 1) { wkhT[od] = hh; wklT[od] = f2bf(f - bf2f(hh)); }
        else if (grp == 2) wvT[od] = hh;
        else woT[od] = hh;
    }
}

// plain transpose+convert (FFN weights)
__global__ void __launch_bounds__(256)
tconv(const float* __restrict__ in, int R, int C, unsigned short* __restrict__ out)
{
    __shared__ float t[32][33];
    const int bx = blockIdx.x * 32;
    const int by = blockIdx.y * 32;
    const int lx = threadIdx.x & 31, ly = threadIdx.x >> 5;
#pragma unroll
    for (int r = 0; r < 4; ++r)
        t[ly + r * 8][lx] = in[(size_t)(by + ly + r * 8) * C + bx + lx];
    __syncthreads();
#pragma unroll
    for (int r = 0; r < 4; ++r) {
        int oc = ly + r * 8;
        out[(size_t)(bx + oc) * R + by + lx] = f2bf(t[lx][oc]);
    }
}

// ---------------------------------------------------------------------------
// Gather sampled K rows into packed pre-swizzled KS[bh][2048][128].
// ---------------------------------------------------------------------------
__global__ void __launch_bounds__(256)
gather_ks(const unsigned short* __restrict__ KP, const int* __restrict__ idxs,
          unsigned short* __restrict__ KS)
{
    const int bh = blockIdx.x, b = bh >> 4, h = bh & 15;
    const int r0 = blockIdx.y * 256;
    const int s = threadIdx.x & 15, jr = threadIdx.x >> 4;
#pragma unroll
    for (int p = 0; p < 16; ++p) {
        int j = r0 + p * 16 + jr;
        int idx = idxs[j];
        int kc = (s & 7) ^ (j & 7);
        const unsigned short* src = KP + (size_t)(b * 2048 + idx) * 2048
                                  + h * 128 + ((s & 8) << 3) + kc * 8;
        *(bf16x8*)(KS + ((size_t)bh * 2048 + j) * 128 + s * 8) =
            *(const bf16x8*)src;
    }
}

// ---------------------------------------------------------------------------
// MFMA M-stat v3: block = (bh, qtile of 128 queries) -> 1024 blocks.
// ---------------------------------------------------------------------------
__global__ void __launch_bounds__(256)
mstat_mfma2(const unsigned short* __restrict__ QP,
            const unsigned short* __restrict__ KS,
            float* __restrict__ Mout)
{
    __shared__ char lds[32768];
    const int tid = threadIdx.x, w = tid >> 6, l = tid & 63;
    const int bh = blockIdx.x, qt = blockIdx.y;
    const int i0 = qt * 128;
    const int lr = l & 15, lg = l >> 4;

    bf16x8 af[2][2][2];   // [m][ks][hi/lo]
#pragma unroll
    for (int half = 0; half < 2; ++half) {
        __syncthreads();
#pragma unroll
        for (int it = 0; it < 4; ++it) {
            int rq = w * 32 + it * 8 + (l >> 3);
            int i = i0 + rq;
            int kc = (l & 7) ^ (rq & 7);
            gload_lds16(QP + (size_t)(bh * 128 + (i >> 4)) * 2048
                           + (i & 15) * 128 + half * 64 + kc * 8,
                        lds + w * 4096 + it * 1024);
        }
        __syncthreads();
#pragma unroll
        for (int m = 0; m < 2; ++m) {
            int rq = w * 32 + m * 16 + lr;
#pragma unroll
            for (int ks = 0; ks < 2; ++ks) {
                int c = (ks * 4 + lg) ^ (rq & 7);
                af[m][ks][half] = *(const bf16x8*)(lds + rq * 128 + (c << 4));
            }
        }
    }
    __syncthreads();

    float mx[2][4], sm[2][4];
#pragma unroll
    for (int m = 0; m < 2; ++m)
#pragma unroll
        for (int r = 0; r < 4; ++r) { mx[m][r] = -FLT_MAX; sm[m][r] = 0.f; }

    const unsigned short* ksbase = KS + (size_t)bh * (2048 * 128);

#pragma unroll
    for (int it = 0; it < 4; ++it)
        gload_lds16(ksbase + w * 2048 + it * 512 + l * 8,
                    lds + w * 4096 + it * 1024);

    for (int jt = 0; jt < 32; ++jt) {
        const int cur = jt & 1;
        __syncthreads();
        if (jt + 1 < 32) {
#pragma unroll
            for (int it = 0; it < 4; ++it)
                gload_lds16(ksbase + (size_t)(jt + 1) * 8192 + w * 2048 + it * 512 + l * 8,
                            lds + (cur ^ 1) * 16384 + w * 4096 + it * 1024);
        }
        const char* kb = lds + cur * 16384;
#pragma unroll
        for (int n = 0; n < 4; ++n) {
            int jr = n * 16 + lr;
            bf16x8 bgh[2], bgl[2];
#pragma unroll
            for (int ks = 0; ks < 2; ++ks) {
                int c = (ks * 4 + lg) ^ (jr & 7);
                bgh[ks] = *(const bf16x8*)(kb + jr * 256 + (c << 4));
                bgl[ks] = *(const bf16x8*)(kb + jr * 256 + (c << 4) + 128);
            }
#pragma unroll
            for (int m = 0; m < 2; ++m) {
                f32x4 a = {};
                a = __builtin_amdgcn_mfma_f32_16x16x32_bf16(af[m][0][0], bgh[0], a, 0, 0, 0);
                a = __builtin_amdgcn_mfma_f32_16x16x32_bf16(af[m][0][1], bgh[0], a, 0, 0, 0);
                a = __builtin_amdgcn_mfma_f32_16x16x32_bf16(af[m][0][0], bgl[0], a, 0, 0, 0);
                a = __builtin_amdgcn_mfma_f32_16x16x32_bf16(af[m][1][0], bgh[1], a, 0, 0, 0);
                a = __builtin_amdgcn_mfma_f32_16x16x32_bf16(af[m][1][1], bgh[1], a, 0, 0, 0);
                a = __builtin_amdgcn_mfma_f32_16x16x32_bf16(af[m][1][0], bgl[1], a, 0, 0, 0);
#pragma unroll
                for (int r = 0; r < 4; ++r) {
                    mx[m][r] = fmaxf(mx[m][r], a[r]);
                    sm[m][r] += a[r];
                }
            }
        }
    }

#pragma unroll
    for (int m = 0; m < 2; ++m)
#pragma unroll
        for (int r = 0; r < 4; ++r) {
            float a = mx[m][r], s = sm[m][r];
#pragma unroll
            for (int mask = 1; mask < 16; mask <<= 1) {
                a = fmaxf(a, __shfl_xor(a, mask));
                s += __shfl_xor(s, mask);
            }
            if (lr == 0) {
                int row = i0 + w * 32 + m * 16 + lg * 4 + r;
                Mout[(size_t)bh * L_SEQ + row] = a - s * (1.0f / 2048.0f);
            }
        }
}

// ---------------------------------------------------------------------------
// Top-40 smallest M per bh (lower-index tie-break).
// ---------------------------------------------------------------------------
__global__ void __launch_bounds__(256)
topk_kernel(const float* __restrict__ M, int* __restrict__ Mtop)
{
    __shared__ float mv[L_SEQ];
    __shared__ float wv_[4];
    __shared__ int wi_[4];
    const int bh = blockIdx.x;
    const int tid = threadIdx.x;
    for (int j = tid; j < L_SEQ; j += 256) mv[j] = M[(size_t)bh * L_SEQ + j];
    __syncthreads();
    for (int u = 0; u < U_TOP; ++u) {
        float best = FLT_MAX;
        int bi = 1 << 30;
        for (int j = tid; j < L_SEQ; j += 256) {
            float v = mv[j];
            if (v < best || (v == best && j < bi)) { best = v; bi = j; }
        }
#pragma unroll
        for (int off = 32; off; off >>= 1) {
            float ov = __shfl_down(best, off);
            int oi = __shfl_down(bi, off);
            if (ov < best || (ov == best && oi < bi)) { best = ov; bi = oi; }
        }
        if ((tid & 63) == 0) { wv_[tid >> 6] = best; wi_[tid >> 6] = bi; }
        __syncthreads();
        if (tid == 0) {
            for (int w = 1; w < 4; ++w)
                if (wv_[w] < best || (wv_[w] == best && wi_[w] < bi)) { best = wv_[w]; bi = wi_[w]; }
            Mtop[bh * U_TOP + u] = bi;
            mv[bi] = FLT_MAX;
        }
        __syncthreads();
    }
}

// ---------------------------------------------------------------------------
// FUSED sparse attention, KV-SPLIT: grid (4 splits, 64 bh) = 256 blocks.
// ---------------------------------------------------------------------------
__global__ void __launch_bounds__(256)
attn_fused(const unsigned short* __restrict__ QP,
           const unsigned short* __restrict__ KP,
           const unsigned short* __restrict__ V,
           const int* __restrict__ Mtop,
           unsigned short* __restrict__ PART,
           float* __restrict__ ML)
{
    __shared__ unsigned short Qs[64 * 64];
    __shared__ unsigned short Ks[128 * 64];
    __shared__ unsigned short Vt[64 * 128];
    __shared__ unsigned short Pb[64 * 128];
    const int sp = blockIdx.x, bh = blockIdx.y;
    const int b = bh >> 4, h = bh & 15;
    const int tid = threadIdx.x, w = tid >> 6, l = tid & 63;
    const int lr = l & 15, lg = l >> 4;

#pragma unroll
    for (int is = 0; is < 2; ++is) {
        int row = w * 16 + is * 8 + (l >> 3);
        int u = row < U_TOP ? row : U_TOP - 1;
        int lsel = Mtop[bh * U_TOP + u];
        int cg = (l & 7) ^ (row & 7);
        gload_lds16(QP + (size_t)(bh * 128 + (lsel >> 4)) * 2048
                       + (lsel & 15) * 128 + cg * 8,
                    &Qs[(w * 16 + is * 8) * 64]);
    }
    __syncthreads();

    bf16x8 af[2];
    {
        int row = w * 16 + lr;
#pragma unroll
        for (int ks = 0; ks < 2; ++ks) {
            int c = (ks * 4 + lg) ^ (row & 7);
            af[ks] = *(const bf16x8*)((const char*)Qs + row * 128 + (c << 4));
        }
    }

    float m_run[4], l_run[4];
    f32x4 oacc[4] = {};
#pragma unroll
    for (int r = 0; r < 4; ++r) { m_run[r] = -FLT_MAX; l_run[r] = 0.f; }

    for (int t = sp * 4; t < sp * 4 + 4; ++t) {
        const int j0 = t * 128;
        __syncthreads();

#pragma unroll
        for (int is = 0; is < 4; ++is) {
            int kr = w * 32 + is * 8 + (l >> 3);
            int cg = (l & 7) ^ (kr & 7);
            gload_lds16(KP + (size_t)(b * 2048 + j0 + kr) * 2048 + h * 128 + cg * 8,
                        &Ks[(w * 32 + is * 8) * 64]);
        }
        {
            int key = tid & 127, dh = (tid >> 7) * 32;
            const unsigned short* vsrc =
                V + (((size_t)(b * L_SEQ + j0 + key)) << 10) + (h << 6) + dh;
            bf16x8 vv[4];
#pragma unroll
            for (int i = 0; i < 4; ++i) vv[i] = *(const bf16x8*)(vsrc + i * 8);
            int ck = key >> 3, klo = (key & 7) * 2;
#pragma unroll
            for (int i = 0; i < 4; ++i)
#pragma unroll
                for (int j = 0; j < 8; ++j) {
                    int d = dh + i * 8 + j;
                    *(unsigned short*)((char*)Vt + d * 256 +
                                       ((ck ^ (d & 7)) << 4) + klo) =
                        (unsigned short)vv[i][j];
                }
        }
        __syncthreads();

        f32x4 sc[8] = {};
#pragma unroll
        for (int ks = 0; ks < 2; ++ks)
#pragma unroll
            for (int n = 0; n < 8; ++n) {
                int krow = n * 16 + lr;
                int c = (ks * 4 + lg) ^ (krow & 7);
                bf16x8 bf = *(const bf16x8*)((const char*)Ks + krow * 128 + (c << 4));
                sc[n] = __builtin_amdgcn_mfma_f32_16x16x32_bf16(af[ks], bf, sc[n], 0, 0, 0);
            }

        float rs[4];
#pragma unroll
        for (int r = 0; r < 4; ++r) {
            int row = w * 16 + lg * 4 + r;
            float mt = -FLT_MAX;
#pragma unroll
            for (int n = 0; n < 8; ++n) mt = fmaxf(mt, sc[n][r]);
            mt *= 0.125f;
#pragma unroll
            for (int mask = 1; mask < 16; mask <<= 1)
                mt = fmaxf(mt, __shfl_xor(mt, mask));
            float mn = fmaxf(m_run[r], mt);
            rs[r] = expf(m_run[r] - mn);
            float ls = 0.f;
            int rsw = row & 7;
#pragma unroll
            for (int n = 0; n < 8; ++n) {
                float p = expf(sc[n][r] * 0.125f - mn);
                ls += p;
                int ckp = (lr >> 3) + 2 * n;
                *(unsigned short*)((char*)Pb + row * 256 +
                                   ((ckp ^ rsw) << 4) + (lr & 7) * 2) = f2bf(p);
            }
#pragma unroll
            for (int mask = 1; mask < 16; mask <<= 1) ls += __shfl_xor(ls, mask);
            l_run[r] = l_run[r] * rs[r] + ls;
            m_run[r] = mn;
        }
        __syncthreads();

#pragma unroll
        for (int n = 0; n < 4; ++n)
#pragma unroll
            for (int r = 0; r < 4; ++r) oacc[n][r] *= rs[r];
#pragma unroll
        for (int ks = 0; ks < 4; ++ks) {
            int arow = w * 16 + lr;
            int ca = (lg + ks * 4) ^ (arow & 7);
            bf16x8 pa = *(const bf16x8*)((const char*)Pb + arow * 256 + (ca << 4));
#pragma unroll
            for (int n = 0; n < 4; ++n) {
                int d = n * 16 + lr;
                int cb = (lg + ks * 4) ^ (d & 7);
                bf16x8 vb = *(const bf16x8*)((const char*)Vt + d * 256 + (cb << 4));
                oacc[n] = __builtin_amdgcn_mfma_f32_16x16x32_bf16(pa, vb, oacc[n], 0, 0, 0);
            }
        }
    }

    const int pbase = (bh * 4 + sp) * 64;
#pragma unroll
    for (int r = 0; r < 4; ++r) {
        int row = w * 16 + lg * 4 + r;
#pragma unroll
        for (int n = 0; n < 4; ++n)
            PART[(size_t)(pbase + row) * 64 + n * 16 + lr] = f2bf(oacc[n][r]);
        if (lr == 0) {
            ML[(size_t)(pbase + row) * 2 + 0] = m_run[r];
            ML[(size_t)(pbase + row) * 2 + 1] = l_run[r];
        }
    }
}

// ---------------------------------------------------------------------------
// Combine KV-splits + scatter-GEMM into zeroed Ab (bo folded into LN1).
// ---------------------------------------------------------------------------
__global__ void __launch_bounds__(256)
woscatter(const unsigned short* __restrict__ PART,
          const float* __restrict__ ML,
          const unsigned short* __restrict__ woT,
          const int* __restrict__ Mtop,
          float* __restrict__ Ab)
{
    const int bh = blockIdx.x, b = bh >> 4, h = bh & 15;
    const int tid = threadIdx.x, w = tid >> 6, l = tid & 63;
    const int lr = l & 15, lg = l >> 4;

    bf16x8 af[3][2];
#pragma unroll
    for (int m = 0; m < 3; ++m) {
        int row = m * 16 + lr;
        float ms[4], ls[4];
#pragma unroll
        for (int s = 0; s < 4; ++s) {
            ms[s] = ML[(size_t)((bh * 4 + s) * 64 + row) * 2 + 0];
            ls[s] = ML[(size_t)((bh * 4 + s) * 64 + row) * 2 + 1];
        }
        float M = fmaxf(fmaxf(ms[0], ms[1]), fmaxf(ms[2], ms[3]));
        float wgt[4], L = 0.f;
#pragma unroll
        for (int s = 0; s < 4; ++s) { wgt[s] = expf(ms[s] - M); L += wgt[s] * ls[s]; }
        float invL = 1.f / L;
#pragma unroll
        for (int ks = 0; ks < 2; ++ks) {
            float a8[8] = {};
#pragma unroll
            for (int s = 0; s < 4; ++s) {
                bf16x8 po = *(const bf16x8*)(PART +
                    (size_t)((bh * 4 + s) * 64 + row) * 64 + (ks * 4 + lg) * 8);
#pragma unroll
                for (int j = 0; j < 8; ++j)
                    a8[j] += wgt[s] * bf2f((unsigned short)po[j]);
            }
            bf16x8 fr;
#pragma unroll
            for (int j = 0; j < 8; ++j) fr[j] = (short)f2bf(a8[j] * invL);
            af[m][ks] = fr;
        }
    }

    int lsel[3][4];
#pragma unroll
    for (int m = 0; m < 3; ++m)
#pragma unroll
        for (int r = 0; r < 4; ++r) {
            int row = m * 16 + lg * 4 + r;
            lsel[m][r] = row < U_TOP ? Mtop[bh * U_TOP + row] : -1;
        }

    for (int nn = 0; nn < 16; ++nn) {
        int ng = w * 16 + nn;
        bf16x8 bg[2];
#pragma unroll
        for (int ks = 0; ks < 2; ++ks)
            bg[ks] = *(const bf16x8*)(woT + (size_t)(ng * 16 + lr) * 1024
                                      + h * 64 + (ks * 4 + lg) * 8);
        f32x4 a[3] = {};
#pragma unroll
        for (int m = 0; m < 3; ++m)
#pragma unroll
            for (int ks = 0; ks < 2; ++ks)
                a[m] = __builtin_amdgcn_mfma_f32_16x16x32_bf16(af[m][ks], bg[ks], a[m], 0, 0, 0);
#pragma unroll
        for (int m = 0; m < 3; ++m)
#pragma unroll
            for (int r = 0; r < 4; ++r)
                if (lsel[m][r] >= 0)
                    atomicAdd(Ab + (size_t)(b * 2048 + lsel[m][r]) * 1024
                              + ng * 16 + lr, a[m][r]);
    }
}

// ---------------------------------------------------------------------------
// LN1: x1 = LN(x + Ab + bo) -> bf16 only.
// ---------------------------------------------------------------------------
__global__ void __launch_bounds__(256)
ln1_kernel(const float* __restrict__ X, const float* __restrict__ A,
           const float* __restrict__ badd,
           const float* __restrict__ g, const float* __restrict__ be,
           unsigned short* __restrict__ out16)
{
    __shared__ float wred[4];
    const int row = blockIdx.x, tid = threadIdx.x;
    float4 xv = *(const float4*)(X + (size_t)row * D_MODEL + tid * 4);
    float4 av = *(const float4*)(A + (size_t)row * D_MODEL + tid * 4);
    float4 bb = *(const float4*)(badd + tid * 4);
    float v0 = xv.x + av.x + bb.x, v1 = xv.y + av.y + bb.y;
    float v2 = xv.z + av.z + bb.z, v3 = xv.w + av.w + bb.w;

    float s = v0 + v1 + v2 + v3;
#pragma unroll
    for (int off = 32; off; off >>= 1) s += __shfl_down(s, off);
    if ((tid & 63) == 0) wred[tid >> 6] = s;
    __syncthreads();
    float mean = (wred[0] + wred[1] + wred[2] + wred[3]) * (1.f / 1024.f);
    __syncthreads();

    float d0 = v0 - mean, d1 = v1 - mean, d2 = v2 - mean, d3 = v3 - mean;
    float q = d0 * d0 + d1 * d1 + d2 * d2 + d3 * d3;
#pragma unroll
    for (int off = 32; off; off >>= 1) q += __shfl_down(q, off);
    if ((tid & 63) == 0) wred[tid >> 6] = q;
    __syncthreads();
    float var = (wred[0] + wred[1] + wred[2] + wred[3]) * (1.f / 1024.f);
    float rstd = rsqrtf(var + 1e-12f);

    float4 gv = *(const float4*)(g + tid * 4);
    float4 bv = *(const float4*)(be + tid * 4);
    ushort4 ob;
    ob.x = f2bf(gv.x * d0 * rstd + bv.x);
    ob.y = f2bf(gv.y * d1 * rstd + bv.y);
    ob.z = f2bf(gv.z * d2 * rstd + bv.z);
    ob.w = f2bf(gv.w * d3 * rstd + bv.w);
    *(ushort4*)(out16 + (size_t)row * D_MODEL + tid * 4) = ob;
}

// ---------------------------------------------------------------------------
// LN2: out = LN(x1(bf16) + F0 + F1), fp32 out (in-place over F0 safe).
// ---------------------------------------------------------------------------
__global__ void __launch_bounds__(256)
ln2_kernel(const unsigned short* __restrict__ X16, const float* __restrict__ F0,
           const float* __restrict__ F1,
           const float* __restrict__ g, const float* __restrict__ be,
           float* __restrict__ out)
{
    __shared__ float wred[4];
    const int row = blockIdx.x, tid = threadIdx.x;
    ushort4 xv = *(const ushort4*)(X16 + (size_t)row * D_MODEL + tid * 4);
    float4 a0 = *(const float4*)(F0 + (size_t)row * D_MODEL + tid * 4);
    float4 a1 = *(const float4*)(F1 + (size_t)row * D_MODEL + tid * 4);
    float v0 = bf2f(xv.x) + a0.x + a1.x, v1 = bf2f(xv.y) + a0.y + a1.y;
    float v2 = bf2f(xv.z) + a0.z + a1.z, v3 = bf2f(xv.w) + a0.w + a1.w;

    float s = v0 + v1 + v2 + v3;
#pragma unroll
    for (int off = 32; off; off >>= 1) s += __shfl_down(s, off);
    if ((tid & 63) == 0) wred[tid >> 6] = s;
    __syncthreads();
    float mean = (wred[0] + wred[1] + wred[2] + wred[3]) * (1.f / 1024.f);
    __syncthreads();

    float d0 = v0 - mean, d1 = v1 - mean, d2 = v2 - mean, d3 = v3 - mean;
    float q = d0 * d0 + d1 * d1 + d2 * d2 + d3 * d3;
#pragma unroll
    for (int off = 32; off; off >>= 1) q += __shfl_down(q, off);
    if ((tid & 63) == 0) wred[tid >> 6] = q;
    __syncthreads();
    float var = (wred[0] + wred[1] + wred[2] + wred[3]) * (1.f / 1024.f);
    float rstd = rsqrtf(var + 1e-12f);

    float4 gv = *(const float4*)(g + tid * 4);
    float4 bv = *(const float4*)(be + tid * 4);
    float4 o;
    o.x = gv.x * d0 * rstd + bv.x;
    o.y = gv.y * d1 * rstd + bv.y;
    o.z = gv.z * d2 * rstd + bv.z;
    o.w = gv.w * d3 * rstd + bv.w;
    *(float4*)(out + (size_t)row * D_MODEL + tid * 4) = o;
}

// ---------------------------------------------------------------------------
extern "C" void kernel_launch(void* const* d_in, const int* in_sizes, int n_in,
                              void* d_out, int out_size, void* d_ws, size_t ws_size,
                              hipStream_t stream)
{
    const float* x   = (const float*)d_in[0];
    const float* wq  = (const float*)d_in[1];
    const float* bq  = (const float*)d_in[2];
    const float* wk  = (const float*)d_in[3];
    const float* bk  = (const float*)d_in[4];
    const float* wv  = (const float*)d_in[5];
    const float* bv  = (const float*)d_in[6];
    const float* wo  = (const float*)d_in[7];
    const float* bo  = (const float*)d_in[8];
    const float* w1  = (const float*)d_in[9];
    const float* b1  = (const float*)d_in[10];
    const float* w2  = (const float*)d_in[11];
    const float* b2  = (const float*)d_in[12];
    const float* g1  = (const float*)d_in[13];
    const float* be1 = (const float*)d_in[14];
    const float* g2  = (const float*)d_in[15];
    const float* be2 = (const float*)d_in[16];
    const int*  idxs = (const int*)d_in[17];

    char* ws  = (char*)d_ws;
    char* dob = (char*)d_out;
    const size_t MB = 1u << 20;

    // ---- workspace (phase-disjoint; peak 128 MB) ----
    unsigned short* QP   = (unsigned short*)(ws);             // 0-32   [qkv..attn]
    unsigned short* KP   = (unsigned short*)(ws + 32 * MB);   // 32-64  [qkv..attn]
    unsigned short* xh   = (unsigned short*)(ws + 64 * MB);   // 64-80  [pre..qkv]
    unsigned short* xl   = (unsigned short*)(ws + 80 * MB);   // 80-96  [pre..qkv]
    unsigned short* KS   = (unsigned short*)(ws + 64 * MB);   // 64-96  [gather..mstat]
    float*          Ab   = (float*)(ws + 64 * MB);            // 64-96  [memset..ln1]
    unsigned short* x1b  = (unsigned short*)(ws);             // 0-16   [ln1..ln2]
    unsigned short* w1T  = (unsigned short*)(ws + 16 * MB);   // 16-24  [tc..ffn]
    unsigned short* w2T  = (unsigned short*)(ws + 24 * MB);   // 24-32  [tc..ffn]
    unsigned short* HID  = (unsigned short*)(ws + 32 * MB);   // 32-96  [ffn] 64MB
    float*          F1   = (float*)(ws + 96 * MB);            // 96-128 [w2..ln2]

    // ---- d_out doubles as scratch until the FFN w2 GEMM ----
    unsigned short* woT  = (unsigned short*)(dob);            // 0-2
    unsigned short* wqhT = (unsigned short*)(dob + 2 * MB);
    unsigned short* wqlT = (unsigned short*)(dob + 4 * MB);
    unsigned short* wkhT = (unsigned short*)(dob + 6 * MB);
    unsigned short* wklT = (unsigned short*)(dob + 8 * MB);
    unsigned short* wvT  = (unsigned short*)(dob + 10 * MB);
    float*          Mb   = (float*)(dob + 12 * MB);           // 512 KB
    int*            Mtop = (int*)(dob + 12 * MB + 768 * 1024);
    unsigned short* Vb   = (unsigned short*)(dob + 13 * MB);  // 13-29
    unsigned short* PART = (unsigned short*)(dob + 29 * MB);  // 29-31
    float*          ML   = (float*)(dob + 31 * MB);           // 128 KB
    float*          F0   = (float*)d_out;                     // w2 z=0 output

    dim3 blk(256);

    // merged preprocessing: x split + wq/wk split-T + wv/wo T
    preprocess<<<dim3(12288), blk, 0, stream>>>(x, wq, wk, wv, wo,
                                                xh, xl, wqhT, wqlT, wkhT, wklT,
                                                wvT, woT);

    // fused q/k/v projections (1536 blocks, ~5/CU)
    gemm_qkv<<<dim3(24, 64), blk, 0, stream>>>(xh, xl, wqhT, wqlT, wkhT, wklT,
                                               wvT, QP, KP, Vb, bq, bk, bv);

    // selection: pre-gather sampled K, streamed MFMA M-stat, top-40
    gather_ks<<<dim3(64, 8), blk, 0, stream>>>(KP, idxs, KS);
    mstat_mfma2<<<dim3(64, 16), blk, 0, stream>>>(QP, KS, Mb);
    topk_kernel<<<dim3(64), blk, 0, stream>>>(Mb, Mtop);

    // fused sparse attention, kv-split 4x -> partials; combine+wo in woscatter
    hipMemsetAsync(Ab, 0, 32 * MB, stream);
    attn_fused<<<dim3(4, N_BH), blk, 0, stream>>>(QP, KP, Vb, Mtop, PART, ML);
    woscatter<<<dim3(N_BH), blk, 0, stream>>>(PART, ML, woT, Mtop, Ab);

    // x1 = LN(x + Ab + bo) -> bf16 only
    ln1_kernel<<<dim3(8192), blk, 0, stream>>>(x, Ab, bo, g1, be1, x1b);

    // FFN weights
    tconv<<<dim3(128, 32), blk, 0, stream>>>(w1, 1024, 4096, w1T);
    tconv<<<dim3(32, 128), blk, 0, stream>>>(w2, 4096, 1024, w2T);

    // FFN: HID = relu(x1@w1+b1); w2 K-split x2 -> F0 (bias) + F1
    gemm_bf16<true, true, false><<<dim3(32, 64), blk, 0, stream>>>(
        x1b, 1024, w1T, 1024, HID, 4096, 1024, b1, nullptr);
    gemm_bf16<false, false, true><<<dim3(8, 64, 2), blk, 0, stream>>>(
        HID, 4096, w2T, 4096, F0, 1024, 2048, b2, F1);

    // out = LN(x1 + F0 + F1)
    ln2_kernel<<<dim3(8192), blk, 0, stream>>>(x1b, F0, F1, g2, be2, (float*)d_out);
}